// Round 2
// baseline (159.605 us; speedup 1.0000x reference)
//
#include <hip/hip_runtime.h>
#include <hip/hip_bf16.h>

#define T_ 4
#define B_ 4
#define C_ 256
#define H_ 32
#define W_ 32
#define TB_ 16
#define Hh_ 16
#define Wh_ 16
#define INVS2 0.70710678118654752440f
#define EPSBN 1e-5f

// Canonical weight arena offsets (bf16 elements)
#define OFF_HW   0
#define OFF_W1   4096
#define OFF_B1   4352
#define OFF_W2   4368
#define OFF_B2   6672
#define OFF_G1   6688
#define OFF_BE1  7200
#define OFF_G2   7712
#define OFF_BE2  8736
#define OFF_G3   9760
#define OFF_BE3  10016
#define OFF_G4   10272
#define OFF_BE4  10528
#define OFF_G5   10784
#define OFF_BE5  11040
#define W_TOTAL  11296
// stats arena (floats): sums1[1024] | sums2[2048] | sums345[1536]
#define NSUMS    4608

struct WPtrs { const void* p[15]; };

typedef __attribute__((ext_vector_type(8))) short short8;
typedef __attribute__((ext_vector_type(4))) float f32x4;

__device__ inline float bf2f(__hip_bfloat16 v) { return __bfloat162float(v); }
__device__ inline float bfu(unsigned short u) { return __uint_as_float((unsigned)u << 16); }

// ---------------------------------------------------------------------------
// k_prep: per-block self-sniff (fp32 vs bf16), convert weights to bf16 arena,
// zero the raw-sums region; block 0 publishes the flag for later kernels.
// ---------------------------------------------------------------------------
__global__ __launch_bounds__(256) void k_prep(const unsigned short* __restrict__ xr,
                                              WPtrs wp,
                                              __hip_bfloat16* __restrict__ wc,
                                              float* __restrict__ sums,
                                              int* __restrict__ flag) {
    int tid = threadIdx.x;
    int cnt = 0;
    for (int i = tid; i < 2048; i += 256) {
        int e = (xr[i] >> 7) & 0xFF;
        if (e >= 134) cnt++;
    }
    for (int o = 1; o < 64; o <<= 1) cnt += __shfl_xor(cnt, o, 64);
    __shared__ int sh[4];
    if ((tid & 63) == 0) sh[tid >> 6] = cnt;
    __syncthreads();
    int f = (sh[0] + sh[1] + sh[2] + sh[3] >= 32) ? 1 : 0;
    if (blockIdx.x == 0 && tid == 0) *flag = f;

    const int sizes[15] = {4096, 256, 16, 2304, 16, 512, 512, 1024, 1024,
                           256, 256, 256, 256, 256, 256};
    int i = blockIdx.x * 256 + tid;
    if (i < W_TOTAL) {
        int seg = 0, off = 0;
        while (i >= off + sizes[seg]) { off += sizes[seg]; seg++; }
        int j = i - off;
        float v = f ? ((const float*)wp.p[seg])[j]
                    : bf2f(((const __hip_bfloat16*)wp.p[seg])[j]);
        wc[i] = __float2bfloat16(v);
    }
    if (i < NSUMS) sums[i] = 0.f;
}

// ---------------------------------------------------------------------------
// Fused LIF + Haar-W. Planar coalesced u8 spikes + i8 Haar codes + BN1 sums.
// Block = (b, c, half); thread = (row-in-half, w-pair).
// ---------------------------------------------------------------------------
__global__ __launch_bounds__(256) void k_lifhaar(const void* __restrict__ x_,
                                                 const int* __restrict__ flag,
                                                 unsigned char* __restrict__ s,
                                                 signed char* __restrict__ l1,
                                                 float* __restrict__ sums1) {
    int bid = blockIdx.x;                      // 2048 = b(4) * c(256) * half(2)
    int tid = threadIdx.x;
    int half = bid & 1;
    int c = (bid >> 1) & 255;
    int b = bid >> 9;
    int wp = tid & 15;
    int hl = tid >> 4;
    int h = half * 16 + hl;
    int f = *flag;
    const float* xf = (const float*)x_;
    const unsigned int* xb = (const unsigned int*)x_;
    int n = ((b * 256 + c) * 32 + h) * 32 + 2 * wp;

    float v0 = 0.f, v1 = 0.f;
    float aL = 0.f, qL = 0.f, aH = 0.f, qH = 0.f;
    #pragma unroll
    for (int t = 0; t < T_; ++t) {
        size_t idx = (size_t)t * 1048576 + n;
        float x0, x1;
        if (f) {
            float2 xx = *(const float2*)(xf + idx);
            x0 = xx.x; x1 = xx.y;
        } else {
            unsigned int u = xb[idx >> 1];
            x0 = __uint_as_float(u << 16);
            x1 = __uint_as_float(u & 0xffff0000u);
        }
        v0 += (x0 - v0) * 0.5f;
        v1 += (x1 - v1) * 0.5f;
        float s0 = (v0 >= 1.f) ? 1.f : 0.f;
        float s1 = (v1 >= 1.f) ? 1.f : 0.f;
        v0 *= (1.f - s0);
        v1 *= (1.f - s1);
        int tb = t * 4 + b;
        ((uchar2*)s)[(size_t)(tb * 256 + c) * 512 + h * 16 + wp] =
            make_uchar2((unsigned char)s0, (unsigned char)s1);
        float cl = s0 + s1, ch = s0 - s1;
        size_t lb = (((size_t)tb * 512 + c) * 32 + h) * 16 + wp;
        l1[lb] = (signed char)(int)cl;
        l1[lb + (size_t)256 * 512] = (signed char)(int)ch;
        aL += cl; qL += cl * cl; aH += ch; qH += ch * ch;
    }
    for (int o = 1; o < 64; o <<= 1) {
        aL += __shfl_xor(aL, o, 64); qL += __shfl_xor(qL, o, 64);
        aH += __shfl_xor(aH, o, 64); qH += __shfl_xor(qH, o, 64);
    }
    __shared__ float part[4][4];
    int lane = tid & 63, wv = tid >> 6;
    if (lane == 0) {
        part[wv][0] = aL; part[wv][1] = qL; part[wv][2] = aH; part[wv][3] = qH;
    }
    __syncthreads();
    if (tid < 4) {
        float tot = part[0][tid] + part[1][tid] + part[2][tid] + part[3][tid];
        const int offs[4] = {0, 512, 256, 768};
        atomicAdd(&sums1[offs[tid] + c], tot);
    }
}

// ---------------------------------------------------------------------------
// Fused k_work: bids [0,256) = conv STATS role (MFMA implicit GEMM, BN4/5
// sum accumulation only — no c1/c2 stores); bids [256,4352) = stage2 role
// (BN1-apply + Haar-H + gates -> l2, BN2 sum accumulation).
// ---------------------------------------------------------------------------
struct SharedU {
    union {
        struct {
            short lo[1025 * 8];            // channel-last bf16, d 0..7 (+zero row)
            short hi[1025 * 8];            // d 8..15
            unsigned short w2s[2304];      // [k][d*9+tap]
            unsigned short w1s[256];       // [k][d]
            unsigned short bs[32];         // B1 | B2
            float parts[4][4][16];         // [wv][g][r*4+which]
        } cv;
        struct {
            float lo[512];
            float hi[512];
            float part[4][8];
        } s2;
    };
};

__global__ __launch_bounds__(256) void k_work(const unsigned char* __restrict__ s,
                                              const signed char* __restrict__ l1,
                                              const float* __restrict__ sums1,
                                              const __hip_bfloat16* __restrict__ wc,
                                              float* __restrict__ stats,
                                              __hip_bfloat16* __restrict__ l2) {
    __shared__ SharedU sm;
    int bid = blockIdx.x;
    int tid = threadIdx.x;
    int lane = tid & 63, wv = tid >> 6;

    if (bid < 256) {
        // ------------------------------ conv stats role ------------------------------
        int img = bid;
        const unsigned short* wr = (const unsigned short*)wc;
        for (int i = tid; i < 2304; i += 256) sm.cv.w2s[i] = wr[OFF_W2 + i];
        sm.cv.w1s[tid] = wr[OFF_W1 + tid];
        if (tid < 16) { sm.cv.bs[tid] = wr[OFF_B1 + tid]; sm.cv.bs[16 + tid] = wr[OFF_B2 + tid]; }
        // zero row (pixel index 1024)
        if (tid < 8) {
            ((unsigned int*)sm.cv.lo)[4096 + (tid & 3)] = 0;
            ((unsigned int*)sm.cv.hi)[4096 + (tid & 3)] = 0;
        }
        // stage planar u8 -> LDS channel-last bf16
        {
            const unsigned int* sp = (const unsigned int*)(s + (size_t)img * 16384);
            int d2 = tid >> 5;               // channel pair 2*d2, 2*d2+1
            int pg = tid & 31;
            unsigned int* dst = (unsigned int*)((d2 < 4) ? sm.cv.lo : sm.cv.hi);
            int dl = d2 & 3;
            #pragma unroll
            for (int p = 0; p < 8; ++p) {
                int base = p * 32 + pg;      // dword index within a channel row
                unsigned int u0 = sp[d2 * 512 + base];
                unsigned int u1 = sp[d2 * 512 + 256 + base];
                #pragma unroll
                for (int jj = 0; jj < 4; ++jj) {
                    int j = (jj + pg) & 3;   // scramble to spread LDS banks
                    unsigned int b0 = (u0 >> (8 * j)) & 255u;
                    unsigned int b1 = (u1 >> (8 * j)) & 255u;
                    unsigned int val = (b0 ? 0x3F80u : 0u) | ((b1 ? 0x3F80u : 0u) << 16);
                    int pix = p * 128 + pg * 4 + j;
                    dst[pix * 4 + dl] = val;
                }
            }
        }
        __syncthreads();

        int m = lane & 15;
        int g = lane >> 4;
        const int tapA[5] = {0, 2, 4, 6, 8};
        const int tapB[5] = {1, 3, 5, 7, 8};

        short8 afr[5], a1f;
        #pragma unroll
        for (int p = 0; p < 5; ++p) {
            int tap = (g < 2) ? tapA[p] : tapB[p];
            short8 av;
            #pragma unroll
            for (int j = 0; j < 8; ++j) {
                int d = (g & 1) * 8 + j;
                unsigned short w = sm.cv.w2s[m * 144 + d * 9 + tap];
                if (p == 4 && g >= 2) w = 0;
                av[j] = (short)w;
            }
            afr[p] = av;
        }
        #pragma unroll
        for (int j = 0; j < 8; ++j) {
            int d = (g & 1) * 8 + j;
            a1f[j] = (g < 2) ? (short)sm.cv.w1s[m * 16 + d] : (short)0;
        }
        float bias1[4], bias2[4];
        #pragma unroll
        for (int r = 0; r < 4; ++r) {
            bias1[r] = bfu(sm.cv.bs[g * 4 + r]);
            bias2[r] = bfu(sm.cv.bs[16 + g * 4 + r]);
        }

        const short* bsrc = (g & 1) ? sm.cv.hi : sm.cv.lo;

        float cs1[4] = {0, 0, 0, 0}, cq1[4] = {0, 0, 0, 0};
        float cs2[4] = {0, 0, 0, 0}, cq2[4] = {0, 0, 0, 0};

        for (int t = wv * 16; t < wv * 16 + 16; ++t) {
            int h = t >> 1;
            int w0 = (t & 1) << 4;
            f32x4 acc2 = {0.f, 0.f, 0.f, 0.f};
            f32x4 acc1 = {0.f, 0.f, 0.f, 0.f};
            #pragma unroll
            for (int p = 0; p < 5; ++p) {
                int tap = (g < 2) ? tapA[p] : tapB[p];
                int row = h + tap / 3 - 1;
                int col = w0 + m + (tap % 3) - 1;
                bool ok = ((unsigned)row < 32u) && ((unsigned)col < 32u);
                int idx = ok ? (row * 32 + col) : 1024;
                short8 bv = *(const short8*)&bsrc[idx * 8];
                acc2 = __builtin_amdgcn_mfma_f32_16x16x32_bf16(afr[p], bv, acc2, 0, 0, 0);
                if (p == 2)
                    acc1 = __builtin_amdgcn_mfma_f32_16x16x32_bf16(a1f, bv, acc1, 0, 0, 0);
            }
            #pragma unroll
            for (int r = 0; r < 4; ++r) {
                float y1 = acc1[r] + bias1[r];
                float y2 = acc2[r] + bias2[r];
                cs1[r] += y1; cq1[r] += y1 * y1;
                cs2[r] += y2; cq2[r] += y2 * y2;
            }
        }
        // reduce across the 16 m-lanes (same g)
        #pragma unroll
        for (int o = 1; o < 16; o <<= 1) {
            #pragma unroll
            for (int r = 0; r < 4; ++r) {
                cs1[r] += __shfl_xor(cs1[r], o, 64);
                cq1[r] += __shfl_xor(cq1[r], o, 64);
                cs2[r] += __shfl_xor(cs2[r], o, 64);
                cq2[r] += __shfl_xor(cq2[r], o, 64);
            }
        }
        if (m == 0) {
            #pragma unroll
            for (int r = 0; r < 4; ++r) {
                sm.cv.parts[wv][g][r * 4 + 0] = cs1[r];
                sm.cv.parts[wv][g][r * 4 + 1] = cq1[r];
                sm.cv.parts[wv][g][r * 4 + 2] = cs2[r];
                sm.cv.parts[wv][g][r * 4 + 3] = cq2[r];
            }
        }
        __syncthreads();
        if (tid < 64) {
            int gg = tid >> 4, r = (tid >> 2) & 3, which = tid & 3;
            float tot = sm.cv.parts[0][gg][r * 4 + which] + sm.cv.parts[1][gg][r * 4 + which]
                      + sm.cv.parts[2][gg][r * 4 + which] + sm.cv.parts[3][gg][r * 4 + which];
            int ch = (img & 15) * 16 + gg * 4 + r;   // global BN channel
            // stats: sums4_sum@3584 sums4_sq@3840 sums5_sum@4096 sums5_sq@4352
            const int base[4] = {3584, 3840, 4096, 4352};
            atomicAdd(&stats[base[which] + ch], tot);
        }
    } else {
        // ------------------------------ stage2 role ------------------------------
        int blk = bid - 256;                  // TB*C = 4096
        int c = blk & 255;
        int tb = blk >> 8;

        const float nrm = 1.f / 8192.f;
        float mL = sums1[c] * INVS2 * nrm;
        float vL = fmaxf(sums1[512 + c] * 0.5f * nrm - mL * mL, 0.f);
        float sL = bf2f(wc[OFF_G1 + c]) * rsqrtf(vL + EPSBN);
        float tL = bf2f(wc[OFF_BE1 + c]) - mL * sL;
        float mH = sums1[256 + c] * INVS2 * nrm;
        float vH = fmaxf(sums1[768 + c] * 0.5f * nrm - mH * mH, 0.f);
        float sH = bf2f(wc[OFF_G1 + 256 + c]) * rsqrtf(vH + EPSBN);
        float tH = bf2f(wc[OFF_BE1 + 256 + c]) - mH * sH;

        const signed char* plo = l1 + (((size_t)tb * 512) + c) * (H_ * Wh_);
        const signed char* phi = l1 + (((size_t)tb * 512) + 256 + c) * (H_ * Wh_);
        float slo = sL * INVS2, shi = sH * INVS2;
        sm.s2.lo[tid & 511] = 0.f;            // placate compiler aliasing; overwritten below
        {
            sm.s2.lo[tid]       = (float)plo[tid] * slo + tL;
            sm.s2.hi[tid]       = (float)phi[tid] * shi + tH;
            sm.s2.lo[tid + 256] = (float)plo[tid + 256] * slo + tL;
            sm.s2.hi[tid + 256] = (float)phi[tid + 256] * shi + tH;
        }
        __syncthreads();

        int w = tid & 15, v = tid >> 4;
        float a = sm.s2.lo[(2 * v) * Wh_ + w], b = sm.s2.lo[(2 * v + 1) * Wh_ + w];
        float zLL = (a + b) * INVS2;
        float zHL = (a - b) * INVS2;
        a = sm.s2.hi[(2 * v) * Wh_ + w]; b = sm.s2.hi[(2 * v + 1) * Wh_ + w];
        float zLH = (a + b) * INVS2;
        float zHH = (a - b) * INVS2;
        zLL = (fabsf(zLL) - 0.5f >= 0.f) ? zLL : 0.f;
        zHL = (fabsf(zHL) - 0.5f >= 0.f) ? zHL : 0.f;
        zLH = (fabsf(zLH) - 0.5f >= 0.f) ? zLH : 0.f;
        zHH = (fabsf(zHH) - 0.5f >= 0.f) ? zHH : 0.f;

        float r0 = zLL, r1 = zHL, r2 = zLH, r3 = zHH;
        float q0 = zLL * zLL, q1 = zHL * zHL, q2 = zLH * zLH, q3 = zHH * zHH;
        for (int o = 1; o < 64; o <<= 1) {
            r0 += __shfl_xor(r0, o, 64); r1 += __shfl_xor(r1, o, 64);
            r2 += __shfl_xor(r2, o, 64); r3 += __shfl_xor(r3, o, 64);
            q0 += __shfl_xor(q0, o, 64); q1 += __shfl_xor(q1, o, 64);
            q2 += __shfl_xor(q2, o, 64); q3 += __shfl_xor(q3, o, 64);
        }
        if (lane == 0) {
            sm.s2.part[wv][0] = r0; sm.s2.part[wv][1] = r1;
            sm.s2.part[wv][2] = r2; sm.s2.part[wv][3] = r3;
            sm.s2.part[wv][4] = q0; sm.s2.part[wv][5] = q1;
            sm.s2.part[wv][6] = q2; sm.s2.part[wv][7] = q3;
        }
        __syncthreads();
        float S0 = sm.s2.part[0][0] + sm.s2.part[1][0] + sm.s2.part[2][0] + sm.s2.part[3][0];
        float S1 = sm.s2.part[0][1] + sm.s2.part[1][1] + sm.s2.part[2][1] + sm.s2.part[3][1];
        float S2 = sm.s2.part[0][2] + sm.s2.part[1][2] + sm.s2.part[2][2] + sm.s2.part[3][2];
        float S3 = sm.s2.part[0][3] + sm.s2.part[1][3] + sm.s2.part[2][3] + sm.s2.part[3][3];
        float Q0 = sm.s2.part[0][4] + sm.s2.part[1][4] + sm.s2.part[2][4] + sm.s2.part[3][4];
        float Q1 = sm.s2.part[0][5] + sm.s2.part[1][5] + sm.s2.part[2][5] + sm.s2.part[3][5];
        float Q2 = sm.s2.part[0][6] + sm.s2.part[1][6] + sm.s2.part[2][6] + sm.s2.part[3][6];
        float Q3 = sm.s2.part[0][7] + sm.s2.part[1][7] + sm.s2.part[2][7] + sm.s2.part[3][7];
        float fLL = (Q0 * (1.f / 256.f) > 0.01f) ? 1.f : 0.f;
        float fHL = (Q1 * (1.f / 256.f) > 0.02f) ? 1.f : 0.f;
        float fLH = (Q2 * (1.f / 256.f) > 0.02f) ? 1.f : 0.f;
        float fHH = (Q3 * (1.f / 256.f) > 0.05f) ? 1.f : 0.f;

        float* sums2 = stats + 1024;
        if (tid < 8) {
            const int cho[8] = {0, 1024, 256, 1280, 512, 1536, 768, 1792};
            const float vals[8] = {fLL * S0, fLL * Q0, fHL * S1, fHL * Q1,
                                   fLH * S2, fLH * Q2, fHH * S3, fHH * Q3};
            atomicAdd(&sums2[cho[tid] + c], vals[tid]);
        }

        size_t ob = (((size_t)tb * 1024) + c) * 256 + tid;
        l2[ob]               = __float2bfloat16(zLL * fLL);
        l2[ob + 256u * 256u] = __float2bfloat16(zHL * fHL);
        l2[ob + 512u * 256u] = __float2bfloat16(zLH * fLH);
        l2[ob + 768u * 256u] = __float2bfloat16(zHH * fHH);
    }
}

// ---------------------------------------------------------------------------
// Fused BN2-apply + block channel matmul + inverse Haar -> rec bf16;
// accumulates BN3 raw sums.
// ---------------------------------------------------------------------------
__global__ __launch_bounds__(256) void k_mixinv(const __hip_bfloat16* __restrict__ l2,
                                                const __hip_bfloat16* __restrict__ wc,
                                                float* __restrict__ stats,
                                                __hip_bfloat16* __restrict__ rec) {
    int bid = blockIdx.x;                 // 256 = tb(16) * cg(16)
    int cg = bid & 15;
    int tb = bid >> 4;
    int tid = threadIdx.x;
    int lane = tid & 63, wvv = tid >> 6;
    const float* sums2 = stats + 1024;

    __shared__ float wt[4][16][16];       // [q][d][k]
    __shared__ float bsc[64], bsh[64];
    __shared__ float parts2[4][32];
    for (int i = tid; i < 1024; i += 256) {
        int q = i >> 8, rem = i & 255, d = rem >> 4, k = rem & 15;
        int nb = q * 4 + (cg >> 2);
        wt[q][d][k] = bf2f(wc[OFF_HW + nb * 256 + d * 16 + k]);
    }
    if (tid < 64) {
        int q = tid >> 4, d = tid & 15;
        int ch = q * 256 + cg * 16 + d;
        float m = sums2[ch] * (1.f / 4096.f);
        float var = fmaxf(sums2[1024 + ch] * (1.f / 4096.f) - m * m, 0.f);
        float sc = bf2f(wc[OFF_G2 + ch]) * rsqrtf(var + EPSBN);
        bsc[tid] = sc;
        bsh[tid] = bf2f(wc[OFF_BE2 + ch]) - m * sc;
    }
    __syncthreads();

    float h[4][16];
    #pragma unroll
    for (int q = 0; q < 4; ++q)
        #pragma unroll
        for (int k = 0; k < 16; ++k) h[q][k] = 0.f;

    int p = tid;
    #pragma unroll
    for (int q = 0; q < 4; ++q) {
        const __hip_bfloat16* base =
            l2 + ((size_t)tb * 1024 + q * 256 + cg * 16) * 256 + p;
        #pragma unroll
        for (int d = 0; d < 16; ++d) {
            float xv = bf2f(base[d * 256]) * bsc[q * 16 + d] + bsh[q * 16 + d];
            #pragma unroll
            for (int k = 0; k < 16; ++k)
                h[q][k] = fmaf(xv, wt[q][d][k], h[q][k]);
        }
    }

    int uh = tid >> 4, uw = tid & 15;
    __hip_bfloat16* ob = rec + ((size_t)tb * 256 + cg * 16) * 1024;
    float sk[16], qk[16];
    #pragma unroll
    for (int k = 0; k < 16; ++k) {
        float LL = h[0][k], HL = h[1][k], LH = h[2][k], HH = h[3][k];
        float v00 = 0.5f * (LL + HL + LH + HH);
        float v01 = 0.5f * (LL + HL - LH - HH);
        float v10 = 0.5f * (LL - HL + LH - HH);
        float v11 = 0.5f * (LL - HL - LH + HH);
        __hip_bfloat162 top, bot;
        top.x = __float2bfloat16(v00); top.y = __float2bfloat16(v01);
        bot.x = __float2bfloat16(v10); bot.y = __float2bfloat16(v11);
        *(__hip_bfloat162*)(ob + (size_t)k * 1024 + (2 * uh) * 32 + 2 * uw) = top;
        *(__hip_bfloat162*)(ob + (size_t)k * 1024 + (2 * uh + 1) * 32 + 2 * uw) = bot;
        sk[k] = v00 + v01 + v10 + v11;
        qk[k] = v00 * v00 + v01 * v01 + v10 * v10 + v11 * v11;
    }
    for (int o = 1; o < 64; o <<= 1) {
        #pragma unroll
        for (int k = 0; k < 16; ++k) {
            sk[k] += __shfl_xor(sk[k], o, 64);
            qk[k] += __shfl_xor(qk[k], o, 64);
        }
    }
    if (lane == 0) {
        #pragma unroll
        for (int k = 0; k < 16; ++k) {
            parts2[wvv][k * 2]     = sk[k];
            parts2[wvv][k * 2 + 1] = qk[k];
        }
    }
    __syncthreads();
    if (tid < 32) {
        int k = tid >> 1, which = tid & 1;
        float tot = parts2[0][tid] + parts2[1][tid] + parts2[2][tid] + parts2[3][tid];
        atomicAdd(&stats[3072 + which * 256 + cg * 16 + k], tot);
    }
}

// ---------------------------------------------------------------------------
// k_final2: per-image (tb, nb) block. Recomputes both convs via MFMA from the
// 4 MB spike array (c1/c2 never touch HBM), reads rec, applies BN3/4/5, and
// writes the output.
// ---------------------------------------------------------------------------
struct FinSh {
    short lo[1025 * 8];
    short hi[1025 * 8];
    unsigned short w2s[2304];
    unsigned short w1s[256];
    unsigned short bs[32];
    float sc3[16], sc4[16], sc5[16], shS[16];
};

__global__ __launch_bounds__(256) void k_final2(const unsigned char* __restrict__ s,
                                                const __hip_bfloat16* __restrict__ rec,
                                                const float* __restrict__ stats,
                                                const __hip_bfloat16* __restrict__ wc,
                                                const int* __restrict__ flag,
                                                void* __restrict__ out_) {
    __shared__ FinSh sm;
    int img = blockIdx.x;                 // 256 = tb(16) * nb(16)
    int tid = threadIdx.x;
    int lane = tid & 63, wv = tid >> 6;

    const unsigned short* wr = (const unsigned short*)wc;
    for (int i = tid; i < 2304; i += 256) sm.w2s[i] = wr[OFF_W2 + i];
    sm.w1s[tid] = wr[OFF_W1 + tid];
    if (tid < 16) { sm.bs[tid] = wr[OFF_B1 + tid]; sm.bs[16 + tid] = wr[OFF_B2 + tid]; }
    if (tid < 8) {
        ((unsigned int*)sm.lo)[4096 + (tid & 3)] = 0;
        ((unsigned int*)sm.hi)[4096 + (tid & 3)] = 0;
    }
    // BN3/4/5 coefficients for this block's 16 channels
    if (tid >= 32 && tid < 48) {
        int k = tid - 32;
        int c = (img & 15) * 16 + k;
        const float inv = 1.f / 16384.f;
        float m3 = stats[3072 + c] * inv;
        float v3 = fmaxf(stats[3328 + c] * inv - m3 * m3, 0.f);
        float sc3 = bf2f(wc[OFF_G3 + c]) * rsqrtf(v3 + EPSBN);
        float sh3 = bf2f(wc[OFF_BE3 + c]) - m3 * sc3;
        float m4 = stats[3584 + c] * inv;
        float v4 = fmaxf(stats[3840 + c] * inv - m4 * m4, 0.f);
        float sc4 = bf2f(wc[OFF_G4 + c]) * rsqrtf(v4 + EPSBN);
        float sh4 = bf2f(wc[OFF_BE4 + c]) - m4 * sc4;
        float m5 = stats[4096 + c] * inv;
        float v5 = fmaxf(stats[4352 + c] * inv - m5 * m5, 0.f);
        float sc5 = bf2f(wc[OFF_G5 + c]) * rsqrtf(v5 + EPSBN);
        float sh5 = bf2f(wc[OFF_BE5 + c]) - m5 * sc5;
        sm.sc3[k] = sc3;
        sm.sc4[k] = sc4;
        sm.sc5[k] = sc5;
        sm.shS[k] = sh3 + sh4 + sh5;
    }
    // stage planar u8 -> LDS channel-last bf16
    {
        const unsigned int* sp = (const unsigned int*)(s + (size_t)img * 16384);
        int d2 = tid >> 5;
        int pg = tid & 31;
        unsigned int* dst = (unsigned int*)((d2 < 4) ? sm.lo : sm.hi);
        int dl = d2 & 3;
        #pragma unroll
        for (int p = 0; p < 8; ++p) {
            int base = p * 32 + pg;
            unsigned int u0 = sp[d2 * 512 + base];
            unsigned int u1 = sp[d2 * 512 + 256 + base];
            #pragma unroll
            for (int jj = 0; jj < 4; ++jj) {
                int j = (jj + pg) & 3;
                unsigned int b0 = (u0 >> (8 * j)) & 255u;
                unsigned int b1 = (u1 >> (8 * j)) & 255u;
                unsigned int val = (b0 ? 0x3F80u : 0u) | ((b1 ? 0x3F80u : 0u) << 16);
                int pix = p * 128 + pg * 4 + j;
                dst[pix * 4 + dl] = val;
            }
        }
    }
    __syncthreads();

    int m = lane & 15;
    int g = lane >> 4;
    const int tapA[5] = {0, 2, 4, 6, 8};
    const int tapB[5] = {1, 3, 5, 7, 8};

    short8 afr[5], a1f;
    #pragma unroll
    for (int p = 0; p < 5; ++p) {
        int tap = (g < 2) ? tapA[p] : tapB[p];
        short8 av;
        #pragma unroll
        for (int j = 0; j < 8; ++j) {
            int d = (g & 1) * 8 + j;
            unsigned short w = sm.w2s[m * 144 + d * 9 + tap];
            if (p == 4 && g >= 2) w = 0;
            av[j] = (short)w;
        }
        afr[p] = av;
    }
    #pragma unroll
    for (int j = 0; j < 8; ++j) {
        int d = (g & 1) * 8 + j;
        a1f[j] = (g < 2) ? (short)sm.w1s[m * 16 + d] : (short)0;
    }
    float bias1[4], bias2[4], c3[4], c4[4], c5[4], cS[4];
    #pragma unroll
    for (int r = 0; r < 4; ++r) {
        int k = g * 4 + r;
        bias1[r] = bfu(sm.bs[k]);
        bias2[r] = bfu(sm.bs[16 + k]);
        c3[r] = sm.sc3[k];
        c4[r] = sm.sc4[k];
        c5[r] = sm.sc5[k];
        cS[r] = sm.shS[k];
    }

    const short* bsrc = (g & 1) ? sm.hi : sm.lo;
    const __hip_bfloat16* rb = rec + (size_t)img * 16384;
    int f = *flag;
    float* of = (float*)out_;
    __hip_bfloat16* ob = (__hip_bfloat16*)out_;
    size_t obase = (size_t)img * 16384;

    for (int t = wv * 16; t < wv * 16 + 16; ++t) {
        int hh = t >> 1;
        int w0 = (t & 1) << 4;
        f32x4 acc2 = {0.f, 0.f, 0.f, 0.f};
        f32x4 acc1 = {0.f, 0.f, 0.f, 0.f};
        #pragma unroll
        for (int p = 0; p < 5; ++p) {
            int tap = (g < 2) ? tapA[p] : tapB[p];
            int row = hh + tap / 3 - 1;
            int col = w0 + m + (tap % 3) - 1;
            bool ok = ((unsigned)row < 32u) && ((unsigned)col < 32u);
            int idx = ok ? (row * 32 + col) : 1024;
            short8 bv = *(const short8*)&bsrc[idx * 8];
            acc2 = __builtin_amdgcn_mfma_f32_16x16x32_bf16(afr[p], bv, acc2, 0, 0, 0);
            if (p == 2)
                acc1 = __builtin_amdgcn_mfma_f32_16x16x32_bf16(a1f, bv, acc1, 0, 0, 0);
        }
        int pix = hh * 32 + w0 + m;
        #pragma unroll
        for (int r = 0; r < 4; ++r) {
            int k = g * 4 + r;
            float y1 = acc1[r] + bias1[r];
            float y2 = acc2[r] + bias2[r];
            float rv = bf2f(rb[(size_t)k * 1024 + pix]);
            float o = rv * c3[r] + y1 * c4[r] + y2 * c5[r] + cS[r];
            size_t oi = obase + (size_t)k * 1024 + pix;
            if (f) of[oi] = o;
            else   ob[oi] = __float2bfloat16(o);
        }
    }
}

// ---------------------------------------------------------------------------
// Workspace map:
//   [0,4M):   s (planar u8 spikes)      [4,8M):  l1 (i8 codes)
//   [8,16M):  l2                        [16,24M): rec
//   [40M..):  weight arena, stats(4608 fl), flag
// c1/c2 live only in registers (stats in k_work, recompute in k_final2).
// ---------------------------------------------------------------------------
extern "C" void kernel_launch(void* const* d_in, const int* in_sizes, int n_in,
                              void* d_out, int out_size, void* d_ws, size_t ws_size,
                              hipStream_t stream) {
    char* ws = (char*)d_ws;
    unsigned char* s_u8  = (unsigned char*)ws;
    signed char* l1c     = (signed char*)(ws + ((size_t)4 << 20));
    __hip_bfloat16* l2   = (__hip_bfloat16*)(ws + ((size_t)8 << 20));
    __hip_bfloat16* rec  = (__hip_bfloat16*)(ws + ((size_t)16 << 20));
    __hip_bfloat16* wc   = (__hip_bfloat16*)(ws + ((size_t)40 << 20));
    float* stats         = (float*)(ws + ((size_t)40 << 20) + (64 << 10));
    int* flag            = (int*)(ws + ((size_t)40 << 20) + (128 << 10));

    WPtrs wp;
    for (int i = 0; i < 15; ++i) wp.p[i] = d_in[i + 1];

    dim3 blk(256);
    k_prep<<<dim3(45), blk, 0, stream>>>((const unsigned short*)d_in[0], wp, wc, stats, flag);
    k_lifhaar<<<dim3(2048), blk, 0, stream>>>(d_in[0], flag, s_u8, l1c, stats);
    k_work<<<dim3(4352), blk, 0, stream>>>(s_u8, l1c, stats, wc, stats, l2);
    k_mixinv<<<dim3(256), blk, 0, stream>>>(l2, wc, stats, rec);
    k_final2<<<dim3(256), blk, 0, stream>>>(s_u8, rec, stats, wc, flag, d_out);
}

// Round 3
// 152.259 us; speedup vs baseline: 1.0482x; 1.0482x over previous
//
#include <hip/hip_runtime.h>
#include <hip/hip_bf16.h>

#define T_ 4
#define B_ 4
#define C_ 256
#define H_ 32
#define W_ 32
#define TB_ 16
#define Hh_ 16
#define Wh_ 16
#define INVS2 0.70710678118654752440f
#define EPSBN 1e-5f

// Canonical weight arena offsets (bf16 elements)
#define OFF_HW   0
#define OFF_W1   4096
#define OFF_B1   4352
#define OFF_W2   4368
#define OFF_B2   6672
#define OFF_G1   6688
#define OFF_BE1  7200
#define OFF_G2   7712
#define OFF_BE2  8736
#define OFF_G3   9760
#define OFF_BE3  10016
#define OFF_G4   10272
#define OFF_BE4  10528
#define OFF_G5   10784
#define OFF_BE5  11040
#define W_TOTAL  11296
// stats arena (floats): sums1[1024] | sums2[2048] | sums345[1536]
#define NSUMS    4608

struct WPtrs { const void* p[15]; };

typedef __attribute__((ext_vector_type(8))) short short8;
typedef __attribute__((ext_vector_type(4))) float f32x4;

__device__ inline float bf2f(__hip_bfloat16 v) { return __bfloat162float(v); }
__device__ inline float bfu(unsigned short u) { return __uint_as_float((unsigned)u << 16); }

// ---------------------------------------------------------------------------
// k_prep: per-block self-sniff (fp32 vs bf16), convert weights to bf16 arena,
// zero the raw-sums region; block 0 publishes the flag for later kernels.
// ---------------------------------------------------------------------------
__global__ __launch_bounds__(256) void k_prep(const unsigned short* __restrict__ xr,
                                              WPtrs wp,
                                              __hip_bfloat16* __restrict__ wc,
                                              float* __restrict__ sums,
                                              int* __restrict__ flag) {
    int tid = threadIdx.x;
    int cnt = 0;
    for (int i = tid; i < 2048; i += 256) {
        int e = (xr[i] >> 7) & 0xFF;
        if (e >= 134) cnt++;
    }
    for (int o = 1; o < 64; o <<= 1) cnt += __shfl_xor(cnt, o, 64);
    __shared__ int sh[4];
    if ((tid & 63) == 0) sh[tid >> 6] = cnt;
    __syncthreads();
    int f = (sh[0] + sh[1] + sh[2] + sh[3] >= 32) ? 1 : 0;
    if (blockIdx.x == 0 && tid == 0) *flag = f;

    const int sizes[15] = {4096, 256, 16, 2304, 16, 512, 512, 1024, 1024,
                           256, 256, 256, 256, 256, 256};
    int i = blockIdx.x * 256 + tid;
    if (i < W_TOTAL) {
        int seg = 0, off = 0;
        while (i >= off + sizes[seg]) { off += sizes[seg]; seg++; }
        int j = i - off;
        float v = f ? ((const float*)wp.p[seg])[j]
                    : bf2f(((const __hip_bfloat16*)wp.p[seg])[j]);
        wc[i] = __float2bfloat16(v);
    }
    if (i < NSUMS) sums[i] = 0.f;
}

// ---------------------------------------------------------------------------
// Fused LIF + Haar-W. Planar coalesced u8 spikes + i8 Haar codes + BN1 sums.
// Block = (b, c, half); thread = (row-in-half, w-pair).
// ---------------------------------------------------------------------------
__global__ __launch_bounds__(256) void k_lifhaar(const void* __restrict__ x_,
                                                 const int* __restrict__ flag,
                                                 unsigned char* __restrict__ s,
                                                 signed char* __restrict__ l1,
                                                 float* __restrict__ sums1) {
    int bid = blockIdx.x;                      // 2048 = b(4) * c(256) * half(2)
    int tid = threadIdx.x;
    int half = bid & 1;
    int c = (bid >> 1) & 255;
    int b = bid >> 9;
    int wp = tid & 15;
    int hl = tid >> 4;
    int h = half * 16 + hl;
    int f = *flag;
    const float* xf = (const float*)x_;
    const unsigned int* xb = (const unsigned int*)x_;
    int n = ((b * 256 + c) * 32 + h) * 32 + 2 * wp;

    float v0 = 0.f, v1 = 0.f;
    float aL = 0.f, qL = 0.f, aH = 0.f, qH = 0.f;
    #pragma unroll
    for (int t = 0; t < T_; ++t) {
        size_t idx = (size_t)t * 1048576 + n;
        float x0, x1;
        if (f) {
            float2 xx = *(const float2*)(xf + idx);
            x0 = xx.x; x1 = xx.y;
        } else {
            unsigned int u = xb[idx >> 1];
            x0 = __uint_as_float(u << 16);
            x1 = __uint_as_float(u & 0xffff0000u);
        }
        v0 += (x0 - v0) * 0.5f;
        v1 += (x1 - v1) * 0.5f;
        float s0 = (v0 >= 1.f) ? 1.f : 0.f;
        float s1 = (v1 >= 1.f) ? 1.f : 0.f;
        v0 *= (1.f - s0);
        v1 *= (1.f - s1);
        int tb = t * 4 + b;
        ((uchar2*)s)[(size_t)(tb * 256 + c) * 512 + h * 16 + wp] =
            make_uchar2((unsigned char)s0, (unsigned char)s1);
        float cl = s0 + s1, ch = s0 - s1;
        size_t lb = (((size_t)tb * 512 + c) * 32 + h) * 16 + wp;
        l1[lb] = (signed char)(int)cl;
        l1[lb + (size_t)256 * 512] = (signed char)(int)ch;
        aL += cl; qL += cl * cl; aH += ch; qH += ch * ch;
    }
    for (int o = 1; o < 64; o <<= 1) {
        aL += __shfl_xor(aL, o, 64); qL += __shfl_xor(qL, o, 64);
        aH += __shfl_xor(aH, o, 64); qH += __shfl_xor(qH, o, 64);
    }
    __shared__ float part[4][4];
    int lane = tid & 63, wv = tid >> 6;
    if (lane == 0) {
        part[wv][0] = aL; part[wv][1] = qL; part[wv][2] = aH; part[wv][3] = qH;
    }
    __syncthreads();
    if (tid < 4) {
        float tot = part[0][tid] + part[1][tid] + part[2][tid] + part[3][tid];
        const int offs[4] = {0, 512, 256, 768};
        atomicAdd(&sums1[offs[tid] + c], tot);
    }
}

// ---------------------------------------------------------------------------
// Fused k_work: bids [0,256) = conv STATS role (MFMA implicit GEMM, BN4/5
// sum accumulation only — no c1/c2 stores); bids [256,4352) = stage2 role
// (BN1-apply + Haar-H + gates -> l2, BN2 sum accumulation).
// ---------------------------------------------------------------------------
struct SharedU {
    union {
        struct {
            short lo[1025 * 8];            // channel-last bf16, d 0..7 (+zero row)
            short hi[1025 * 8];            // d 8..15
            unsigned short w2s[2304];      // [k][d*9+tap]
            unsigned short w1s[256];       // [k][d]
            unsigned short bs[32];         // B1 | B2
            float parts[4][4][16];         // [wv][g][r*4+which]
        } cv;
        struct {
            float lo[512];
            float hi[512];
            float part[4][8];
        } s2;
    };
};

__global__ __launch_bounds__(256) void k_work(const unsigned char* __restrict__ s,
                                              const signed char* __restrict__ l1,
                                              const float* __restrict__ sums1,
                                              const __hip_bfloat16* __restrict__ wc,
                                              float* __restrict__ stats,
                                              __hip_bfloat16* __restrict__ l2) {
    __shared__ SharedU sm;
    int bid = blockIdx.x;
    int tid = threadIdx.x;
    int lane = tid & 63, wv = tid >> 6;

    if (bid < 256) {
        // ------------------------------ conv stats role ------------------------------
        int img = bid;
        const unsigned short* wr = (const unsigned short*)wc;
        for (int i = tid; i < 2304; i += 256) sm.cv.w2s[i] = wr[OFF_W2 + i];
        sm.cv.w1s[tid] = wr[OFF_W1 + tid];
        if (tid < 16) { sm.cv.bs[tid] = wr[OFF_B1 + tid]; sm.cv.bs[16 + tid] = wr[OFF_B2 + tid]; }
        // zero row (pixel index 1024)
        if (tid < 8) {
            ((unsigned int*)sm.cv.lo)[4096 + (tid & 3)] = 0;
            ((unsigned int*)sm.cv.hi)[4096 + (tid & 3)] = 0;
        }
        // stage planar u8 -> LDS channel-last bf16
        {
            const unsigned int* sp = (const unsigned int*)(s + (size_t)img * 16384);
            int d2 = tid >> 5;               // channel pair 2*d2, 2*d2+1
            int pg = tid & 31;
            unsigned int* dst = (unsigned int*)((d2 < 4) ? sm.cv.lo : sm.cv.hi);
            int dl = d2 & 3;
            #pragma unroll
            for (int p = 0; p < 8; ++p) {
                int base = p * 32 + pg;      // dword index within a channel row
                unsigned int u0 = sp[d2 * 512 + base];
                unsigned int u1 = sp[d2 * 512 + 256 + base];
                #pragma unroll
                for (int jj = 0; jj < 4; ++jj) {
                    int j = (jj + pg) & 3;   // scramble to spread LDS banks
                    unsigned int b0 = (u0 >> (8 * j)) & 255u;
                    unsigned int b1 = (u1 >> (8 * j)) & 255u;
                    unsigned int val = (b0 ? 0x3F80u : 0u) | ((b1 ? 0x3F80u : 0u) << 16);
                    int pix = p * 128 + pg * 4 + j;
                    dst[pix * 4 + dl] = val;
                }
            }
        }
        __syncthreads();

        int m = lane & 15;
        int g = lane >> 4;
        const int tapA[5] = {0, 2, 4, 6, 8};
        const int tapB[5] = {1, 3, 5, 7, 8};

        short8 afr[5], a1f;
        #pragma unroll
        for (int p = 0; p < 5; ++p) {
            int tap = (g < 2) ? tapA[p] : tapB[p];
            short8 av;
            #pragma unroll
            for (int j = 0; j < 8; ++j) {
                int d = (g & 1) * 8 + j;
                unsigned short w = sm.cv.w2s[m * 144 + d * 9 + tap];
                if (p == 4 && g >= 2) w = 0;
                av[j] = (short)w;
            }
            afr[p] = av;
        }
        #pragma unroll
        for (int j = 0; j < 8; ++j) {
            int d = (g & 1) * 8 + j;
            a1f[j] = (g < 2) ? (short)sm.cv.w1s[m * 16 + d] : (short)0;
        }
        float bias1[4], bias2[4];
        #pragma unroll
        for (int r = 0; r < 4; ++r) {
            bias1[r] = bfu(sm.cv.bs[g * 4 + r]);
            bias2[r] = bfu(sm.cv.bs[16 + g * 4 + r]);
        }

        const short* bsrc = (g & 1) ? sm.cv.hi : sm.cv.lo;

        float cs1[4] = {0, 0, 0, 0}, cq1[4] = {0, 0, 0, 0};
        float cs2[4] = {0, 0, 0, 0}, cq2[4] = {0, 0, 0, 0};

        for (int t = wv * 16; t < wv * 16 + 16; ++t) {
            int h = t >> 1;
            int w0 = (t & 1) << 4;
            f32x4 acc2 = {0.f, 0.f, 0.f, 0.f};
            f32x4 acc1 = {0.f, 0.f, 0.f, 0.f};
            #pragma unroll
            for (int p = 0; p < 5; ++p) {
                int tap = (g < 2) ? tapA[p] : tapB[p];
                int row = h + tap / 3 - 1;
                int col = w0 + m + (tap % 3) - 1;
                bool ok = ((unsigned)row < 32u) && ((unsigned)col < 32u);
                int idx = ok ? (row * 32 + col) : 1024;
                short8 bv = *(const short8*)&bsrc[idx * 8];
                acc2 = __builtin_amdgcn_mfma_f32_16x16x32_bf16(afr[p], bv, acc2, 0, 0, 0);
                if (p == 2)
                    acc1 = __builtin_amdgcn_mfma_f32_16x16x32_bf16(a1f, bv, acc1, 0, 0, 0);
            }
            #pragma unroll
            for (int r = 0; r < 4; ++r) {
                float y1 = acc1[r] + bias1[r];
                float y2 = acc2[r] + bias2[r];
                cs1[r] += y1; cq1[r] += y1 * y1;
                cs2[r] += y2; cq2[r] += y2 * y2;
            }
        }
        // reduce across the 16 m-lanes (same g)
        #pragma unroll
        for (int o = 1; o < 16; o <<= 1) {
            #pragma unroll
            for (int r = 0; r < 4; ++r) {
                cs1[r] += __shfl_xor(cs1[r], o, 64);
                cq1[r] += __shfl_xor(cq1[r], o, 64);
                cs2[r] += __shfl_xor(cs2[r], o, 64);
                cq2[r] += __shfl_xor(cq2[r], o, 64);
            }
        }
        if (m == 0) {
            #pragma unroll
            for (int r = 0; r < 4; ++r) {
                sm.cv.parts[wv][g][r * 4 + 0] = cs1[r];
                sm.cv.parts[wv][g][r * 4 + 1] = cq1[r];
                sm.cv.parts[wv][g][r * 4 + 2] = cs2[r];
                sm.cv.parts[wv][g][r * 4 + 3] = cq2[r];
            }
        }
        __syncthreads();
        if (tid < 64) {
            int gg = tid >> 4, r = (tid >> 2) & 3, which = tid & 3;
            float tot = sm.cv.parts[0][gg][r * 4 + which] + sm.cv.parts[1][gg][r * 4 + which]
                      + sm.cv.parts[2][gg][r * 4 + which] + sm.cv.parts[3][gg][r * 4 + which];
            int ch = (img & 15) * 16 + gg * 4 + r;   // global BN channel
            // stats: sums4_sum@3584 sums4_sq@3840 sums5_sum@4096 sums5_sq@4352
            const int base[4] = {3584, 3840, 4096, 4352};
            atomicAdd(&stats[base[which] + ch], tot);
        }
    } else {
        // ------------------------------ stage2 role ------------------------------
        int blk = bid - 256;                  // TB*C = 4096
        int c = blk & 255;
        int tb = blk >> 8;

        const float nrm = 1.f / 8192.f;
        float mL = sums1[c] * INVS2 * nrm;
        float vL = fmaxf(sums1[512 + c] * 0.5f * nrm - mL * mL, 0.f);
        float sL = bf2f(wc[OFF_G1 + c]) * rsqrtf(vL + EPSBN);
        float tL = bf2f(wc[OFF_BE1 + c]) - mL * sL;
        float mH = sums1[256 + c] * INVS2 * nrm;
        float vH = fmaxf(sums1[768 + c] * 0.5f * nrm - mH * mH, 0.f);
        float sH = bf2f(wc[OFF_G1 + 256 + c]) * rsqrtf(vH + EPSBN);
        float tH = bf2f(wc[OFF_BE1 + 256 + c]) - mH * sH;

        const signed char* plo = l1 + (((size_t)tb * 512) + c) * (H_ * Wh_);
        const signed char* phi = l1 + (((size_t)tb * 512) + 256 + c) * (H_ * Wh_);
        float slo = sL * INVS2, shi = sH * INVS2;
        sm.s2.lo[tid & 511] = 0.f;            // placate compiler aliasing; overwritten below
        {
            sm.s2.lo[tid]       = (float)plo[tid] * slo + tL;
            sm.s2.hi[tid]       = (float)phi[tid] * shi + tH;
            sm.s2.lo[tid + 256] = (float)plo[tid + 256] * slo + tL;
            sm.s2.hi[tid + 256] = (float)phi[tid + 256] * shi + tH;
        }
        __syncthreads();

        int w = tid & 15, v = tid >> 4;
        float a = sm.s2.lo[(2 * v) * Wh_ + w], b = sm.s2.lo[(2 * v + 1) * Wh_ + w];
        float zLL = (a + b) * INVS2;
        float zHL = (a - b) * INVS2;
        a = sm.s2.hi[(2 * v) * Wh_ + w]; b = sm.s2.hi[(2 * v + 1) * Wh_ + w];
        float zLH = (a + b) * INVS2;
        float zHH = (a - b) * INVS2;
        zLL = (fabsf(zLL) - 0.5f >= 0.f) ? zLL : 0.f;
        zHL = (fabsf(zHL) - 0.5f >= 0.f) ? zHL : 0.f;
        zLH = (fabsf(zLH) - 0.5f >= 0.f) ? zLH : 0.f;
        zHH = (fabsf(zHH) - 0.5f >= 0.f) ? zHH : 0.f;

        float r0 = zLL, r1 = zHL, r2 = zLH, r3 = zHH;
        float q0 = zLL * zLL, q1 = zHL * zHL, q2 = zLH * zLH, q3 = zHH * zHH;
        for (int o = 1; o < 64; o <<= 1) {
            r0 += __shfl_xor(r0, o, 64); r1 += __shfl_xor(r1, o, 64);
            r2 += __shfl_xor(r2, o, 64); r3 += __shfl_xor(r3, o, 64);
            q0 += __shfl_xor(q0, o, 64); q1 += __shfl_xor(q1, o, 64);
            q2 += __shfl_xor(q2, o, 64); q3 += __shfl_xor(q3, o, 64);
        }
        if (lane == 0) {
            sm.s2.part[wv][0] = r0; sm.s2.part[wv][1] = r1;
            sm.s2.part[wv][2] = r2; sm.s2.part[wv][3] = r3;
            sm.s2.part[wv][4] = q0; sm.s2.part[wv][5] = q1;
            sm.s2.part[wv][6] = q2; sm.s2.part[wv][7] = q3;
        }
        __syncthreads();
        float S0 = sm.s2.part[0][0] + sm.s2.part[1][0] + sm.s2.part[2][0] + sm.s2.part[3][0];
        float S1 = sm.s2.part[0][1] + sm.s2.part[1][1] + sm.s2.part[2][1] + sm.s2.part[3][1];
        float S2 = sm.s2.part[0][2] + sm.s2.part[1][2] + sm.s2.part[2][2] + sm.s2.part[3][2];
        float S3 = sm.s2.part[0][3] + sm.s2.part[1][3] + sm.s2.part[2][3] + sm.s2.part[3][3];
        float Q0 = sm.s2.part[0][4] + sm.s2.part[1][4] + sm.s2.part[2][4] + sm.s2.part[3][4];
        float Q1 = sm.s2.part[0][5] + sm.s2.part[1][5] + sm.s2.part[2][5] + sm.s2.part[3][5];
        float Q2 = sm.s2.part[0][6] + sm.s2.part[1][6] + sm.s2.part[2][6] + sm.s2.part[3][6];
        float Q3 = sm.s2.part[0][7] + sm.s2.part[1][7] + sm.s2.part[2][7] + sm.s2.part[3][7];
        float fLL = (Q0 * (1.f / 256.f) > 0.01f) ? 1.f : 0.f;
        float fHL = (Q1 * (1.f / 256.f) > 0.02f) ? 1.f : 0.f;
        float fLH = (Q2 * (1.f / 256.f) > 0.02f) ? 1.f : 0.f;
        float fHH = (Q3 * (1.f / 256.f) > 0.05f) ? 1.f : 0.f;

        float* sums2 = stats + 1024;
        if (tid < 8) {
            const int cho[8] = {0, 1024, 256, 1280, 512, 1536, 768, 1792};
            const float vals[8] = {fLL * S0, fLL * Q0, fHL * S1, fHL * Q1,
                                   fLH * S2, fLH * Q2, fHH * S3, fHH * Q3};
            atomicAdd(&sums2[cho[tid] + c], vals[tid]);
        }

        size_t ob = (((size_t)tb * 1024) + c) * 256 + tid;
        l2[ob]               = __float2bfloat16(zLL * fLL);
        l2[ob + 256u * 256u] = __float2bfloat16(zHL * fHL);
        l2[ob + 512u * 256u] = __float2bfloat16(zLH * fLH);
        l2[ob + 768u * 256u] = __float2bfloat16(zHH * fHH);
    }
}

// ---------------------------------------------------------------------------
// Fused BN2-apply + block channel matmul + inverse Haar -> rec bf16;
// accumulates BN3 raw sums.
// ---------------------------------------------------------------------------
__global__ __launch_bounds__(256) void k_mixinv(const __hip_bfloat16* __restrict__ l2,
                                                const __hip_bfloat16* __restrict__ wc,
                                                float* __restrict__ stats,
                                                __hip_bfloat16* __restrict__ rec) {
    int bid = blockIdx.x;                 // 256 = tb(16) * cg(16)
    int cg = bid & 15;
    int tb = bid >> 4;
    int tid = threadIdx.x;
    int lane = tid & 63, wvv = tid >> 6;
    const float* sums2 = stats + 1024;

    __shared__ float wt[4][16][16];       // [q][d][k]
    __shared__ float bsc[64], bsh[64];
    __shared__ float parts2[4][32];
    for (int i = tid; i < 1024; i += 256) {
        int q = i >> 8, rem = i & 255, d = rem >> 4, k = rem & 15;
        int nb = q * 4 + (cg >> 2);
        wt[q][d][k] = bf2f(wc[OFF_HW + nb * 256 + d * 16 + k]);
    }
    if (tid < 64) {
        int q = tid >> 4, d = tid & 15;
        int ch = q * 256 + cg * 16 + d;
        float m = sums2[ch] * (1.f / 4096.f);
        float var = fmaxf(sums2[1024 + ch] * (1.f / 4096.f) - m * m, 0.f);
        float sc = bf2f(wc[OFF_G2 + ch]) * rsqrtf(var + EPSBN);
        bsc[tid] = sc;
        bsh[tid] = bf2f(wc[OFF_BE2 + ch]) - m * sc;
    }
    __syncthreads();

    float h[4][16];
    #pragma unroll
    for (int q = 0; q < 4; ++q)
        #pragma unroll
        for (int k = 0; k < 16; ++k) h[q][k] = 0.f;

    int p = tid;
    #pragma unroll
    for (int q = 0; q < 4; ++q) {
        const __hip_bfloat16* base =
            l2 + ((size_t)tb * 1024 + q * 256 + cg * 16) * 256 + p;
        #pragma unroll
        for (int d = 0; d < 16; ++d) {
            float xv = bf2f(base[d * 256]) * bsc[q * 16 + d] + bsh[q * 16 + d];
            #pragma unroll
            for (int k = 0; k < 16; ++k)
                h[q][k] = fmaf(xv, wt[q][d][k], h[q][k]);
        }
    }

    int uh = tid >> 4, uw = tid & 15;
    __hip_bfloat16* ob = rec + ((size_t)tb * 256 + cg * 16) * 1024;
    float sk[16], qk[16];
    #pragma unroll
    for (int k = 0; k < 16; ++k) {
        float LL = h[0][k], HL = h[1][k], LH = h[2][k], HH = h[3][k];
        float v00 = 0.5f * (LL + HL + LH + HH);
        float v01 = 0.5f * (LL + HL - LH - HH);
        float v10 = 0.5f * (LL - HL + LH - HH);
        float v11 = 0.5f * (LL - HL - LH + HH);
        __hip_bfloat162 top, bot;
        top.x = __float2bfloat16(v00); top.y = __float2bfloat16(v01);
        bot.x = __float2bfloat16(v10); bot.y = __float2bfloat16(v11);
        *(__hip_bfloat162*)(ob + (size_t)k * 1024 + (2 * uh) * 32 + 2 * uw) = top;
        *(__hip_bfloat162*)(ob + (size_t)k * 1024 + (2 * uh + 1) * 32 + 2 * uw) = bot;
        sk[k] = v00 + v01 + v10 + v11;
        qk[k] = v00 * v00 + v01 * v01 + v10 * v10 + v11 * v11;
    }
    for (int o = 1; o < 64; o <<= 1) {
        #pragma unroll
        for (int k = 0; k < 16; ++k) {
            sk[k] += __shfl_xor(sk[k], o, 64);
            qk[k] += __shfl_xor(qk[k], o, 64);
        }
    }
    if (lane == 0) {
        #pragma unroll
        for (int k = 0; k < 16; ++k) {
            parts2[wvv][k * 2]     = sk[k];
            parts2[wvv][k * 2 + 1] = qk[k];
        }
    }
    __syncthreads();
    if (tid < 32) {
        int k = tid >> 1, which = tid & 1;
        float tot = parts2[0][tid] + parts2[1][tid] + parts2[2][tid] + parts2[3][tid];
        atomicAdd(&stats[3072 + which * 256 + cg * 16 + k], tot);
    }
}

// ---------------------------------------------------------------------------
// k_final2: grid 1024 = img(256) x sub(4). Each block stages the full spike
// image, recomputes both convs via MFMA for its 16 of 64 output tiles,
// reads rec, applies BN3/4/5, writes the output. 4 blocks/CU for latency
// hiding (256-block version was grid-limited to 4 waves/CU).
// ---------------------------------------------------------------------------
struct FinSh {
    short lo[1025 * 8];
    short hi[1025 * 8];
    unsigned short w2s[2304];
    unsigned short w1s[256];
    unsigned short bs[32];
    float sc3[16], sc4[16], sc5[16], shS[16];
};

__global__ __launch_bounds__(256) void k_final2(const unsigned char* __restrict__ s,
                                                const __hip_bfloat16* __restrict__ rec,
                                                const float* __restrict__ stats,
                                                const __hip_bfloat16* __restrict__ wc,
                                                const int* __restrict__ flag,
                                                void* __restrict__ out_) {
    __shared__ FinSh sm;
    int img = blockIdx.x >> 2;            // 256 images = tb(16) * nb(16)
    int sub = blockIdx.x & 3;             // quarter of the 64 output tiles
    int tid = threadIdx.x;
    int lane = tid & 63, wv = tid >> 6;

    const unsigned short* wr = (const unsigned short*)wc;
    for (int i = tid; i < 2304; i += 256) sm.w2s[i] = wr[OFF_W2 + i];
    sm.w1s[tid] = wr[OFF_W1 + tid];
    if (tid < 16) { sm.bs[tid] = wr[OFF_B1 + tid]; sm.bs[16 + tid] = wr[OFF_B2 + tid]; }
    if (tid < 8) {
        ((unsigned int*)sm.lo)[4096 + (tid & 3)] = 0;
        ((unsigned int*)sm.hi)[4096 + (tid & 3)] = 0;
    }
    // BN3/4/5 coefficients for this block's 16 channels
    if (tid >= 32 && tid < 48) {
        int k = tid - 32;
        int c = (img & 15) * 16 + k;
        const float inv = 1.f / 16384.f;
        float m3 = stats[3072 + c] * inv;
        float v3 = fmaxf(stats[3328 + c] * inv - m3 * m3, 0.f);
        float sc3 = bf2f(wc[OFF_G3 + c]) * rsqrtf(v3 + EPSBN);
        float sh3 = bf2f(wc[OFF_BE3 + c]) - m3 * sc3;
        float m4 = stats[3584 + c] * inv;
        float v4 = fmaxf(stats[3840 + c] * inv - m4 * m4, 0.f);
        float sc4 = bf2f(wc[OFF_G4 + c]) * rsqrtf(v4 + EPSBN);
        float sh4 = bf2f(wc[OFF_BE4 + c]) - m4 * sc4;
        float m5 = stats[4096 + c] * inv;
        float v5 = fmaxf(stats[4352 + c] * inv - m5 * m5, 0.f);
        float sc5 = bf2f(wc[OFF_G5 + c]) * rsqrtf(v5 + EPSBN);
        float sh5 = bf2f(wc[OFF_BE5 + c]) - m5 * sc5;
        sm.sc3[k] = sc3;
        sm.sc4[k] = sc4;
        sm.sc5[k] = sc5;
        sm.shS[k] = sh3 + sh4 + sh5;
    }
    // stage planar u8 -> LDS channel-last bf16 (full image; halo needed)
    {
        const unsigned int* sp = (const unsigned int*)(s + (size_t)img * 16384);
        int d2 = tid >> 5;
        int pg = tid & 31;
        unsigned int* dst = (unsigned int*)((d2 < 4) ? sm.lo : sm.hi);
        int dl = d2 & 3;
        #pragma unroll
        for (int p = 0; p < 8; ++p) {
            int base = p * 32 + pg;
            unsigned int u0 = sp[d2 * 512 + base];
            unsigned int u1 = sp[d2 * 512 + 256 + base];
            #pragma unroll
            for (int jj = 0; jj < 4; ++jj) {
                int j = (jj + pg) & 3;
                unsigned int b0 = (u0 >> (8 * j)) & 255u;
                unsigned int b1 = (u1 >> (8 * j)) & 255u;
                unsigned int val = (b0 ? 0x3F80u : 0u) | ((b1 ? 0x3F80u : 0u) << 16);
                int pix = p * 128 + pg * 4 + j;
                dst[pix * 4 + dl] = val;
            }
        }
    }
    __syncthreads();

    int m = lane & 15;
    int g = lane >> 4;
    const int tapA[5] = {0, 2, 4, 6, 8};
    const int tapB[5] = {1, 3, 5, 7, 8};

    short8 afr[5], a1f;
    #pragma unroll
    for (int p = 0; p < 5; ++p) {
        int tap = (g < 2) ? tapA[p] : tapB[p];
        short8 av;
        #pragma unroll
        for (int j = 0; j < 8; ++j) {
            int d = (g & 1) * 8 + j;
            unsigned short w = sm.w2s[m * 144 + d * 9 + tap];
            if (p == 4 && g >= 2) w = 0;
            av[j] = (short)w;
        }
        afr[p] = av;
    }
    #pragma unroll
    for (int j = 0; j < 8; ++j) {
        int d = (g & 1) * 8 + j;
        a1f[j] = (g < 2) ? (short)sm.w1s[m * 16 + d] : (short)0;
    }
    float bias1[4], bias2[4], c3[4], c4[4], c5[4], cS[4];
    #pragma unroll
    for (int r = 0; r < 4; ++r) {
        int k = g * 4 + r;
        bias1[r] = bfu(sm.bs[k]);
        bias2[r] = bfu(sm.bs[16 + k]);
        c3[r] = sm.sc3[k];
        c4[r] = sm.sc4[k];
        c5[r] = sm.sc5[k];
        cS[r] = sm.shS[k];
    }

    const short* bsrc = (g & 1) ? sm.hi : sm.lo;
    const __hip_bfloat16* rb = rec + (size_t)img * 16384;
    int f = *flag;
    float* of = (float*)out_;
    __hip_bfloat16* ob = (__hip_bfloat16*)out_;
    size_t obase = (size_t)img * 16384;

    #pragma unroll
    for (int ti = 0; ti < 4; ++ti) {
        int t = sub * 16 + wv * 4 + ti;
        int hh = t >> 1;
        int w0 = (t & 1) << 4;
        f32x4 acc2 = {0.f, 0.f, 0.f, 0.f};
        f32x4 acc1 = {0.f, 0.f, 0.f, 0.f};
        #pragma unroll
        for (int p = 0; p < 5; ++p) {
            int tap = (g < 2) ? tapA[p] : tapB[p];
            int row = hh + tap / 3 - 1;
            int col = w0 + m + (tap % 3) - 1;
            bool ok = ((unsigned)row < 32u) && ((unsigned)col < 32u);
            int idx = ok ? (row * 32 + col) : 1024;
            short8 bv = *(const short8*)&bsrc[idx * 8];
            acc2 = __builtin_amdgcn_mfma_f32_16x16x32_bf16(afr[p], bv, acc2, 0, 0, 0);
            if (p == 2)
                acc1 = __builtin_amdgcn_mfma_f32_16x16x32_bf16(a1f, bv, acc1, 0, 0, 0);
        }
        int pix = hh * 32 + w0 + m;
        #pragma unroll
        for (int r = 0; r < 4; ++r) {
            int k = g * 4 + r;
            float y1 = acc1[r] + bias1[r];
            float y2 = acc2[r] + bias2[r];
            float rv = bf2f(rb[(size_t)k * 1024 + pix]);
            float o = rv * c3[r] + y1 * c4[r] + y2 * c5[r] + cS[r];
            size_t oi = obase + (size_t)k * 1024 + pix;
            if (f) of[oi] = o;
            else   ob[oi] = __float2bfloat16(o);
        }
    }
}

// ---------------------------------------------------------------------------
// Workspace map:
//   [0,4M):   s (planar u8 spikes)      [4,8M):  l1 (i8 codes)
//   [8,16M):  l2                        [16,24M): rec
//   [40M..):  weight arena, stats(4608 fl), flag
// c1/c2 live only in registers (stats in k_work, recompute in k_final2).
// ---------------------------------------------------------------------------
extern "C" void kernel_launch(void* const* d_in, const int* in_sizes, int n_in,
                              void* d_out, int out_size, void* d_ws, size_t ws_size,
                              hipStream_t stream) {
    char* ws = (char*)d_ws;
    unsigned char* s_u8  = (unsigned char*)ws;
    signed char* l1c     = (signed char*)(ws + ((size_t)4 << 20));
    __hip_bfloat16* l2   = (__hip_bfloat16*)(ws + ((size_t)8 << 20));
    __hip_bfloat16* rec  = (__hip_bfloat16*)(ws + ((size_t)16 << 20));
    __hip_bfloat16* wc   = (__hip_bfloat16*)(ws + ((size_t)40 << 20));
    float* stats         = (float*)(ws + ((size_t)40 << 20) + (64 << 10));
    int* flag            = (int*)(ws + ((size_t)40 << 20) + (128 << 10));

    WPtrs wp;
    for (int i = 0; i < 15; ++i) wp.p[i] = d_in[i + 1];

    dim3 blk(256);
    k_prep<<<dim3(45), blk, 0, stream>>>((const unsigned short*)d_in[0], wp, wc, stats, flag);
    k_lifhaar<<<dim3(2048), blk, 0, stream>>>(d_in[0], flag, s_u8, l1c, stats);
    k_work<<<dim3(4352), blk, 0, stream>>>(s_u8, l1c, stats, wc, stats, l2);
    k_mixinv<<<dim3(256), blk, 0, stream>>>(l2, wc, stats, rec);
    k_final2<<<dim3(1024), blk, 0, stream>>>(s_u8, rec, stats, wc, flag, d_out);
}

// Round 4
// 151.511 us; speedup vs baseline: 1.0534x; 1.0049x over previous
//
#include <hip/hip_runtime.h>
#include <hip/hip_bf16.h>

#define T_ 4
#define B_ 4
#define C_ 256
#define H_ 32
#define W_ 32
#define TB_ 16
#define Hh_ 16
#define Wh_ 16
#define INVS2 0.70710678118654752440f
#define EPSBN 1e-5f

// Canonical weight arena offsets (bf16 elements)
#define OFF_HW   0
#define OFF_W1   4096
#define OFF_B1   4352
#define OFF_W2   4368
#define OFF_B2   6672
#define OFF_G1   6688
#define OFF_BE1  7200
#define OFF_G2   7712
#define OFF_BE2  8736
#define OFF_G3   9760
#define OFF_BE3  10016
#define OFF_G4   10272
#define OFF_BE4  10528
#define OFF_G5   10784
#define OFF_BE5  11040
#define W_TOTAL  11296
// stats arena (floats): sums1[1024] | sums2[2048] | sums345[1536]
#define NSUMS    4608

struct WPtrs { const void* p[15]; };

typedef __attribute__((ext_vector_type(8))) short short8;
typedef __attribute__((ext_vector_type(4))) float f32x4;

__device__ inline float bf2f(__hip_bfloat16 v) { return __bfloat162float(v); }
__device__ inline float bfu(unsigned short u) { return __uint_as_float((unsigned)u << 16); }

// ---------------------------------------------------------------------------
// k_prep: per-block self-sniff (fp32 vs bf16), convert weights to bf16 arena,
// zero the raw-sums region; block 0 publishes the flag for later kernels.
// ---------------------------------------------------------------------------
__global__ __launch_bounds__(256) void k_prep(const unsigned short* __restrict__ xr,
                                              WPtrs wp,
                                              __hip_bfloat16* __restrict__ wc,
                                              float* __restrict__ sums,
                                              int* __restrict__ flag) {
    int tid = threadIdx.x;
    int cnt = 0;
    for (int i = tid; i < 2048; i += 256) {
        int e = (xr[i] >> 7) & 0xFF;
        if (e >= 134) cnt++;
    }
    for (int o = 1; o < 64; o <<= 1) cnt += __shfl_xor(cnt, o, 64);
    __shared__ int sh[4];
    if ((tid & 63) == 0) sh[tid >> 6] = cnt;
    __syncthreads();
    int f = (sh[0] + sh[1] + sh[2] + sh[3] >= 32) ? 1 : 0;
    if (blockIdx.x == 0 && tid == 0) *flag = f;

    const int sizes[15] = {4096, 256, 16, 2304, 16, 512, 512, 1024, 1024,
                           256, 256, 256, 256, 256, 256};
    int i = blockIdx.x * 256 + tid;
    if (i < W_TOTAL) {
        int seg = 0, off = 0;
        while (i >= off + sizes[seg]) { off += sizes[seg]; seg++; }
        int j = i - off;
        float v = f ? ((const float*)wp.p[seg])[j]
                    : bf2f(((const __hip_bfloat16*)wp.p[seg])[j]);
        wc[i] = __float2bfloat16(v);
    }
    if (i < NSUMS) sums[i] = 0.f;
}

// ---------------------------------------------------------------------------
// Fused LIF + Haar-W. Planar coalesced u8 spikes + i8 Haar codes + BN1 sums.
// Block = (b, c, half); thread = (row-in-half, w-pair).
// ---------------------------------------------------------------------------
__global__ __launch_bounds__(256) void k_lifhaar(const void* __restrict__ x_,
                                                 const int* __restrict__ flag,
                                                 unsigned char* __restrict__ s,
                                                 signed char* __restrict__ l1,
                                                 float* __restrict__ sums1) {
    int bid = blockIdx.x;                      // 2048 = b(4) * c(256) * half(2)
    int tid = threadIdx.x;
    int half = bid & 1;
    int c = (bid >> 1) & 255;
    int b = bid >> 9;
    int wp = tid & 15;
    int hl = tid >> 4;
    int h = half * 16 + hl;
    int f = *flag;
    const float* xf = (const float*)x_;
    const unsigned int* xb = (const unsigned int*)x_;
    int n = ((b * 256 + c) * 32 + h) * 32 + 2 * wp;

    float v0 = 0.f, v1 = 0.f;
    float aL = 0.f, qL = 0.f, aH = 0.f, qH = 0.f;
    #pragma unroll
    for (int t = 0; t < T_; ++t) {
        size_t idx = (size_t)t * 1048576 + n;
        float x0, x1;
        if (f) {
            float2 xx = *(const float2*)(xf + idx);
            x0 = xx.x; x1 = xx.y;
        } else {
            unsigned int u = xb[idx >> 1];
            x0 = __uint_as_float(u << 16);
            x1 = __uint_as_float(u & 0xffff0000u);
        }
        v0 += (x0 - v0) * 0.5f;
        v1 += (x1 - v1) * 0.5f;
        float s0 = (v0 >= 1.f) ? 1.f : 0.f;
        float s1 = (v1 >= 1.f) ? 1.f : 0.f;
        v0 *= (1.f - s0);
        v1 *= (1.f - s1);
        int tb = t * 4 + b;
        ((uchar2*)s)[(size_t)(tb * 256 + c) * 512 + h * 16 + wp] =
            make_uchar2((unsigned char)s0, (unsigned char)s1);
        float cl = s0 + s1, ch = s0 - s1;
        size_t lb = (((size_t)tb * 512 + c) * 32 + h) * 16 + wp;
        l1[lb] = (signed char)(int)cl;
        l1[lb + (size_t)256 * 512] = (signed char)(int)ch;
        aL += cl; qL += cl * cl; aH += ch; qH += ch * ch;
    }
    for (int o = 1; o < 64; o <<= 1) {
        aL += __shfl_xor(aL, o, 64); qL += __shfl_xor(qL, o, 64);
        aH += __shfl_xor(aH, o, 64); qH += __shfl_xor(qH, o, 64);
    }
    __shared__ float part[4][4];
    int lane = tid & 63, wv = tid >> 6;
    if (lane == 0) {
        part[wv][0] = aL; part[wv][1] = qL; part[wv][2] = aH; part[wv][3] = qH;
    }
    __syncthreads();
    if (tid < 4) {
        float tot = part[0][tid] + part[1][tid] + part[2][tid] + part[3][tid];
        const int offs[4] = {0, 512, 256, 768};
        atomicAdd(&sums1[offs[tid] + c], tot);
    }
}

// ---------------------------------------------------------------------------
// Fused k_work: bids [0,256) = conv STATS role (MFMA implicit GEMM, BN4/5
// sum accumulation only — no c1/c2 stores); bids [256,4352) = stage2 role
// (BN1-apply + Haar-H + gates -> l2, BN2 sum accumulation).
// ---------------------------------------------------------------------------
struct SharedU {
    union {
        struct {
            short lo[1025 * 8];            // channel-last bf16, d 0..7 (+zero row)
            short hi[1025 * 8];            // d 8..15
            unsigned short w2s[2304];      // [k][d*9+tap]
            unsigned short w1s[256];       // [k][d]
            unsigned short bs[32];         // B1 | B2
            float parts[4][4][16];         // [wv][g][r*4+which]
        } cv;
        struct {
            float lo[512];
            float hi[512];
            float part[4][8];
        } s2;
    };
};

__global__ __launch_bounds__(256) void k_work(const unsigned char* __restrict__ s,
                                              const signed char* __restrict__ l1,
                                              const float* __restrict__ sums1,
                                              const __hip_bfloat16* __restrict__ wc,
                                              float* __restrict__ stats,
                                              __hip_bfloat16* __restrict__ l2) {
    __shared__ SharedU sm;
    int bid = blockIdx.x;
    int tid = threadIdx.x;
    int lane = tid & 63, wv = tid >> 6;

    if (bid < 256) {
        // ------------------------------ conv stats role ------------------------------
        int img = bid;
        const unsigned short* wr = (const unsigned short*)wc;
        for (int i = tid; i < 2304; i += 256) sm.cv.w2s[i] = wr[OFF_W2 + i];
        sm.cv.w1s[tid] = wr[OFF_W1 + tid];
        if (tid < 16) { sm.cv.bs[tid] = wr[OFF_B1 + tid]; sm.cv.bs[16 + tid] = wr[OFF_B2 + tid]; }
        // zero row (pixel index 1024)
        if (tid < 8) {
            ((unsigned int*)sm.cv.lo)[4096 + (tid & 3)] = 0;
            ((unsigned int*)sm.cv.hi)[4096 + (tid & 3)] = 0;
        }
        // stage planar u8 -> LDS channel-last bf16
        {
            const unsigned int* sp = (const unsigned int*)(s + (size_t)img * 16384);
            int d2 = tid >> 5;               // channel pair 2*d2, 2*d2+1
            int pg = tid & 31;
            unsigned int* dst = (unsigned int*)((d2 < 4) ? sm.cv.lo : sm.cv.hi);
            int dl = d2 & 3;
            #pragma unroll
            for (int p = 0; p < 8; ++p) {
                int base = p * 32 + pg;      // dword index within a channel row
                unsigned int u0 = sp[d2 * 512 + base];
                unsigned int u1 = sp[d2 * 512 + 256 + base];
                #pragma unroll
                for (int jj = 0; jj < 4; ++jj) {
                    int j = (jj + pg) & 3;   // scramble to spread LDS banks
                    unsigned int b0 = (u0 >> (8 * j)) & 255u;
                    unsigned int b1 = (u1 >> (8 * j)) & 255u;
                    unsigned int val = (b0 ? 0x3F80u : 0u) | ((b1 ? 0x3F80u : 0u) << 16);
                    int pix = p * 128 + pg * 4 + j;
                    dst[pix * 4 + dl] = val;
                }
            }
        }
        __syncthreads();

        int m = lane & 15;
        int g = lane >> 4;
        const int tapA[5] = {0, 2, 4, 6, 8};
        const int tapB[5] = {1, 3, 5, 7, 8};

        short8 afr[5], a1f;
        #pragma unroll
        for (int p = 0; p < 5; ++p) {
            int tap = (g < 2) ? tapA[p] : tapB[p];
            short8 av;
            #pragma unroll
            for (int j = 0; j < 8; ++j) {
                int d = (g & 1) * 8 + j;
                unsigned short w = sm.cv.w2s[m * 144 + d * 9 + tap];
                if (p == 4 && g >= 2) w = 0;
                av[j] = (short)w;
            }
            afr[p] = av;
        }
        #pragma unroll
        for (int j = 0; j < 8; ++j) {
            int d = (g & 1) * 8 + j;
            a1f[j] = (g < 2) ? (short)sm.cv.w1s[m * 16 + d] : (short)0;
        }
        float bias1[4], bias2[4];
        #pragma unroll
        for (int r = 0; r < 4; ++r) {
            bias1[r] = bfu(sm.cv.bs[g * 4 + r]);
            bias2[r] = bfu(sm.cv.bs[16 + g * 4 + r]);
        }

        const short* bsrc = (g & 1) ? sm.cv.hi : sm.cv.lo;

        float cs1[4] = {0, 0, 0, 0}, cq1[4] = {0, 0, 0, 0};
        float cs2[4] = {0, 0, 0, 0}, cq2[4] = {0, 0, 0, 0};

        for (int t = wv * 16; t < wv * 16 + 16; ++t) {
            int h = t >> 1;
            int w0 = (t & 1) << 4;
            f32x4 acc2 = {0.f, 0.f, 0.f, 0.f};
            f32x4 acc1 = {0.f, 0.f, 0.f, 0.f};
            #pragma unroll
            for (int p = 0; p < 5; ++p) {
                int tap = (g < 2) ? tapA[p] : tapB[p];
                int row = h + tap / 3 - 1;
                int col = w0 + m + (tap % 3) - 1;
                bool ok = ((unsigned)row < 32u) && ((unsigned)col < 32u);
                int idx = ok ? (row * 32 + col) : 1024;
                short8 bv = *(const short8*)&bsrc[idx * 8];
                acc2 = __builtin_amdgcn_mfma_f32_16x16x32_bf16(afr[p], bv, acc2, 0, 0, 0);
                if (p == 2)
                    acc1 = __builtin_amdgcn_mfma_f32_16x16x32_bf16(a1f, bv, acc1, 0, 0, 0);
            }
            #pragma unroll
            for (int r = 0; r < 4; ++r) {
                float y1 = acc1[r] + bias1[r];
                float y2 = acc2[r] + bias2[r];
                cs1[r] += y1; cq1[r] += y1 * y1;
                cs2[r] += y2; cq2[r] += y2 * y2;
            }
        }
        // reduce across the 16 m-lanes (same g)
        #pragma unroll
        for (int o = 1; o < 16; o <<= 1) {
            #pragma unroll
            for (int r = 0; r < 4; ++r) {
                cs1[r] += __shfl_xor(cs1[r], o, 64);
                cq1[r] += __shfl_xor(cq1[r], o, 64);
                cs2[r] += __shfl_xor(cs2[r], o, 64);
                cq2[r] += __shfl_xor(cq2[r], o, 64);
            }
        }
        if (m == 0) {
            #pragma unroll
            for (int r = 0; r < 4; ++r) {
                sm.cv.parts[wv][g][r * 4 + 0] = cs1[r];
                sm.cv.parts[wv][g][r * 4 + 1] = cq1[r];
                sm.cv.parts[wv][g][r * 4 + 2] = cs2[r];
                sm.cv.parts[wv][g][r * 4 + 3] = cq2[r];
            }
        }
        __syncthreads();
        if (tid < 64) {
            int gg = tid >> 4, r = (tid >> 2) & 3, which = tid & 3;
            float tot = sm.cv.parts[0][gg][r * 4 + which] + sm.cv.parts[1][gg][r * 4 + which]
                      + sm.cv.parts[2][gg][r * 4 + which] + sm.cv.parts[3][gg][r * 4 + which];
            int ch = (img & 15) * 16 + gg * 4 + r;   // global BN channel
            // stats: sums4_sum@3584 sums4_sq@3840 sums5_sum@4096 sums5_sq@4352
            const int base[4] = {3584, 3840, 4096, 4352};
            atomicAdd(&stats[base[which] + ch], tot);
        }
    } else {
        // ------------------------------ stage2 role ------------------------------
        int blk = bid - 256;                  // TB*C = 4096
        int c = blk & 255;
        int tb = blk >> 8;

        const float nrm = 1.f / 8192.f;
        float mL = sums1[c] * INVS2 * nrm;
        float vL = fmaxf(sums1[512 + c] * 0.5f * nrm - mL * mL, 0.f);
        float sL = bf2f(wc[OFF_G1 + c]) * rsqrtf(vL + EPSBN);
        float tL = bf2f(wc[OFF_BE1 + c]) - mL * sL;
        float mH = sums1[256 + c] * INVS2 * nrm;
        float vH = fmaxf(sums1[768 + c] * 0.5f * nrm - mH * mH, 0.f);
        float sH = bf2f(wc[OFF_G1 + 256 + c]) * rsqrtf(vH + EPSBN);
        float tH = bf2f(wc[OFF_BE1 + 256 + c]) - mH * sH;

        const signed char* plo = l1 + (((size_t)tb * 512) + c) * (H_ * Wh_);
        const signed char* phi = l1 + (((size_t)tb * 512) + 256 + c) * (H_ * Wh_);
        float slo = sL * INVS2, shi = sH * INVS2;
        sm.s2.lo[tid & 511] = 0.f;            // placate compiler aliasing; overwritten below
        {
            sm.s2.lo[tid]       = (float)plo[tid] * slo + tL;
            sm.s2.hi[tid]       = (float)phi[tid] * shi + tH;
            sm.s2.lo[tid + 256] = (float)plo[tid + 256] * slo + tL;
            sm.s2.hi[tid + 256] = (float)phi[tid + 256] * shi + tH;
        }
        __syncthreads();

        int w = tid & 15, v = tid >> 4;
        float a = sm.s2.lo[(2 * v) * Wh_ + w], b = sm.s2.lo[(2 * v + 1) * Wh_ + w];
        float zLL = (a + b) * INVS2;
        float zHL = (a - b) * INVS2;
        a = sm.s2.hi[(2 * v) * Wh_ + w]; b = sm.s2.hi[(2 * v + 1) * Wh_ + w];
        float zLH = (a + b) * INVS2;
        float zHH = (a - b) * INVS2;
        zLL = (fabsf(zLL) - 0.5f >= 0.f) ? zLL : 0.f;
        zHL = (fabsf(zHL) - 0.5f >= 0.f) ? zHL : 0.f;
        zLH = (fabsf(zLH) - 0.5f >= 0.f) ? zLH : 0.f;
        zHH = (fabsf(zHH) - 0.5f >= 0.f) ? zHH : 0.f;

        float r0 = zLL, r1 = zHL, r2 = zLH, r3 = zHH;
        float q0 = zLL * zLL, q1 = zHL * zHL, q2 = zLH * zLH, q3 = zHH * zHH;
        for (int o = 1; o < 64; o <<= 1) {
            r0 += __shfl_xor(r0, o, 64); r1 += __shfl_xor(r1, o, 64);
            r2 += __shfl_xor(r2, o, 64); r3 += __shfl_xor(r3, o, 64);
            q0 += __shfl_xor(q0, o, 64); q1 += __shfl_xor(q1, o, 64);
            q2 += __shfl_xor(q2, o, 64); q3 += __shfl_xor(q3, o, 64);
        }
        if (lane == 0) {
            sm.s2.part[wv][0] = r0; sm.s2.part[wv][1] = r1;
            sm.s2.part[wv][2] = r2; sm.s2.part[wv][3] = r3;
            sm.s2.part[wv][4] = q0; sm.s2.part[wv][5] = q1;
            sm.s2.part[wv][6] = q2; sm.s2.part[wv][7] = q3;
        }
        __syncthreads();
        float S0 = sm.s2.part[0][0] + sm.s2.part[1][0] + sm.s2.part[2][0] + sm.s2.part[3][0];
        float S1 = sm.s2.part[0][1] + sm.s2.part[1][1] + sm.s2.part[2][1] + sm.s2.part[3][1];
        float S2 = sm.s2.part[0][2] + sm.s2.part[1][2] + sm.s2.part[2][2] + sm.s2.part[3][2];
        float S3 = sm.s2.part[0][3] + sm.s2.part[1][3] + sm.s2.part[2][3] + sm.s2.part[3][3];
        float Q0 = sm.s2.part[0][4] + sm.s2.part[1][4] + sm.s2.part[2][4] + sm.s2.part[3][4];
        float Q1 = sm.s2.part[0][5] + sm.s2.part[1][5] + sm.s2.part[2][5] + sm.s2.part[3][5];
        float Q2 = sm.s2.part[0][6] + sm.s2.part[1][6] + sm.s2.part[2][6] + sm.s2.part[3][6];
        float Q3 = sm.s2.part[0][7] + sm.s2.part[1][7] + sm.s2.part[2][7] + sm.s2.part[3][7];
        float fLL = (Q0 * (1.f / 256.f) > 0.01f) ? 1.f : 0.f;
        float fHL = (Q1 * (1.f / 256.f) > 0.02f) ? 1.f : 0.f;
        float fLH = (Q2 * (1.f / 256.f) > 0.02f) ? 1.f : 0.f;
        float fHH = (Q3 * (1.f / 256.f) > 0.05f) ? 1.f : 0.f;

        float* sums2 = stats + 1024;
        if (tid < 8) {
            const int cho[8] = {0, 1024, 256, 1280, 512, 1536, 768, 1792};
            const float vals[8] = {fLL * S0, fLL * Q0, fHL * S1, fHL * Q1,
                                   fLH * S2, fLH * Q2, fHH * S3, fHH * Q3};
            atomicAdd(&sums2[cho[tid] + c], vals[tid]);
        }

        size_t ob = (((size_t)tb * 1024) + c) * 256 + tid;
        l2[ob]               = __float2bfloat16(zLL * fLL);
        l2[ob + 256u * 256u] = __float2bfloat16(zHL * fHL);
        l2[ob + 512u * 256u] = __float2bfloat16(zLH * fLH);
        l2[ob + 768u * 256u] = __float2bfloat16(zHH * fHH);
    }
}

// ---------------------------------------------------------------------------
// Fused BN2-apply + block channel matmul + inverse Haar -> rec bf16;
// accumulates BN3 raw sums. Grid 1024 = tb(16) x cg(16) x ks(4): each block
// computes 4 of the 16 output channels (4 blocks/CU for latency hiding;
// the 256-block version was grid-limited to 4 waves/CU). xv loads are
// duplicated 4x but L2-resident.
// ---------------------------------------------------------------------------
__global__ __launch_bounds__(256) void k_mixinv(const __hip_bfloat16* __restrict__ l2,
                                                const __hip_bfloat16* __restrict__ wc,
                                                float* __restrict__ stats,
                                                __hip_bfloat16* __restrict__ rec) {
    int bid = blockIdx.x;                 // 1024 = tb(16) * cg(16) * ks(4)
    int ks = bid & 3;
    int cg = (bid >> 2) & 15;
    int tb = bid >> 6;
    int tid = threadIdx.x;
    int lane = tid & 63, wvv = tid >> 6;
    const float* sums2 = stats + 1024;

    __shared__ float wt[4][16][4];        // [q][d][kk] for k = ks*4+kk
    __shared__ float bsc[64], bsh[64];
    __shared__ float parts2[4][8];
    {
        int i = tid;                      // 256 entries = q(4) * d(16) * kk(4)
        int q = i >> 6, rem = i & 63, d = rem >> 2, kk = rem & 3;
        int nb = q * 4 + (cg >> 2);
        int k = ks * 4 + kk;
        wt[q][d][kk] = bf2f(wc[OFF_HW + nb * 256 + d * 16 + k]);
    }
    if (tid < 64) {
        int q = tid >> 4, d = tid & 15;
        int ch = q * 256 + cg * 16 + d;
        float m = sums2[ch] * (1.f / 4096.f);
        float var = fmaxf(sums2[1024 + ch] * (1.f / 4096.f) - m * m, 0.f);
        float sc = bf2f(wc[OFF_G2 + ch]) * rsqrtf(var + EPSBN);
        bsc[tid] = sc;
        bsh[tid] = bf2f(wc[OFF_BE2 + ch]) - m * sc;
    }
    __syncthreads();

    float h[4][4];
    #pragma unroll
    for (int q = 0; q < 4; ++q)
        #pragma unroll
        for (int kk = 0; kk < 4; ++kk) h[q][kk] = 0.f;

    int p = tid;
    #pragma unroll
    for (int q = 0; q < 4; ++q) {
        const __hip_bfloat16* base =
            l2 + ((size_t)tb * 1024 + q * 256 + cg * 16) * 256 + p;
        #pragma unroll
        for (int d = 0; d < 16; ++d) {
            float xv = bf2f(base[d * 256]) * bsc[q * 16 + d] + bsh[q * 16 + d];
            #pragma unroll
            for (int kk = 0; kk < 4; ++kk)
                h[q][kk] = fmaf(xv, wt[q][d][kk], h[q][kk]);
        }
    }

    int uh = tid >> 4, uw = tid & 15;
    __hip_bfloat16* ob = rec + ((size_t)tb * 256 + cg * 16) * 1024;
    float sk[4], qk[4];
    #pragma unroll
    for (int kk = 0; kk < 4; ++kk) {
        int k = ks * 4 + kk;
        float LL = h[0][kk], HL = h[1][kk], LH = h[2][kk], HH = h[3][kk];
        float v00 = 0.5f * (LL + HL + LH + HH);
        float v01 = 0.5f * (LL + HL - LH - HH);
        float v10 = 0.5f * (LL - HL + LH - HH);
        float v11 = 0.5f * (LL - HL - LH + HH);
        __hip_bfloat162 top, bot;
        top.x = __float2bfloat16(v00); top.y = __float2bfloat16(v01);
        bot.x = __float2bfloat16(v10); bot.y = __float2bfloat16(v11);
        *(__hip_bfloat162*)(ob + (size_t)k * 1024 + (2 * uh) * 32 + 2 * uw) = top;
        *(__hip_bfloat162*)(ob + (size_t)k * 1024 + (2 * uh + 1) * 32 + 2 * uw) = bot;
        sk[kk] = v00 + v01 + v10 + v11;
        qk[kk] = v00 * v00 + v01 * v01 + v10 * v10 + v11 * v11;
    }
    for (int o = 1; o < 64; o <<= 1) {
        #pragma unroll
        for (int kk = 0; kk < 4; ++kk) {
            sk[kk] += __shfl_xor(sk[kk], o, 64);
            qk[kk] += __shfl_xor(qk[kk], o, 64);
        }
    }
    if (lane == 0) {
        #pragma unroll
        for (int kk = 0; kk < 4; ++kk) {
            parts2[wvv][kk * 2]     = sk[kk];
            parts2[wvv][kk * 2 + 1] = qk[kk];
        }
    }
    __syncthreads();
    if (tid < 8) {
        int kk = tid >> 1, which = tid & 1;
        float tot = parts2[0][tid] + parts2[1][tid] + parts2[2][tid] + parts2[3][tid];
        atomicAdd(&stats[3072 + which * 256 + cg * 16 + ks * 4 + kk], tot);
    }
}

// ---------------------------------------------------------------------------
// k_final2: grid 1024 = img(256) x sub(4). Each block stages the full spike
// image, recomputes both convs via MFMA for its 16 of 64 output tiles,
// reads rec, applies BN3/4/5, writes the output. 4 blocks/CU for latency
// hiding (256-block version was grid-limited to 4 waves/CU).
// ---------------------------------------------------------------------------
struct FinSh {
    short lo[1025 * 8];
    short hi[1025 * 8];
    unsigned short w2s[2304];
    unsigned short w1s[256];
    unsigned short bs[32];
    float sc3[16], sc4[16], sc5[16], shS[16];
};

__global__ __launch_bounds__(256) void k_final2(const unsigned char* __restrict__ s,
                                                const __hip_bfloat16* __restrict__ rec,
                                                const float* __restrict__ stats,
                                                const __hip_bfloat16* __restrict__ wc,
                                                const int* __restrict__ flag,
                                                void* __restrict__ out_) {
    __shared__ FinSh sm;
    int img = blockIdx.x >> 2;            // 256 images = tb(16) * nb(16)
    int sub = blockIdx.x & 3;             // quarter of the 64 output tiles
    int tid = threadIdx.x;
    int lane = tid & 63, wv = tid >> 6;

    const unsigned short* wr = (const unsigned short*)wc;
    for (int i = tid; i < 2304; i += 256) sm.w2s[i] = wr[OFF_W2 + i];
    sm.w1s[tid] = wr[OFF_W1 + tid];
    if (tid < 16) { sm.bs[tid] = wr[OFF_B1 + tid]; sm.bs[16 + tid] = wr[OFF_B2 + tid]; }
    if (tid < 8) {
        ((unsigned int*)sm.lo)[4096 + (tid & 3)] = 0;
        ((unsigned int*)sm.hi)[4096 + (tid & 3)] = 0;
    }
    // BN3/4/5 coefficients for this block's 16 channels
    if (tid >= 32 && tid < 48) {
        int k = tid - 32;
        int c = (img & 15) * 16 + k;
        const float inv = 1.f / 16384.f;
        float m3 = stats[3072 + c] * inv;
        float v3 = fmaxf(stats[3328 + c] * inv - m3 * m3, 0.f);
        float sc3 = bf2f(wc[OFF_G3 + c]) * rsqrtf(v3 + EPSBN);
        float sh3 = bf2f(wc[OFF_BE3 + c]) - m3 * sc3;
        float m4 = stats[3584 + c] * inv;
        float v4 = fmaxf(stats[3840 + c] * inv - m4 * m4, 0.f);
        float sc4 = bf2f(wc[OFF_G4 + c]) * rsqrtf(v4 + EPSBN);
        float sh4 = bf2f(wc[OFF_BE4 + c]) - m4 * sc4;
        float m5 = stats[4096 + c] * inv;
        float v5 = fmaxf(stats[4352 + c] * inv - m5 * m5, 0.f);
        float sc5 = bf2f(wc[OFF_G5 + c]) * rsqrtf(v5 + EPSBN);
        float sh5 = bf2f(wc[OFF_BE5 + c]) - m5 * sc5;
        sm.sc3[k] = sc3;
        sm.sc4[k] = sc4;
        sm.sc5[k] = sc5;
        sm.shS[k] = sh3 + sh4 + sh5;
    }
    // stage planar u8 -> LDS channel-last bf16 (full image; halo needed)
    {
        const unsigned int* sp = (const unsigned int*)(s + (size_t)img * 16384);
        int d2 = tid >> 5;
        int pg = tid & 31;
        unsigned int* dst = (unsigned int*)((d2 < 4) ? sm.lo : sm.hi);
        int dl = d2 & 3;
        #pragma unroll
        for (int p = 0; p < 8; ++p) {
            int base = p * 32 + pg;
            unsigned int u0 = sp[d2 * 512 + base];
            unsigned int u1 = sp[d2 * 512 + 256 + base];
            #pragma unroll
            for (int jj = 0; jj < 4; ++jj) {
                int j = (jj + pg) & 3;
                unsigned int b0 = (u0 >> (8 * j)) & 255u;
                unsigned int b1 = (u1 >> (8 * j)) & 255u;
                unsigned int val = (b0 ? 0x3F80u : 0u) | ((b1 ? 0x3F80u : 0u) << 16);
                int pix = p * 128 + pg * 4 + j;
                dst[pix * 4 + dl] = val;
            }
        }
    }
    __syncthreads();

    int m = lane & 15;
    int g = lane >> 4;
    const int tapA[5] = {0, 2, 4, 6, 8};
    const int tapB[5] = {1, 3, 5, 7, 8};

    short8 afr[5], a1f;
    #pragma unroll
    for (int p = 0; p < 5; ++p) {
        int tap = (g < 2) ? tapA[p] : tapB[p];
        short8 av;
        #pragma unroll
        for (int j = 0; j < 8; ++j) {
            int d = (g & 1) * 8 + j;
            unsigned short w = sm.w2s[m * 144 + d * 9 + tap];
            if (p == 4 && g >= 2) w = 0;
            av[j] = (short)w;
        }
        afr[p] = av;
    }
    #pragma unroll
    for (int j = 0; j < 8; ++j) {
        int d = (g & 1) * 8 + j;
        a1f[j] = (g < 2) ? (short)sm.w1s[m * 16 + d] : (short)0;
    }
    float bias1[4], bias2[4], c3[4], c4[4], c5[4], cS[4];
    #pragma unroll
    for (int r = 0; r < 4; ++r) {
        int k = g * 4 + r;
        bias1[r] = bfu(sm.bs[k]);
        bias2[r] = bfu(sm.bs[16 + k]);
        c3[r] = sm.sc3[k];
        c4[r] = sm.sc4[k];
        c5[r] = sm.sc5[k];
        cS[r] = sm.shS[k];
    }

    const short* bsrc = (g & 1) ? sm.hi : sm.lo;
    const __hip_bfloat16* rb = rec + (size_t)img * 16384;
    int f = *flag;
    float* of = (float*)out_;
    __hip_bfloat16* ob = (__hip_bfloat16*)out_;
    size_t obase = (size_t)img * 16384;

    #pragma unroll
    for (int ti = 0; ti < 4; ++ti) {
        int t = sub * 16 + wv * 4 + ti;
        int hh = t >> 1;
        int w0 = (t & 1) << 4;
        f32x4 acc2 = {0.f, 0.f, 0.f, 0.f};
        f32x4 acc1 = {0.f, 0.f, 0.f, 0.f};
        #pragma unroll
        for (int p = 0; p < 5; ++p) {
            int tap = (g < 2) ? tapA[p] : tapB[p];
            int row = hh + tap / 3 - 1;
            int col = w0 + m + (tap % 3) - 1;
            bool ok = ((unsigned)row < 32u) && ((unsigned)col < 32u);
            int idx = ok ? (row * 32 + col) : 1024;
            short8 bv = *(const short8*)&bsrc[idx * 8];
            acc2 = __builtin_amdgcn_mfma_f32_16x16x32_bf16(afr[p], bv, acc2, 0, 0, 0);
            if (p == 2)
                acc1 = __builtin_amdgcn_mfma_f32_16x16x32_bf16(a1f, bv, acc1, 0, 0, 0);
        }
        int pix = hh * 32 + w0 + m;
        #pragma unroll
        for (int r = 0; r < 4; ++r) {
            int k = g * 4 + r;
            float y1 = acc1[r] + bias1[r];
            float y2 = acc2[r] + bias2[r];
            float rv = bf2f(rb[(size_t)k * 1024 + pix]);
            float o = rv * c3[r] + y1 * c4[r] + y2 * c5[r] + cS[r];
            size_t oi = obase + (size_t)k * 1024 + pix;
            if (f) of[oi] = o;
            else   ob[oi] = __float2bfloat16(o);
        }
    }
}

// ---------------------------------------------------------------------------
// Workspace map:
//   [0,4M):   s (planar u8 spikes)      [4,8M):  l1 (i8 codes)
//   [8,16M):  l2                        [16,24M): rec
//   [40M..):  weight arena, stats(4608 fl), flag
// c1/c2 live only in registers (stats in k_work, recompute in k_final2).
// ---------------------------------------------------------------------------
extern "C" void kernel_launch(void* const* d_in, const int* in_sizes, int n_in,
                              void* d_out, int out_size, void* d_ws, size_t ws_size,
                              hipStream_t stream) {
    char* ws = (char*)d_ws;
    unsigned char* s_u8  = (unsigned char*)ws;
    signed char* l1c     = (signed char*)(ws + ((size_t)4 << 20));
    __hip_bfloat16* l2   = (__hip_bfloat16*)(ws + ((size_t)8 << 20));
    __hip_bfloat16* rec  = (__hip_bfloat16*)(ws + ((size_t)16 << 20));
    __hip_bfloat16* wc   = (__hip_bfloat16*)(ws + ((size_t)40 << 20));
    float* stats         = (float*)(ws + ((size_t)40 << 20) + (64 << 10));
    int* flag            = (int*)(ws + ((size_t)40 << 20) + (128 << 10));

    WPtrs wp;
    for (int i = 0; i < 15; ++i) wp.p[i] = d_in[i + 1];

    dim3 blk(256);
    k_prep<<<dim3(45), blk, 0, stream>>>((const unsigned short*)d_in[0], wp, wc, stats, flag);
    k_lifhaar<<<dim3(2048), blk, 0, stream>>>(d_in[0], flag, s_u8, l1c, stats);
    k_work<<<dim3(4352), blk, 0, stream>>>(s_u8, l1c, stats, wc, stats, l2);
    k_mixinv<<<dim3(1024), blk, 0, stream>>>(l2, wc, stats, rec);
    k_final2<<<dim3(1024), blk, 0, stream>>>(s_u8, rec, stats, wc, flag, d_out);
}

// Round 5
// 145.788 us; speedup vs baseline: 1.0948x; 1.0393x over previous
//
#include <hip/hip_runtime.h>
#include <hip/hip_bf16.h>

#define T_ 4
#define B_ 4
#define C_ 256
#define H_ 32
#define W_ 32
#define TB_ 16
#define Hh_ 16
#define Wh_ 16
#define INVS2 0.70710678118654752440f
#define EPSBN 1e-5f

// Canonical weight arena offsets (bf16 elements)
#define OFF_HW   0
#define OFF_W1   4096
#define OFF_B1   4352
#define OFF_W2   4368
#define OFF_B2   6672
#define OFF_G1   6688
#define OFF_BE1  7200
#define OFF_G2   7712
#define OFF_BE2  8736
#define OFF_G3   9760
#define OFF_BE3  10016
#define OFF_G4   10272
#define OFF_BE4  10528
#define OFF_G5   10784
#define OFF_BE5  11040
#define W_TOTAL  11296
// stats arena (floats):
//   [0..1024)   unused (legacy sums1 slot, kept for layout stability)
//   [1024..3072) sums2 (BN2)        — zeroed by prep role, atomics in k_work
//   [3072..4608) sums345 (BN3/4/5)  — zeroed by prep role, atomics later
//   [4608..12800) parts1[8][4][256] — written unconditionally by lifhaar role
#define NSUMS    4608
#define P1OFF    4608

struct WPtrs { const void* p[15]; };

typedef __attribute__((ext_vector_type(8))) short short8;
typedef __attribute__((ext_vector_type(4))) float f32x4;

__device__ inline float bf2f(__hip_bfloat16 v) { return __bfloat162float(v); }
__device__ inline float bfu(unsigned short u) { return __uint_as_float((unsigned)u << 16); }

// ---------------------------------------------------------------------------
// K1 k_lifprep: grid 2093.
//   bids [0,2048): LIF + Haar-W role (self-sniffed dtype flag; BN1 partials
//                  written to private slots — no atomics, no pre-zero needed).
//   bids [2048,2093): prep role — convert weights to bf16 arena, zero
//                  sums2/sums345, block 2048 publishes flag for later kernels.
// ---------------------------------------------------------------------------
__global__ __launch_bounds__(256) void k_lifprep(const void* __restrict__ x_,
                                                 WPtrs wp,
                                                 __hip_bfloat16* __restrict__ wc,
                                                 float* __restrict__ stats,
                                                 int* __restrict__ flag,
                                                 unsigned char* __restrict__ s,
                                                 signed char* __restrict__ l1) {
    int bid = blockIdx.x;
    int tid = threadIdx.x;

    // --- self-sniff (all blocks; identical result) ---
    const unsigned short* xr = (const unsigned short*)x_;
    int cnt = 0;
    for (int i = tid; i < 2048; i += 256) {
        int e = (xr[i] >> 7) & 0xFF;
        if (e >= 134) cnt++;
    }
    for (int o = 1; o < 64; o <<= 1) cnt += __shfl_xor(cnt, o, 64);
    __shared__ int sh[4];
    __shared__ float part[4][4];
    if ((tid & 63) == 0) sh[tid >> 6] = cnt;
    __syncthreads();
    int f = (sh[0] + sh[1] + sh[2] + sh[3] >= 32) ? 1 : 0;

    if (bid >= 2048) {
        // ------------------------------ prep role ------------------------------
        int pb = bid - 2048;
        if (pb == 0 && tid == 0) *flag = f;
        const int sizes[15] = {4096, 256, 16, 2304, 16, 512, 512, 1024, 1024,
                               256, 256, 256, 256, 256, 256};
        int i = pb * 256 + tid;
        if (i < W_TOTAL) {
            int seg = 0, off = 0;
            while (i >= off + sizes[seg]) { off += sizes[seg]; seg++; }
            int j = i - off;
            float v = f ? ((const float*)wp.p[seg])[j]
                        : bf2f(((const __hip_bfloat16*)wp.p[seg])[j]);
            wc[i] = __float2bfloat16(v);
        }
        if (i < 3584) stats[1024 + i] = 0.f;   // zero sums2 + sums345
        return;
    }

    // ------------------------------ LIF+Haar role ------------------------------
    int half = bid & 1;
    int c = (bid >> 1) & 255;
    int b = bid >> 9;
    int wp_ = tid & 15;
    int hl = tid >> 4;
    int h = half * 16 + hl;
    const float* xf = (const float*)x_;
    const unsigned int* xb = (const unsigned int*)x_;
    int n = ((b * 256 + c) * 32 + h) * 32 + 2 * wp_;

    float v0 = 0.f, v1 = 0.f;
    float aL = 0.f, qL = 0.f, aH = 0.f, qH = 0.f;
    #pragma unroll
    for (int t = 0; t < T_; ++t) {
        size_t idx = (size_t)t * 1048576 + n;
        float x0, x1;
        if (f) {
            float2 xx = *(const float2*)(xf + idx);
            x0 = xx.x; x1 = xx.y;
        } else {
            unsigned int u = xb[idx >> 1];
            x0 = __uint_as_float(u << 16);
            x1 = __uint_as_float(u & 0xffff0000u);
        }
        v0 += (x0 - v0) * 0.5f;
        v1 += (x1 - v1) * 0.5f;
        float s0 = (v0 >= 1.f) ? 1.f : 0.f;
        float s1 = (v1 >= 1.f) ? 1.f : 0.f;
        v0 *= (1.f - s0);
        v1 *= (1.f - s1);
        int tb = t * 4 + b;
        ((uchar2*)s)[(size_t)(tb * 256 + c) * 512 + h * 16 + wp_] =
            make_uchar2((unsigned char)s0, (unsigned char)s1);
        float cl = s0 + s1, ch = s0 - s1;
        size_t lb = (((size_t)tb * 512 + c) * 32 + h) * 16 + wp_;
        l1[lb] = (signed char)(int)cl;
        l1[lb + (size_t)256 * 512] = (signed char)(int)ch;
        aL += cl; qL += cl * cl; aH += ch; qH += ch * ch;
    }
    for (int o = 1; o < 64; o <<= 1) {
        aL += __shfl_xor(aL, o, 64); qL += __shfl_xor(qL, o, 64);
        aH += __shfl_xor(aH, o, 64); qH += __shfl_xor(qH, o, 64);
    }
    int lane = tid & 63, wv = tid >> 6;
    if (lane == 0) {
        part[wv][0] = aL; part[wv][1] = qL; part[wv][2] = aH; part[wv][3] = qH;
    }
    __syncthreads();
    if (tid < 4) {
        float tot = part[0][tid] + part[1][tid] + part[2][tid] + part[3][tid];
        // parts1[slot][which][c]; slot = b*2+half, which: 0=aL 1=qL 2=aH 3=qH
        stats[P1OFF + ((b * 2 + half) * 4 + tid) * 256 + c] = tot;
    }
}

// ---------------------------------------------------------------------------
// K2 k_work: bids [0,256) = conv role (MFMA implicit GEMM -> c1/c2 stores +
// BN4/5 sums); bids [256,4352) = stage2 role (BN1-apply + Haar-H + gates ->
// l2, BN2 sums). BN1 coefficients derived by summing the 8 parts1 slots.
// ---------------------------------------------------------------------------
struct SharedU {
    union {
        struct {
            short lo[1025 * 8];            // channel-last bf16, d 0..7 (+zero row)
            short hi[1025 * 8];            // d 8..15
            unsigned short w2s[2304];      // [k][d*9+tap]
            unsigned short w1s[256];       // [k][d]
            unsigned short bs[32];         // B1 | B2
            float parts[4][4][16];         // [wv][g][r*4+which]
        } cv;
        struct {
            float lo[512];
            float hi[512];
            float part[4][8];
        } s2;
    };
};

__global__ __launch_bounds__(256) void k_work(const unsigned char* __restrict__ s,
                                              const signed char* __restrict__ l1,
                                              const __hip_bfloat16* __restrict__ wc,
                                              float* __restrict__ stats,
                                              __hip_bfloat16* __restrict__ l2,
                                              __hip_bfloat16* __restrict__ c1,
                                              __hip_bfloat16* __restrict__ c2) {
    __shared__ SharedU sm;
    int bid = blockIdx.x;
    int tid = threadIdx.x;
    int lane = tid & 63, wv = tid >> 6;

    if (bid < 256) {
        // ------------------------------ conv role ------------------------------
        int img = bid;
        const unsigned short* wr = (const unsigned short*)wc;
        for (int i = tid; i < 2304; i += 256) sm.cv.w2s[i] = wr[OFF_W2 + i];
        sm.cv.w1s[tid] = wr[OFF_W1 + tid];
        if (tid < 16) { sm.cv.bs[tid] = wr[OFF_B1 + tid]; sm.cv.bs[16 + tid] = wr[OFF_B2 + tid]; }
        // zero row (pixel index 1024)
        if (tid < 8) {
            ((unsigned int*)sm.cv.lo)[4096 + (tid & 3)] = 0;
            ((unsigned int*)sm.cv.hi)[4096 + (tid & 3)] = 0;
        }
        // stage planar u8 -> LDS channel-last bf16
        {
            const unsigned int* sp = (const unsigned int*)(s + (size_t)img * 16384);
            int d2 = tid >> 5;               // channel pair 2*d2, 2*d2+1
            int pg = tid & 31;
            unsigned int* dst = (unsigned int*)((d2 < 4) ? sm.cv.lo : sm.cv.hi);
            int dl = d2 & 3;
            #pragma unroll
            for (int p = 0; p < 8; ++p) {
                int base = p * 32 + pg;      // dword index within a channel row
                unsigned int u0 = sp[d2 * 512 + base];
                unsigned int u1 = sp[d2 * 512 + 256 + base];
                #pragma unroll
                for (int jj = 0; jj < 4; ++jj) {
                    int j = (jj + pg) & 3;   // scramble to spread LDS banks
                    unsigned int b0 = (u0 >> (8 * j)) & 255u;
                    unsigned int b1 = (u1 >> (8 * j)) & 255u;
                    unsigned int val = (b0 ? 0x3F80u : 0u) | ((b1 ? 0x3F80u : 0u) << 16);
                    int pix = p * 128 + pg * 4 + j;
                    dst[pix * 4 + dl] = val;
                }
            }
        }
        __syncthreads();

        int m = lane & 15;
        int g = lane >> 4;
        const int tapA[5] = {0, 2, 4, 6, 8};
        const int tapB[5] = {1, 3, 5, 7, 8};

        short8 afr[5], a1f;
        #pragma unroll
        for (int p = 0; p < 5; ++p) {
            int tap = (g < 2) ? tapA[p] : tapB[p];
            short8 av;
            #pragma unroll
            for (int j = 0; j < 8; ++j) {
                int d = (g & 1) * 8 + j;
                unsigned short w = sm.cv.w2s[m * 144 + d * 9 + tap];
                if (p == 4 && g >= 2) w = 0;
                av[j] = (short)w;
            }
            afr[p] = av;
        }
        #pragma unroll
        for (int j = 0; j < 8; ++j) {
            int d = (g & 1) * 8 + j;
            a1f[j] = (g < 2) ? (short)sm.cv.w1s[m * 16 + d] : (short)0;
        }
        float bias1[4], bias2[4];
        #pragma unroll
        for (int r = 0; r < 4; ++r) {
            bias1[r] = bfu(sm.cv.bs[g * 4 + r]);
            bias2[r] = bfu(sm.cv.bs[16 + g * 4 + r]);
        }

        __hip_bfloat16* o1 = c1 + (size_t)img * 16384;
        __hip_bfloat16* o2 = c2 + (size_t)img * 16384;
        const short* bsrc = (g & 1) ? sm.cv.hi : sm.cv.lo;

        float cs1[4] = {0, 0, 0, 0}, cq1[4] = {0, 0, 0, 0};
        float cs2[4] = {0, 0, 0, 0}, cq2[4] = {0, 0, 0, 0};

        for (int t = wv * 16; t < wv * 16 + 16; ++t) {
            int h = t >> 1;
            int w0 = (t & 1) << 4;
            f32x4 acc2 = {0.f, 0.f, 0.f, 0.f};
            f32x4 acc1 = {0.f, 0.f, 0.f, 0.f};
            #pragma unroll
            for (int p = 0; p < 5; ++p) {
                int tap = (g < 2) ? tapA[p] : tapB[p];
                int row = h + tap / 3 - 1;
                int col = w0 + m + (tap % 3) - 1;
                bool ok = ((unsigned)row < 32u) && ((unsigned)col < 32u);
                int idx = ok ? (row * 32 + col) : 1024;
                short8 bv = *(const short8*)&bsrc[idx * 8];
                acc2 = __builtin_amdgcn_mfma_f32_16x16x32_bf16(afr[p], bv, acc2, 0, 0, 0);
                if (p == 2)
                    acc1 = __builtin_amdgcn_mfma_f32_16x16x32_bf16(a1f, bv, acc1, 0, 0, 0);
            }
            int pix = h * 32 + w0 + m;
            #pragma unroll
            for (int r = 0; r < 4; ++r) {
                int k = g * 4 + r;
                float y1 = acc1[r] + bias1[r];
                float y2 = acc2[r] + bias2[r];
                o1[(size_t)k * 1024 + pix] = __float2bfloat16(y1);
                o2[(size_t)k * 1024 + pix] = __float2bfloat16(y2);
                cs1[r] += y1; cq1[r] += y1 * y1;
                cs2[r] += y2; cq2[r] += y2 * y2;
            }
        }
        // reduce across the 16 m-lanes (same g)
        #pragma unroll
        for (int o = 1; o < 16; o <<= 1) {
            #pragma unroll
            for (int r = 0; r < 4; ++r) {
                cs1[r] += __shfl_xor(cs1[r], o, 64);
                cq1[r] += __shfl_xor(cq1[r], o, 64);
                cs2[r] += __shfl_xor(cs2[r], o, 64);
                cq2[r] += __shfl_xor(cq2[r], o, 64);
            }
        }
        if (m == 0) {
            #pragma unroll
            for (int r = 0; r < 4; ++r) {
                sm.cv.parts[wv][g][r * 4 + 0] = cs1[r];
                sm.cv.parts[wv][g][r * 4 + 1] = cq1[r];
                sm.cv.parts[wv][g][r * 4 + 2] = cs2[r];
                sm.cv.parts[wv][g][r * 4 + 3] = cq2[r];
            }
        }
        __syncthreads();
        if (tid < 64) {
            int gg = tid >> 4, r = (tid >> 2) & 3, which = tid & 3;
            float tot = sm.cv.parts[0][gg][r * 4 + which] + sm.cv.parts[1][gg][r * 4 + which]
                      + sm.cv.parts[2][gg][r * 4 + which] + sm.cv.parts[3][gg][r * 4 + which];
            int ch = (img & 15) * 16 + gg * 4 + r;   // global BN channel
            // stats: sums4_sum@3584 sums4_sq@3840 sums5_sum@4096 sums5_sq@4352
            const int base[4] = {3584, 3840, 4096, 4352};
            atomicAdd(&stats[base[which] + ch], tot);
        }
    } else {
        // ------------------------------ stage2 role ------------------------------
        int blk = bid - 256;                  // TB*C = 4096
        int c = blk & 255;
        int tb = blk >> 8;

        // BN1 raw sums: sum the 8 parts1 slots
        const float* p1 = stats + P1OFF;
        float aLs = 0.f, qLs = 0.f, aHs = 0.f, qHs = 0.f;
        #pragma unroll
        for (int slot = 0; slot < 8; ++slot) {
            aLs += p1[(slot * 4 + 0) * 256 + c];
            qLs += p1[(slot * 4 + 1) * 256 + c];
            aHs += p1[(slot * 4 + 2) * 256 + c];
            qHs += p1[(slot * 4 + 3) * 256 + c];
        }

        const float nrm = 1.f / 8192.f;
        float mL = aLs * INVS2 * nrm;
        float vL = fmaxf(qLs * 0.5f * nrm - mL * mL, 0.f);
        float sL = bf2f(wc[OFF_G1 + c]) * rsqrtf(vL + EPSBN);
        float tL = bf2f(wc[OFF_BE1 + c]) - mL * sL;
        float mH = aHs * INVS2 * nrm;
        float vH = fmaxf(qHs * 0.5f * nrm - mH * mH, 0.f);
        float sH = bf2f(wc[OFF_G1 + 256 + c]) * rsqrtf(vH + EPSBN);
        float tH = bf2f(wc[OFF_BE1 + 256 + c]) - mH * sH;

        const signed char* plo = l1 + (((size_t)tb * 512) + c) * (H_ * Wh_);
        const signed char* phi = l1 + (((size_t)tb * 512) + 256 + c) * (H_ * Wh_);
        float slo = sL * INVS2, shi = sH * INVS2;
        sm.s2.lo[tid & 511] = 0.f;            // placate compiler aliasing; overwritten below
        {
            sm.s2.lo[tid]       = (float)plo[tid] * slo + tL;
            sm.s2.hi[tid]       = (float)phi[tid] * shi + tH;
            sm.s2.lo[tid + 256] = (float)plo[tid + 256] * slo + tL;
            sm.s2.hi[tid + 256] = (float)phi[tid + 256] * shi + tH;
        }
        __syncthreads();

        int w = tid & 15, v = tid >> 4;
        float a = sm.s2.lo[(2 * v) * Wh_ + w], b = sm.s2.lo[(2 * v + 1) * Wh_ + w];
        float zLL = (a + b) * INVS2;
        float zHL = (a - b) * INVS2;
        a = sm.s2.hi[(2 * v) * Wh_ + w]; b = sm.s2.hi[(2 * v + 1) * Wh_ + w];
        float zLH = (a + b) * INVS2;
        float zHH = (a - b) * INVS2;
        zLL = (fabsf(zLL) - 0.5f >= 0.f) ? zLL : 0.f;
        zHL = (fabsf(zHL) - 0.5f >= 0.f) ? zHL : 0.f;
        zLH = (fabsf(zLH) - 0.5f >= 0.f) ? zLH : 0.f;
        zHH = (fabsf(zHH) - 0.5f >= 0.f) ? zHH : 0.f;

        float r0 = zLL, r1 = zHL, r2 = zLH, r3 = zHH;
        float q0 = zLL * zLL, q1 = zHL * zHL, q2 = zLH * zLH, q3 = zHH * zHH;
        for (int o = 1; o < 64; o <<= 1) {
            r0 += __shfl_xor(r0, o, 64); r1 += __shfl_xor(r1, o, 64);
            r2 += __shfl_xor(r2, o, 64); r3 += __shfl_xor(r3, o, 64);
            q0 += __shfl_xor(q0, o, 64); q1 += __shfl_xor(q1, o, 64);
            q2 += __shfl_xor(q2, o, 64); q3 += __shfl_xor(q3, o, 64);
        }
        if (lane == 0) {
            sm.s2.part[wv][0] = r0; sm.s2.part[wv][1] = r1;
            sm.s2.part[wv][2] = r2; sm.s2.part[wv][3] = r3;
            sm.s2.part[wv][4] = q0; sm.s2.part[wv][5] = q1;
            sm.s2.part[wv][6] = q2; sm.s2.part[wv][7] = q3;
        }
        __syncthreads();
        float S0 = sm.s2.part[0][0] + sm.s2.part[1][0] + sm.s2.part[2][0] + sm.s2.part[3][0];
        float S1 = sm.s2.part[0][1] + sm.s2.part[1][1] + sm.s2.part[2][1] + sm.s2.part[3][1];
        float S2 = sm.s2.part[0][2] + sm.s2.part[1][2] + sm.s2.part[2][2] + sm.s2.part[3][2];
        float S3 = sm.s2.part[0][3] + sm.s2.part[1][3] + sm.s2.part[2][3] + sm.s2.part[3][3];
        float Q0 = sm.s2.part[0][4] + sm.s2.part[1][4] + sm.s2.part[2][4] + sm.s2.part[3][4];
        float Q1 = sm.s2.part[0][5] + sm.s2.part[1][5] + sm.s2.part[2][5] + sm.s2.part[3][5];
        float Q2 = sm.s2.part[0][6] + sm.s2.part[1][6] + sm.s2.part[2][6] + sm.s2.part[3][6];
        float Q3 = sm.s2.part[0][7] + sm.s2.part[1][7] + sm.s2.part[2][7] + sm.s2.part[3][7];
        float fLL = (Q0 * (1.f / 256.f) > 0.01f) ? 1.f : 0.f;
        float fHL = (Q1 * (1.f / 256.f) > 0.02f) ? 1.f : 0.f;
        float fLH = (Q2 * (1.f / 256.f) > 0.02f) ? 1.f : 0.f;
        float fHH = (Q3 * (1.f / 256.f) > 0.05f) ? 1.f : 0.f;

        float* sums2 = stats + 1024;
        if (tid < 8) {
            const int cho[8] = {0, 1024, 256, 1280, 512, 1536, 768, 1792};
            const float vals[8] = {fLL * S0, fLL * Q0, fHL * S1, fHL * Q1,
                                   fLH * S2, fLH * Q2, fHH * S3, fHH * Q3};
            atomicAdd(&sums2[cho[tid] + c], vals[tid]);
        }

        size_t ob = (((size_t)tb * 1024) + c) * 256 + tid;
        l2[ob]               = __float2bfloat16(zLL * fLL);
        l2[ob + 256u * 256u] = __float2bfloat16(zHL * fHL);
        l2[ob + 512u * 256u] = __float2bfloat16(zLH * fLH);
        l2[ob + 768u * 256u] = __float2bfloat16(zHH * fHH);
    }
}

// ---------------------------------------------------------------------------
// K3 k_mixinv: BN2-apply + block channel matmul + inverse Haar -> rec bf16;
// accumulates BN3 raw sums. Grid 1024 = tb(16) x cg(16) x ks(4): each block
// computes 4 of the 16 output channels (4 blocks/CU).
// ---------------------------------------------------------------------------
__global__ __launch_bounds__(256) void k_mixinv(const __hip_bfloat16* __restrict__ l2,
                                                const __hip_bfloat16* __restrict__ wc,
                                                float* __restrict__ stats,
                                                __hip_bfloat16* __restrict__ rec) {
    int bid = blockIdx.x;                 // 1024 = tb(16) * cg(16) * ks(4)
    int ks = bid & 3;
    int cg = (bid >> 2) & 15;
    int tb = bid >> 6;
    int tid = threadIdx.x;
    int lane = tid & 63, wvv = tid >> 6;
    const float* sums2 = stats + 1024;

    __shared__ float wt[4][16][4];        // [q][d][kk] for k = ks*4+kk
    __shared__ float bsc[64], bsh[64];
    __shared__ float parts2[4][8];
    {
        int i = tid;                      // 256 entries = q(4) * d(16) * kk(4)
        int q = i >> 6, rem = i & 63, d = rem >> 2, kk = rem & 3;
        int nb = q * 4 + (cg >> 2);
        int k = ks * 4 + kk;
        wt[q][d][kk] = bf2f(wc[OFF_HW + nb * 256 + d * 16 + k]);
    }
    if (tid < 64) {
        int q = tid >> 4, d = tid & 15;
        int ch = q * 256 + cg * 16 + d;
        float m = sums2[ch] * (1.f / 4096.f);
        float var = fmaxf(sums2[1024 + ch] * (1.f / 4096.f) - m * m, 0.f);
        float sc = bf2f(wc[OFF_G2 + ch]) * rsqrtf(var + EPSBN);
        bsc[tid] = sc;
        bsh[tid] = bf2f(wc[OFF_BE2 + ch]) - m * sc;
    }
    __syncthreads();

    float h[4][4];
    #pragma unroll
    for (int q = 0; q < 4; ++q)
        #pragma unroll
        for (int kk = 0; kk < 4; ++kk) h[q][kk] = 0.f;

    int p = tid;
    #pragma unroll
    for (int q = 0; q < 4; ++q) {
        const __hip_bfloat16* base =
            l2 + ((size_t)tb * 1024 + q * 256 + cg * 16) * 256 + p;
        #pragma unroll
        for (int d = 0; d < 16; ++d) {
            float xv = bf2f(base[d * 256]) * bsc[q * 16 + d] + bsh[q * 16 + d];
            #pragma unroll
            for (int kk = 0; kk < 4; ++kk)
                h[q][kk] = fmaf(xv, wt[q][d][kk], h[q][kk]);
        }
    }

    int uh = tid >> 4, uw = tid & 15;
    __hip_bfloat16* ob = rec + ((size_t)tb * 256 + cg * 16) * 1024;
    float sk[4], qk[4];
    #pragma unroll
    for (int kk = 0; kk < 4; ++kk) {
        int k = ks * 4 + kk;
        float LL = h[0][kk], HL = h[1][kk], LH = h[2][kk], HH = h[3][kk];
        float v00 = 0.5f * (LL + HL + LH + HH);
        float v01 = 0.5f * (LL + HL - LH - HH);
        float v10 = 0.5f * (LL - HL + LH - HH);
        float v11 = 0.5f * (LL - HL - LH + HH);
        __hip_bfloat162 top, bot;
        top.x = __float2bfloat16(v00); top.y = __float2bfloat16(v01);
        bot.x = __float2bfloat16(v10); bot.y = __float2bfloat16(v11);
        *(__hip_bfloat162*)(ob + (size_t)k * 1024 + (2 * uh) * 32 + 2 * uw) = top;
        *(__hip_bfloat162*)(ob + (size_t)k * 1024 + (2 * uh + 1) * 32 + 2 * uw) = bot;
        sk[kk] = v00 + v01 + v10 + v11;
        qk[kk] = v00 * v00 + v01 * v01 + v10 * v10 + v11 * v11;
    }
    for (int o = 1; o < 64; o <<= 1) {
        #pragma unroll
        for (int kk = 0; kk < 4; ++kk) {
            sk[kk] += __shfl_xor(sk[kk], o, 64);
            qk[kk] += __shfl_xor(qk[kk], o, 64);
        }
    }
    if (lane == 0) {
        #pragma unroll
        for (int kk = 0; kk < 4; ++kk) {
            parts2[wvv][kk * 2]     = sk[kk];
            parts2[wvv][kk * 2 + 1] = qk[kk];
        }
    }
    __syncthreads();
    if (tid < 8) {
        int kk = tid >> 1, which = tid & 1;
        float tot = parts2[0][tid] + parts2[1][tid] + parts2[2][tid] + parts2[3][tid];
        atomicAdd(&stats[3072 + which * 256 + cg * 16 + ks * 4 + kk], tot);
    }
}

// ---------------------------------------------------------------------------
// K4 k_final: elementwise combine at 8192 blocks (pure-BW regime); derives
// BN3/4/5 coefficients from raw sums (block-uniform per half-channel).
// ---------------------------------------------------------------------------
__global__ __launch_bounds__(256) void k_final(const __hip_bfloat16* __restrict__ rec,
                                               const __hip_bfloat16* __restrict__ c1,
                                               const __hip_bfloat16* __restrict__ c2,
                                               const float* __restrict__ stats,
                                               const __hip_bfloat16* __restrict__ wc,
                                               const int* __restrict__ flag,
                                               void* __restrict__ out_) {
    int n2 = blockIdx.x * 256 + threadIdx.x;    // bf162 index
    int c = ((n2 * 2) >> 10) & 255;
    const float inv = 1.f / 16384.f;
    float m3 = stats[3072 + c] * inv;
    float v3 = fmaxf(stats[3328 + c] * inv - m3 * m3, 0.f);
    float sc3 = bf2f(wc[OFF_G3 + c]) * rsqrtf(v3 + EPSBN);
    float sh3 = bf2f(wc[OFF_BE3 + c]) - m3 * sc3;
    float m4 = stats[3584 + c] * inv;
    float v4 = fmaxf(stats[3840 + c] * inv - m4 * m4, 0.f);
    float sc4 = bf2f(wc[OFF_G4 + c]) * rsqrtf(v4 + EPSBN);
    float sh4 = bf2f(wc[OFF_BE4 + c]) - m4 * sc4;
    float m5 = stats[4096 + c] * inv;
    float v5 = fmaxf(stats[4352 + c] * inv - m5 * m5, 0.f);
    float sc5 = bf2f(wc[OFF_G5 + c]) * rsqrtf(v5 + EPSBN);
    float sh5 = bf2f(wc[OFF_BE5 + c]) - m5 * sc5;

    __hip_bfloat162 r = ((const __hip_bfloat162*)rec)[n2];
    __hip_bfloat162 a = ((const __hip_bfloat162*)c1)[n2];
    __hip_bfloat162 b = ((const __hip_bfloat162*)c2)[n2];
    float v0 = bf2f(r.x) * sc3 + sh3 + bf2f(a.x) * sc4 + sh4 + bf2f(b.x) * sc5 + sh5;
    float v1 = bf2f(r.y) * sc3 + sh3 + bf2f(a.y) * sc4 + sh4 + bf2f(b.y) * sc5 + sh5;
    if (*flag) {
        ((float2*)out_)[n2] = make_float2(v0, v1);
    } else {
        __hip_bfloat162 o;
        o.x = __float2bfloat16(v0); o.y = __float2bfloat16(v1);
        ((__hip_bfloat162*)out_)[n2] = o;
    }
}

// ---------------------------------------------------------------------------
// Workspace map:
//   [0,4M):   s (planar u8 spikes)      [4,8M):  l1 (i8 codes)
//   [8,16M):  l2                        [16,24M): rec
//   [24,32M): c1                        [32,40M): c2
//   [40M..):  weight arena, stats(12800 fl incl parts1), flag
// ---------------------------------------------------------------------------
extern "C" void kernel_launch(void* const* d_in, const int* in_sizes, int n_in,
                              void* d_out, int out_size, void* d_ws, size_t ws_size,
                              hipStream_t stream) {
    char* ws = (char*)d_ws;
    unsigned char* s_u8  = (unsigned char*)ws;
    signed char* l1c     = (signed char*)(ws + ((size_t)4 << 20));
    __hip_bfloat16* l2   = (__hip_bfloat16*)(ws + ((size_t)8 << 20));
    __hip_bfloat16* rec  = (__hip_bfloat16*)(ws + ((size_t)16 << 20));
    __hip_bfloat16* c1   = (__hip_bfloat16*)(ws + ((size_t)24 << 20));
    __hip_bfloat16* c2   = (__hip_bfloat16*)(ws + ((size_t)32 << 20));
    __hip_bfloat16* wc   = (__hip_bfloat16*)(ws + ((size_t)40 << 20));
    float* stats         = (float*)(ws + ((size_t)40 << 20) + (64 << 10));
    int* flag            = (int*)(ws + ((size_t)40 << 20) + (128 << 10));

    WPtrs wp;
    for (int i = 0; i < 15; ++i) wp.p[i] = d_in[i + 1];

    dim3 blk(256);
    k_lifprep<<<dim3(2093), blk, 0, stream>>>(d_in[0], wp, wc, stats, flag, s_u8, l1c);
    k_work<<<dim3(4352), blk, 0, stream>>>(s_u8, l1c, wc, stats, l2, c1, c2);
    k_mixinv<<<dim3(1024), blk, 0, stream>>>(l2, wc, stats, rec);
    k_final<<<dim3(8192), blk, 0, stream>>>(rec, c1, c2, stats, wc, flag, d_out);
}

// Round 6
// 143.123 us; speedup vs baseline: 1.1152x; 1.0186x over previous
//
#include <hip/hip_runtime.h>
#include <hip/hip_bf16.h>

#define T_ 4
#define B_ 4
#define C_ 256
#define H_ 32
#define W_ 32
#define TB_ 16
#define Hh_ 16
#define Wh_ 16
#define INVS2 0.70710678118654752440f
#define EPSBN 1e-5f

// Canonical weight arena offsets (bf16 elements)
#define OFF_HW   0
#define OFF_W1   4096
#define OFF_B1   4352
#define OFF_W2   4368
#define OFF_B2   6672
#define OFF_G1   6688
#define OFF_BE1  7200
#define OFF_G2   7712
#define OFF_BE2  8736
#define OFF_G3   9760
#define OFF_BE3  10016
#define OFF_G4   10272
#define OFF_BE4  10528
#define OFF_G5   10784
#define OFF_BE5  11040
#define W_TOTAL  11296
// stats arena (floats):
//   [0..1024)   unused (legacy sums1 slot, kept for layout stability)
//   [1024..3072) sums2 (BN2)        — zeroed by prep role, atomics in k_work
//   [3072..4608) sums345 (BN3/4/5)  — zeroed by prep role, atomics later
//   [4608..12800) parts1[8][4][256] — written unconditionally by lifhaar role
#define NSUMS    4608
#define P1OFF    4608

struct WPtrs { const void* p[15]; };

typedef __attribute__((ext_vector_type(8))) short short8;
typedef __attribute__((ext_vector_type(4))) float f32x4;

__device__ inline float bf2f(__hip_bfloat16 v) { return __bfloat162float(v); }
__device__ inline float bfu(unsigned short u) { return __uint_as_float((unsigned)u << 16); }

// ---------------------------------------------------------------------------
// K1 k_lifprep: grid 2093.
//   bids [0,2048): LIF + Haar-W role (self-sniffed dtype flag; BN1 partials
//                  written to private slots — no atomics, no pre-zero needed).
//   bids [2048,2093): prep role — convert weights to bf16 arena, zero
//                  sums2/sums345, block 2048 publishes flag for later kernels.
// ---------------------------------------------------------------------------
__global__ __launch_bounds__(256) void k_lifprep(const void* __restrict__ x_,
                                                 WPtrs wp,
                                                 __hip_bfloat16* __restrict__ wc,
                                                 float* __restrict__ stats,
                                                 int* __restrict__ flag,
                                                 unsigned char* __restrict__ s,
                                                 signed char* __restrict__ l1) {
    int bid = blockIdx.x;
    int tid = threadIdx.x;

    // --- self-sniff (all blocks; identical result) ---
    const unsigned short* xr = (const unsigned short*)x_;
    int cnt = 0;
    for (int i = tid; i < 2048; i += 256) {
        int e = (xr[i] >> 7) & 0xFF;
        if (e >= 134) cnt++;
    }
    for (int o = 1; o < 64; o <<= 1) cnt += __shfl_xor(cnt, o, 64);
    __shared__ int sh[4];
    __shared__ float part[4][4];
    if ((tid & 63) == 0) sh[tid >> 6] = cnt;
    __syncthreads();
    int f = (sh[0] + sh[1] + sh[2] + sh[3] >= 32) ? 1 : 0;

    if (bid >= 2048) {
        // ------------------------------ prep role ------------------------------
        int pb = bid - 2048;
        if (pb == 0 && tid == 0) *flag = f;
        const int sizes[15] = {4096, 256, 16, 2304, 16, 512, 512, 1024, 1024,
                               256, 256, 256, 256, 256, 256};
        int i = pb * 256 + tid;
        if (i < W_TOTAL) {
            int seg = 0, off = 0;
            while (i >= off + sizes[seg]) { off += sizes[seg]; seg++; }
            int j = i - off;
            float v = f ? ((const float*)wp.p[seg])[j]
                        : bf2f(((const __hip_bfloat16*)wp.p[seg])[j]);
            wc[i] = __float2bfloat16(v);
        }
        if (i < 3584) stats[1024 + i] = 0.f;   // zero sums2 + sums345
        return;
    }

    // ------------------------------ LIF+Haar role ------------------------------
    int half = bid & 1;
    int c = (bid >> 1) & 255;
    int b = bid >> 9;
    int wp_ = tid & 15;
    int hl = tid >> 4;
    int h = half * 16 + hl;
    const float* xf = (const float*)x_;
    const unsigned int* xb = (const unsigned int*)x_;
    int n = ((b * 256 + c) * 32 + h) * 32 + 2 * wp_;

    float v0 = 0.f, v1 = 0.f;
    float aL = 0.f, qL = 0.f, aH = 0.f, qH = 0.f;
    #pragma unroll
    for (int t = 0; t < T_; ++t) {
        size_t idx = (size_t)t * 1048576 + n;
        float x0, x1;
        if (f) {
            float2 xx = *(const float2*)(xf + idx);
            x0 = xx.x; x1 = xx.y;
        } else {
            unsigned int u = xb[idx >> 1];
            x0 = __uint_as_float(u << 16);
            x1 = __uint_as_float(u & 0xffff0000u);
        }
        v0 += (x0 - v0) * 0.5f;
        v1 += (x1 - v1) * 0.5f;
        float s0 = (v0 >= 1.f) ? 1.f : 0.f;
        float s1 = (v1 >= 1.f) ? 1.f : 0.f;
        v0 *= (1.f - s0);
        v1 *= (1.f - s1);
        int tb = t * 4 + b;
        ((uchar2*)s)[(size_t)(tb * 256 + c) * 512 + h * 16 + wp_] =
            make_uchar2((unsigned char)s0, (unsigned char)s1);
        float cl = s0 + s1, ch = s0 - s1;
        size_t lb = (((size_t)tb * 512 + c) * 32 + h) * 16 + wp_;
        l1[lb] = (signed char)(int)cl;
        l1[lb + (size_t)256 * 512] = (signed char)(int)ch;
        aL += cl; qL += cl * cl; aH += ch; qH += ch * ch;
    }
    for (int o = 1; o < 64; o <<= 1) {
        aL += __shfl_xor(aL, o, 64); qL += __shfl_xor(qL, o, 64);
        aH += __shfl_xor(aH, o, 64); qH += __shfl_xor(qH, o, 64);
    }
    int lane = tid & 63, wv = tid >> 6;
    if (lane == 0) {
        part[wv][0] = aL; part[wv][1] = qL; part[wv][2] = aH; part[wv][3] = qH;
    }
    __syncthreads();
    if (tid < 4) {
        float tot = part[0][tid] + part[1][tid] + part[2][tid] + part[3][tid];
        // parts1[slot][which][c]; slot = b*2+half, which: 0=aL 1=qL 2=aH 3=qH
        stats[P1OFF + ((b * 2 + half) * 4 + tid) * 256 + c] = tot;
    }
}

// ---------------------------------------------------------------------------
// K2 k_work: bids [0,256) = conv role (MFMA implicit GEMM -> interleaved
// cc=(y1,y2) bf162 stores + BN4/5 sums); bids [256,4352) = stage2 role
// (BN1-apply + Haar-H + gates -> l2, BN2 sums; vectorized int l1 loads).
// BN1 coefficients derived by summing the 8 parts1 slots.
// ---------------------------------------------------------------------------
struct SharedU {
    union {
        struct {
            short lo[1025 * 8];            // channel-last bf16, d 0..7 (+zero row)
            short hi[1025 * 8];            // d 8..15
            unsigned short w2s[2304];      // [k][d*9+tap]
            unsigned short w1s[256];       // [k][d]
            unsigned short bs[32];         // B1 | B2
            float parts[4][4][16];         // [wv][g][r*4+which]
        } cv;
        struct {
            float lo[512];
            float hi[512];
            float part[4][8];
        } s2;
    };
};

__global__ __launch_bounds__(256) void k_work(const unsigned char* __restrict__ s,
                                              const signed char* __restrict__ l1,
                                              const __hip_bfloat16* __restrict__ wc,
                                              float* __restrict__ stats,
                                              __hip_bfloat16* __restrict__ l2,
                                              __hip_bfloat162* __restrict__ cc) {
    __shared__ SharedU sm;
    int bid = blockIdx.x;
    int tid = threadIdx.x;
    int lane = tid & 63, wv = tid >> 6;

    if (bid < 256) {
        // ------------------------------ conv role ------------------------------
        int img = bid;
        const unsigned short* wr = (const unsigned short*)wc;
        for (int i = tid; i < 2304; i += 256) sm.cv.w2s[i] = wr[OFF_W2 + i];
        sm.cv.w1s[tid] = wr[OFF_W1 + tid];
        if (tid < 16) { sm.cv.bs[tid] = wr[OFF_B1 + tid]; sm.cv.bs[16 + tid] = wr[OFF_B2 + tid]; }
        // zero row (pixel index 1024)
        if (tid < 8) {
            ((unsigned int*)sm.cv.lo)[4096 + (tid & 3)] = 0;
            ((unsigned int*)sm.cv.hi)[4096 + (tid & 3)] = 0;
        }
        // stage planar u8 -> LDS channel-last bf16
        {
            const unsigned int* sp = (const unsigned int*)(s + (size_t)img * 16384);
            int d2 = tid >> 5;               // channel pair 2*d2, 2*d2+1
            int pg = tid & 31;
            unsigned int* dst = (unsigned int*)((d2 < 4) ? sm.cv.lo : sm.cv.hi);
            int dl = d2 & 3;
            #pragma unroll
            for (int p = 0; p < 8; ++p) {
                int base = p * 32 + pg;      // dword index within a channel row
                unsigned int u0 = sp[d2 * 512 + base];
                unsigned int u1 = sp[d2 * 512 + 256 + base];
                #pragma unroll
                for (int jj = 0; jj < 4; ++jj) {
                    int j = (jj + pg) & 3;   // scramble to spread LDS banks
                    unsigned int b0 = (u0 >> (8 * j)) & 255u;
                    unsigned int b1 = (u1 >> (8 * j)) & 255u;
                    unsigned int val = (b0 ? 0x3F80u : 0u) | ((b1 ? 0x3F80u : 0u) << 16);
                    int pix = p * 128 + pg * 4 + j;
                    dst[pix * 4 + dl] = val;
                }
            }
        }
        __syncthreads();

        int m = lane & 15;
        int g = lane >> 4;
        const int tapA[5] = {0, 2, 4, 6, 8};
        const int tapB[5] = {1, 3, 5, 7, 8};

        short8 afr[5], a1f;
        #pragma unroll
        for (int p = 0; p < 5; ++p) {
            int tap = (g < 2) ? tapA[p] : tapB[p];
            short8 av;
            #pragma unroll
            for (int j = 0; j < 8; ++j) {
                int d = (g & 1) * 8 + j;
                unsigned short w = sm.cv.w2s[m * 144 + d * 9 + tap];
                if (p == 4 && g >= 2) w = 0;
                av[j] = (short)w;
            }
            afr[p] = av;
        }
        #pragma unroll
        for (int j = 0; j < 8; ++j) {
            int d = (g & 1) * 8 + j;
            a1f[j] = (g < 2) ? (short)sm.cv.w1s[m * 16 + d] : (short)0;
        }
        float bias1[4], bias2[4];
        #pragma unroll
        for (int r = 0; r < 4; ++r) {
            bias1[r] = bfu(sm.cv.bs[g * 4 + r]);
            bias2[r] = bfu(sm.cv.bs[16 + g * 4 + r]);
        }

        __hip_bfloat162* occ = cc + (size_t)img * 16384;
        const short* bsrc = (g & 1) ? sm.cv.hi : sm.cv.lo;

        float cs1[4] = {0, 0, 0, 0}, cq1[4] = {0, 0, 0, 0};
        float cs2[4] = {0, 0, 0, 0}, cq2[4] = {0, 0, 0, 0};

        for (int t = wv * 16; t < wv * 16 + 16; ++t) {
            int h = t >> 1;
            int w0 = (t & 1) << 4;
            f32x4 acc2 = {0.f, 0.f, 0.f, 0.f};
            f32x4 acc1 = {0.f, 0.f, 0.f, 0.f};
            #pragma unroll
            for (int p = 0; p < 5; ++p) {
                int tap = (g < 2) ? tapA[p] : tapB[p];
                int row = h + tap / 3 - 1;
                int col = w0 + m + (tap % 3) - 1;
                bool ok = ((unsigned)row < 32u) && ((unsigned)col < 32u);
                int idx = ok ? (row * 32 + col) : 1024;
                short8 bv = *(const short8*)&bsrc[idx * 8];
                acc2 = __builtin_amdgcn_mfma_f32_16x16x32_bf16(afr[p], bv, acc2, 0, 0, 0);
                if (p == 2)
                    acc1 = __builtin_amdgcn_mfma_f32_16x16x32_bf16(a1f, bv, acc1, 0, 0, 0);
            }
            int pix = h * 32 + w0 + m;
            #pragma unroll
            for (int r = 0; r < 4; ++r) {
                int k = g * 4 + r;
                float y1 = acc1[r] + bias1[r];
                float y2 = acc2[r] + bias2[r];
                __hip_bfloat162 pr;
                pr.x = __float2bfloat16(y1);
                pr.y = __float2bfloat16(y2);
                occ[(size_t)k * 1024 + pix] = pr;
                cs1[r] += y1; cq1[r] += y1 * y1;
                cs2[r] += y2; cq2[r] += y2 * y2;
            }
        }
        // reduce across the 16 m-lanes (same g)
        #pragma unroll
        for (int o = 1; o < 16; o <<= 1) {
            #pragma unroll
            for (int r = 0; r < 4; ++r) {
                cs1[r] += __shfl_xor(cs1[r], o, 64);
                cq1[r] += __shfl_xor(cq1[r], o, 64);
                cs2[r] += __shfl_xor(cs2[r], o, 64);
                cq2[r] += __shfl_xor(cq2[r], o, 64);
            }
        }
        if (m == 0) {
            #pragma unroll
            for (int r = 0; r < 4; ++r) {
                sm.cv.parts[wv][g][r * 4 + 0] = cs1[r];
                sm.cv.parts[wv][g][r * 4 + 1] = cq1[r];
                sm.cv.parts[wv][g][r * 4 + 2] = cs2[r];
                sm.cv.parts[wv][g][r * 4 + 3] = cq2[r];
            }
        }
        __syncthreads();
        if (tid < 64) {
            int gg = tid >> 4, r = (tid >> 2) & 3, which = tid & 3;
            float tot = sm.cv.parts[0][gg][r * 4 + which] + sm.cv.parts[1][gg][r * 4 + which]
                      + sm.cv.parts[2][gg][r * 4 + which] + sm.cv.parts[3][gg][r * 4 + which];
            int ch = (img & 15) * 16 + gg * 4 + r;   // global BN channel
            // stats: sums4_sum@3584 sums4_sq@3840 sums5_sum@4096 sums5_sq@4352
            const int base[4] = {3584, 3840, 4096, 4352};
            atomicAdd(&stats[base[which] + ch], tot);
        }
    } else {
        // ------------------------------ stage2 role ------------------------------
        int blk = bid - 256;                  // TB*C = 4096
        int c = blk & 255;
        int tb = blk >> 8;

        // BN1 raw sums: sum the 8 parts1 slots
        const float* p1 = stats + P1OFF;
        float aLs = 0.f, qLs = 0.f, aHs = 0.f, qHs = 0.f;
        #pragma unroll
        for (int slot = 0; slot < 8; ++slot) {
            aLs += p1[(slot * 4 + 0) * 256 + c];
            qLs += p1[(slot * 4 + 1) * 256 + c];
            aHs += p1[(slot * 4 + 2) * 256 + c];
            qHs += p1[(slot * 4 + 3) * 256 + c];
        }

        const float nrm = 1.f / 8192.f;
        float mL = aLs * INVS2 * nrm;
        float vL = fmaxf(qLs * 0.5f * nrm - mL * mL, 0.f);
        float sL = bf2f(wc[OFF_G1 + c]) * rsqrtf(vL + EPSBN);
        float tL = bf2f(wc[OFF_BE1 + c]) - mL * sL;
        float mH = aHs * INVS2 * nrm;
        float vH = fmaxf(qHs * 0.5f * nrm - mH * mH, 0.f);
        float sH = bf2f(wc[OFF_G1 + 256 + c]) * rsqrtf(vH + EPSBN);
        float tH = bf2f(wc[OFF_BE1 + 256 + c]) - mH * sH;

        const signed char* plo = l1 + (((size_t)tb * 512) + c) * (H_ * Wh_);
        const signed char* phi = l1 + (((size_t)tb * 512) + 256 + c) * (H_ * Wh_);
        float slo = sL * INVS2, shi = sH * INVS2;
        // vectorized: tid<128 unpack lo (128 ints = 512 i8), tid>=128 hi
        {
            int t2 = tid & 127;
            bool isLo = tid < 128;
            int v = isLo ? ((const int*)plo)[t2] : ((const int*)phi)[t2];
            float sc = isLo ? slo : shi;
            float tc = isLo ? tL : tH;
            float* dst = isLo ? sm.s2.lo : sm.s2.hi;
            f32x4 fv;
            #pragma unroll
            for (int j = 0; j < 4; ++j)
                fv[j] = (float)(signed char)((v >> (8 * j)) & 0xFF) * sc + tc;
            *(f32x4*)&dst[t2 * 4] = fv;
        }
        __syncthreads();

        int w = tid & 15, v = tid >> 4;
        float a = sm.s2.lo[(2 * v) * Wh_ + w], b = sm.s2.lo[(2 * v + 1) * Wh_ + w];
        float zLL = (a + b) * INVS2;
        float zHL = (a - b) * INVS2;
        a = sm.s2.hi[(2 * v) * Wh_ + w]; b = sm.s2.hi[(2 * v + 1) * Wh_ + w];
        float zLH = (a + b) * INVS2;
        float zHH = (a - b) * INVS2;
        zLL = (fabsf(zLL) - 0.5f >= 0.f) ? zLL : 0.f;
        zHL = (fabsf(zHL) - 0.5f >= 0.f) ? zHL : 0.f;
        zLH = (fabsf(zLH) - 0.5f >= 0.f) ? zLH : 0.f;
        zHH = (fabsf(zHH) - 0.5f >= 0.f) ? zHH : 0.f;

        float r0 = zLL, r1 = zHL, r2 = zLH, r3 = zHH;
        float q0 = zLL * zLL, q1 = zHL * zHL, q2 = zLH * zLH, q3 = zHH * zHH;
        for (int o = 1; o < 64; o <<= 1) {
            r0 += __shfl_xor(r0, o, 64); r1 += __shfl_xor(r1, o, 64);
            r2 += __shfl_xor(r2, o, 64); r3 += __shfl_xor(r3, o, 64);
            q0 += __shfl_xor(q0, o, 64); q1 += __shfl_xor(q1, o, 64);
            q2 += __shfl_xor(q2, o, 64); q3 += __shfl_xor(q3, o, 64);
        }
        if (lane == 0) {
            sm.s2.part[wv][0] = r0; sm.s2.part[wv][1] = r1;
            sm.s2.part[wv][2] = r2; sm.s2.part[wv][3] = r3;
            sm.s2.part[wv][4] = q0; sm.s2.part[wv][5] = q1;
            sm.s2.part[wv][6] = q2; sm.s2.part[wv][7] = q3;
        }
        __syncthreads();
        float S0 = sm.s2.part[0][0] + sm.s2.part[1][0] + sm.s2.part[2][0] + sm.s2.part[3][0];
        float S1 = sm.s2.part[0][1] + sm.s2.part[1][1] + sm.s2.part[2][1] + sm.s2.part[3][1];
        float S2 = sm.s2.part[0][2] + sm.s2.part[1][2] + sm.s2.part[2][2] + sm.s2.part[3][2];
        float S3 = sm.s2.part[0][3] + sm.s2.part[1][3] + sm.s2.part[2][3] + sm.s2.part[3][3];
        float Q0 = sm.s2.part[0][4] + sm.s2.part[1][4] + sm.s2.part[2][4] + sm.s2.part[3][4];
        float Q1 = sm.s2.part[0][5] + sm.s2.part[1][5] + sm.s2.part[2][5] + sm.s2.part[3][5];
        float Q2 = sm.s2.part[0][6] + sm.s2.part[1][6] + sm.s2.part[2][6] + sm.s2.part[3][6];
        float Q3 = sm.s2.part[0][7] + sm.s2.part[1][7] + sm.s2.part[2][7] + sm.s2.part[3][7];
        float fLL = (Q0 * (1.f / 256.f) > 0.01f) ? 1.f : 0.f;
        float fHL = (Q1 * (1.f / 256.f) > 0.02f) ? 1.f : 0.f;
        float fLH = (Q2 * (1.f / 256.f) > 0.02f) ? 1.f : 0.f;
        float fHH = (Q3 * (1.f / 256.f) > 0.05f) ? 1.f : 0.f;

        float* sums2 = stats + 1024;
        if (tid < 8) {
            const int cho[8] = {0, 1024, 256, 1280, 512, 1536, 768, 1792};
            const float vals[8] = {fLL * S0, fLL * Q0, fHL * S1, fHL * Q1,
                                   fLH * S2, fLH * Q2, fHH * S3, fHH * Q3};
            atomicAdd(&sums2[cho[tid] + c], vals[tid]);
        }

        size_t ob = (((size_t)tb * 1024) + c) * 256 + tid;
        l2[ob]               = __float2bfloat16(zLL * fLL);
        l2[ob + 256u * 256u] = __float2bfloat16(zHL * fHL);
        l2[ob + 512u * 256u] = __float2bfloat16(zLH * fLH);
        l2[ob + 768u * 256u] = __float2bfloat16(zHH * fHH);
    }
}

// ---------------------------------------------------------------------------
// K3 k_mixinv: BN2-apply + block channel matmul + inverse Haar -> rec bf16;
// accumulates BN3 raw sums. Grid 1024 = tb(16) x cg(16) x ks(4): each block
// computes 4 of the 16 output channels (4 blocks/CU).
// ---------------------------------------------------------------------------
__global__ __launch_bounds__(256) void k_mixinv(const __hip_bfloat16* __restrict__ l2,
                                                const __hip_bfloat16* __restrict__ wc,
                                                float* __restrict__ stats,
                                                __hip_bfloat16* __restrict__ rec) {
    int bid = blockIdx.x;                 // 1024 = tb(16) * cg(16) * ks(4)
    int ks = bid & 3;
    int cg = (bid >> 2) & 15;
    int tb = bid >> 6;
    int tid = threadIdx.x;
    int lane = tid & 63, wvv = tid >> 6;
    const float* sums2 = stats + 1024;

    __shared__ float wt[4][16][4];        // [q][d][kk] for k = ks*4+kk
    __shared__ float bsc[64], bsh[64];
    __shared__ float parts2[4][8];
    {
        int i = tid;                      // 256 entries = q(4) * d(16) * kk(4)
        int q = i >> 6, rem = i & 63, d = rem >> 2, kk = rem & 3;
        int nb = q * 4 + (cg >> 2);
        int k = ks * 4 + kk;
        wt[q][d][kk] = bf2f(wc[OFF_HW + nb * 256 + d * 16 + k]);
    }
    if (tid < 64) {
        int q = tid >> 4, d = tid & 15;
        int ch = q * 256 + cg * 16 + d;
        float m = sums2[ch] * (1.f / 4096.f);
        float var = fmaxf(sums2[1024 + ch] * (1.f / 4096.f) - m * m, 0.f);
        float sc = bf2f(wc[OFF_G2 + ch]) * rsqrtf(var + EPSBN);
        bsc[tid] = sc;
        bsh[tid] = bf2f(wc[OFF_BE2 + ch]) - m * sc;
    }
    __syncthreads();

    float h[4][4];
    #pragma unroll
    for (int q = 0; q < 4; ++q)
        #pragma unroll
        for (int kk = 0; kk < 4; ++kk) h[q][kk] = 0.f;

    int p = tid;
    #pragma unroll
    for (int q = 0; q < 4; ++q) {
        const __hip_bfloat16* base =
            l2 + ((size_t)tb * 1024 + q * 256 + cg * 16) * 256 + p;
        #pragma unroll
        for (int d = 0; d < 16; ++d) {
            float xv = bf2f(base[d * 256]) * bsc[q * 16 + d] + bsh[q * 16 + d];
            #pragma unroll
            for (int kk = 0; kk < 4; ++kk)
                h[q][kk] = fmaf(xv, wt[q][d][kk], h[q][kk]);
        }
    }

    int uh = tid >> 4, uw = tid & 15;
    __hip_bfloat16* ob = rec + ((size_t)tb * 256 + cg * 16) * 1024;
    float sk[4], qk[4];
    #pragma unroll
    for (int kk = 0; kk < 4; ++kk) {
        int k = ks * 4 + kk;
        float LL = h[0][kk], HL = h[1][kk], LH = h[2][kk], HH = h[3][kk];
        float v00 = 0.5f * (LL + HL + LH + HH);
        float v01 = 0.5f * (LL + HL - LH - HH);
        float v10 = 0.5f * (LL - HL + LH - HH);
        float v11 = 0.5f * (LL - HL - LH + HH);
        __hip_bfloat162 top, bot;
        top.x = __float2bfloat16(v00); top.y = __float2bfloat16(v01);
        bot.x = __float2bfloat16(v10); bot.y = __float2bfloat16(v11);
        *(__hip_bfloat162*)(ob + (size_t)k * 1024 + (2 * uh) * 32 + 2 * uw) = top;
        *(__hip_bfloat162*)(ob + (size_t)k * 1024 + (2 * uh + 1) * 32 + 2 * uw) = bot;
        sk[kk] = v00 + v01 + v10 + v11;
        qk[kk] = v00 * v00 + v01 * v01 + v10 * v10 + v11 * v11;
    }
    for (int o = 1; o < 64; o <<= 1) {
        #pragma unroll
        for (int kk = 0; kk < 4; ++kk) {
            sk[kk] += __shfl_xor(sk[kk], o, 64);
            qk[kk] += __shfl_xor(qk[kk], o, 64);
        }
    }
    if (lane == 0) {
        #pragma unroll
        for (int kk = 0; kk < 4; ++kk) {
            parts2[wvv][kk * 2]     = sk[kk];
            parts2[wvv][kk * 2 + 1] = qk[kk];
        }
    }
    __syncthreads();
    if (tid < 8) {
        int kk = tid >> 1, which = tid & 1;
        float tot = parts2[0][tid] + parts2[1][tid] + parts2[2][tid] + parts2[3][tid];
        atomicAdd(&stats[3072 + which * 256 + cg * 16 + ks * 4 + kk], tot);
    }
}

// ---------------------------------------------------------------------------
// K4 k_final: elementwise combine at 8192 blocks (pure-BW regime); derives
// BN3/4/5 coefficients from raw sums (block-uniform per half-channel).
// Reads rec (bf162) + interleaved cc=(y1,y2) pairs.
// ---------------------------------------------------------------------------
__global__ __launch_bounds__(256) void k_final(const __hip_bfloat16* __restrict__ rec,
                                               const __hip_bfloat162* __restrict__ cc,
                                               const float* __restrict__ stats,
                                               const __hip_bfloat16* __restrict__ wc,
                                               const int* __restrict__ flag,
                                               void* __restrict__ out_) {
    int n2 = blockIdx.x * 256 + threadIdx.x;    // bf162 index (2 output elems)
    int c = ((n2 * 2) >> 10) & 255;
    const float inv = 1.f / 16384.f;
    float m3 = stats[3072 + c] * inv;
    float v3 = fmaxf(stats[3328 + c] * inv - m3 * m3, 0.f);
    float sc3 = bf2f(wc[OFF_G3 + c]) * rsqrtf(v3 + EPSBN);
    float sh3 = bf2f(wc[OFF_BE3 + c]) - m3 * sc3;
    float m4 = stats[3584 + c] * inv;
    float v4 = fmaxf(stats[3840 + c] * inv - m4 * m4, 0.f);
    float sc4 = bf2f(wc[OFF_G4 + c]) * rsqrtf(v4 + EPSBN);
    float sh4 = bf2f(wc[OFF_BE4 + c]) - m4 * sc4;
    float m5 = stats[4096 + c] * inv;
    float v5 = fmaxf(stats[4352 + c] * inv - m5 * m5, 0.f);
    float sc5 = bf2f(wc[OFF_G5 + c]) * rsqrtf(v5 + EPSBN);
    float sh5 = bf2f(wc[OFF_BE5 + c]) - m5 * sc5;

    __hip_bfloat162 r = ((const __hip_bfloat162*)rec)[n2];
    __hip_bfloat162 pa = cc[2 * n2];        // (y1,y2) of elem 2*n2
    __hip_bfloat162 pb = cc[2 * n2 + 1];    // (y1,y2) of elem 2*n2+1
    float v0 = bf2f(r.x) * sc3 + sh3 + bf2f(pa.x) * sc4 + sh4 + bf2f(pa.y) * sc5 + sh5;
    float v1 = bf2f(r.y) * sc3 + sh3 + bf2f(pb.x) * sc4 + sh4 + bf2f(pb.y) * sc5 + sh5;
    if (*flag) {
        ((float2*)out_)[n2] = make_float2(v0, v1);
    } else {
        __hip_bfloat162 o;
        o.x = __float2bfloat16(v0); o.y = __float2bfloat16(v1);
        ((__hip_bfloat162*)out_)[n2] = o;
    }
}

// ---------------------------------------------------------------------------
// Workspace map:
//   [0,4M):   s (planar u8 spikes)      [4,8M):  l1 (i8 codes)
//   [8,16M):  l2                        [16,24M): rec
//   [24,40M): cc (interleaved y1,y2 bf162 pairs)
//   [40M..):  weight arena, stats(12800 fl incl parts1), flag
// ---------------------------------------------------------------------------
extern "C" void kernel_launch(void* const* d_in, const int* in_sizes, int n_in,
                              void* d_out, int out_size, void* d_ws, size_t ws_size,
                              hipStream_t stream) {
    char* ws = (char*)d_ws;
    unsigned char* s_u8  = (unsigned char*)ws;
    signed char* l1c     = (signed char*)(ws + ((size_t)4 << 20));
    __hip_bfloat16* l2   = (__hip_bfloat16*)(ws + ((size_t)8 << 20));
    __hip_bfloat16* rec  = (__hip_bfloat16*)(ws + ((size_t)16 << 20));
    __hip_bfloat162* cc  = (__hip_bfloat162*)(ws + ((size_t)24 << 20));
    __hip_bfloat16* wc   = (__hip_bfloat16*)(ws + ((size_t)40 << 20));
    float* stats         = (float*)(ws + ((size_t)40 << 20) + (64 << 10));
    int* flag            = (int*)(ws + ((size_t)40 << 20) + (128 << 10));

    WPtrs wp;
    for (int i = 0; i < 15; ++i) wp.p[i] = d_in[i + 1];

    dim3 blk(256);
    k_lifprep<<<dim3(2093), blk, 0, stream>>>(d_in[0], wp, wc, stats, flag, s_u8, l1c);
    k_work<<<dim3(4352), blk, 0, stream>>>(s_u8, l1c, wc, stats, l2, cc);
    k_mixinv<<<dim3(1024), blk, 0, stream>>>(l2, wc, stats, rec);
    k_final<<<dim3(8192), blk, 0, stream>>>(rec, cc, stats, wc, flag, d_out);
}

// Round 7
// 139.125 us; speedup vs baseline: 1.1472x; 1.0287x over previous
//
#include <hip/hip_runtime.h>
#include <hip/hip_bf16.h>

#define T_ 4
#define B_ 4
#define C_ 256
#define H_ 32
#define W_ 32
#define TB_ 16
#define Hh_ 16
#define Wh_ 16
#define INVS2 0.70710678118654752440f
#define EPSBN 1e-5f

// Canonical weight arena offsets (bf16 elements)
#define OFF_HW   0
#define OFF_W1   4096
#define OFF_B1   4352
#define OFF_W2   4368
#define OFF_B2   6672
#define OFF_G1   6688
#define OFF_BE1  7200
#define OFF_G2   7712
#define OFF_BE2  8736
#define OFF_G3   9760
#define OFF_BE3  10016
#define OFF_G4   10272
#define OFF_BE4  10528
#define OFF_G5   10784
#define OFF_BE5  11040
#define W_TOTAL  11296
// stats arena (floats):
//   [0..1024)   unused (legacy sums1 slot, kept for layout stability)
//   [1024..3072) sums2 (BN2)        — zeroed by prep role, atomics in k_work
//   [3072..4608) sums345 (BN3/4/5)  — zeroed by prep role, atomics later
//   [4608..8704) parts1[4][4][256]  — written unconditionally by lif role
#define NSUMS    4608
#define P1OFF    4608

struct WPtrs { const void* p[15]; };

typedef __attribute__((ext_vector_type(8))) short short8;
typedef __attribute__((ext_vector_type(4))) short s16x4;
typedef __attribute__((ext_vector_type(4))) float f32x4;

__device__ inline float bf2f(__hip_bfloat16 v) { return __bfloat162float(v); }
__device__ inline float bfu(unsigned short u) { return __uint_as_float((unsigned)u << 16); }
__device__ inline unsigned short f2bfu(float v) {
    union { __hip_bfloat16 h; unsigned short u; } c;
    c.h = __float2bfloat16(v);
    return c.u;
}

// ---------------------------------------------------------------------------
// K1 k_lifprep: grid 1069.
//   bids [0,1024): LIF + Haar-W role, 4 pixels/thread (vectorized x loads,
//                  uchar4 s stores, packed 2B l1 stores; BN1 partials to
//                  private slots — no atomics, no pre-zero needed).
//   bids [1024,1069): prep role — convert weights to bf16 arena, zero
//                  sums2/sums345, block 1024 publishes flag for later kernels.
// ---------------------------------------------------------------------------
__global__ __launch_bounds__(256) void k_lifprep(const void* __restrict__ x_,
                                                 WPtrs wp,
                                                 __hip_bfloat16* __restrict__ wc,
                                                 float* __restrict__ stats,
                                                 int* __restrict__ flag,
                                                 unsigned char* __restrict__ s,
                                                 signed char* __restrict__ l1) {
    int bid = blockIdx.x;
    int tid = threadIdx.x;

    // --- self-sniff (all blocks; identical result) ---
    const unsigned short* xr = (const unsigned short*)x_;
    int cnt = 0;
    for (int i = tid; i < 2048; i += 256) {
        int e = (xr[i] >> 7) & 0xFF;
        if (e >= 134) cnt++;
    }
    for (int o = 1; o < 64; o <<= 1) cnt += __shfl_xor(cnt, o, 64);
    __shared__ int sh[4];
    __shared__ float part[4][4];
    if ((tid & 63) == 0) sh[tid >> 6] = cnt;
    __syncthreads();
    int f = (sh[0] + sh[1] + sh[2] + sh[3] >= 32) ? 1 : 0;

    if (bid >= 1024) {
        // ------------------------------ prep role ------------------------------
        int pb = bid - 1024;
        if (pb == 0 && tid == 0) *flag = f;
        const int sizes[15] = {4096, 256, 16, 2304, 16, 512, 512, 1024, 1024,
                               256, 256, 256, 256, 256, 256};
        int i = pb * 256 + tid;
        if (i < W_TOTAL) {
            int seg = 0, off = 0;
            while (i >= off + sizes[seg]) { off += sizes[seg]; seg++; }
            int j = i - off;
            float v = f ? ((const float*)wp.p[seg])[j]
                        : bf2f(((const __hip_bfloat16*)wp.p[seg])[j]);
            wc[i] = __float2bfloat16(v);
        }
        if (i < 3584) stats[1024 + i] = 0.f;   // zero sums2 + sums345
        return;
    }

    // ------------------------------ LIF+Haar role ------------------------------
    int c = bid & 255;
    int b = bid >> 8;
    int wq = tid & 7;                     // 8 quads of 4 pixels per row
    int h = tid >> 3;                     // 32 rows
    const float* xf = (const float*)x_;
    int n = ((b * 256 + c) * 32 + h) * 32 + 4 * wq;

    float v0 = 0.f, v1 = 0.f, v2 = 0.f, v3 = 0.f;
    float aL = 0.f, qL = 0.f, aH = 0.f, qH = 0.f;
    #pragma unroll
    for (int t = 0; t < T_; ++t) {
        size_t idx = (size_t)t * 1048576 + n;
        float x0, x1, x2, x3;
        if (f) {
            float4 xx = *(const float4*)(xf + idx);
            x0 = xx.x; x1 = xx.y; x2 = xx.z; x3 = xx.w;
        } else {
            uint2 u = *(const uint2*)((const char*)x_ + idx * 2);
            x0 = __uint_as_float(u.x << 16);
            x1 = __uint_as_float(u.x & 0xffff0000u);
            x2 = __uint_as_float(u.y << 16);
            x3 = __uint_as_float(u.y & 0xffff0000u);
        }
        v0 += (x0 - v0) * 0.5f;
        v1 += (x1 - v1) * 0.5f;
        v2 += (x2 - v2) * 0.5f;
        v3 += (x3 - v3) * 0.5f;
        float s0 = (v0 >= 1.f) ? 1.f : 0.f;
        float s1 = (v1 >= 1.f) ? 1.f : 0.f;
        float s2 = (v2 >= 1.f) ? 1.f : 0.f;
        float s3 = (v3 >= 1.f) ? 1.f : 0.f;
        v0 *= (1.f - s0);
        v1 *= (1.f - s1);
        v2 *= (1.f - s2);
        v3 *= (1.f - s3);
        int tb = t * 4 + b;
        *(uchar4*)(s + (size_t)(tb * 256 + c) * 1024 + h * 32 + wq * 4) =
            make_uchar4((unsigned char)s0, (unsigned char)s1,
                        (unsigned char)s2, (unsigned char)s3);
        float cl0 = s0 + s1, ch0 = s0 - s1;
        float cl1 = s2 + s3, ch1 = s2 - s3;
        size_t lb = (((size_t)tb * 512 + c) * 32 + h) * 16 + 2 * wq;
        unsigned short plo = (unsigned short)((unsigned char)(signed char)(int)cl0 |
                                              ((unsigned char)(signed char)(int)cl1 << 8));
        unsigned short phi = (unsigned short)((unsigned char)(signed char)(int)ch0 |
                                              ((unsigned char)(signed char)(int)ch1 << 8));
        *(unsigned short*)(l1 + lb) = plo;
        *(unsigned short*)(l1 + lb + (size_t)256 * 512) = phi;
        aL += cl0 + cl1; qL += cl0 * cl0 + cl1 * cl1;
        aH += ch0 + ch1; qH += ch0 * ch0 + ch1 * ch1;
    }
    for (int o = 1; o < 64; o <<= 1) {
        aL += __shfl_xor(aL, o, 64); qL += __shfl_xor(qL, o, 64);
        aH += __shfl_xor(aH, o, 64); qH += __shfl_xor(qH, o, 64);
    }
    int lane = tid & 63, wv = tid >> 6;
    if (lane == 0) {
        part[wv][0] = aL; part[wv][1] = qL; part[wv][2] = aH; part[wv][3] = qH;
    }
    __syncthreads();
    if (tid < 4) {
        float tot = part[0][tid] + part[1][tid] + part[2][tid] + part[3][tid];
        // parts1[slot=b][which][c]; which: 0=aL 1=qL 2=aH 3=qH
        stats[P1OFF + (b * 4 + tid) * 256 + c] = tot;
    }
}

// ---------------------------------------------------------------------------
// K2 k_work: bids [0,256) = conv role (MFMA implicit GEMM -> interleaved
// cc=(y1,y2) bf162 stores + BN4/5 sums); bids [256,4352) = stage2 role
// (BN1-apply + Haar-H + gates -> l2 pixel-major q-interleaved, BN2 sums).
// BN1 coefficients derived by summing the 4 parts1 slots.
// l2 layout: l2[(((tb*256 + c)*256 + pix)*4 + q] bf16, q = LL/HL/LH/HH.
// ---------------------------------------------------------------------------
struct SharedU {
    union {
        struct {
            short lo[1025 * 8];            // channel-last bf16, d 0..7 (+zero row)
            short hi[1025 * 8];            // d 8..15
            unsigned short w2s[2304];      // [k][d*9+tap]
            unsigned short w1s[256];       // [k][d]
            unsigned short bs[32];         // B1 | B2
            float parts[4][4][16];         // [wv][g][r*4+which]
        } cv;
        struct {
            float lo[512];
            float hi[512];
            float part[4][8];
        } s2;
    };
};

__global__ __launch_bounds__(256) void k_work(const unsigned char* __restrict__ s,
                                              const signed char* __restrict__ l1,
                                              const __hip_bfloat16* __restrict__ wc,
                                              float* __restrict__ stats,
                                              __hip_bfloat16* __restrict__ l2,
                                              __hip_bfloat162* __restrict__ cc) {
    __shared__ SharedU sm;
    int bid = blockIdx.x;
    int tid = threadIdx.x;
    int lane = tid & 63, wv = tid >> 6;

    if (bid < 256) {
        // ------------------------------ conv role ------------------------------
        int img = bid;
        const unsigned short* wr = (const unsigned short*)wc;
        for (int i = tid; i < 2304; i += 256) sm.cv.w2s[i] = wr[OFF_W2 + i];
        sm.cv.w1s[tid] = wr[OFF_W1 + tid];
        if (tid < 16) { sm.cv.bs[tid] = wr[OFF_B1 + tid]; sm.cv.bs[16 + tid] = wr[OFF_B2 + tid]; }
        // zero row (pixel index 1024)
        if (tid < 8) {
            ((unsigned int*)sm.cv.lo)[4096 + (tid & 3)] = 0;
            ((unsigned int*)sm.cv.hi)[4096 + (tid & 3)] = 0;
        }
        // stage planar u8 -> LDS channel-last bf16
        {
            const unsigned int* sp = (const unsigned int*)(s + (size_t)img * 16384);
            int d2 = tid >> 5;               // channel pair 2*d2, 2*d2+1
            int pg = tid & 31;
            unsigned int* dst = (unsigned int*)((d2 < 4) ? sm.cv.lo : sm.cv.hi);
            int dl = d2 & 3;
            #pragma unroll
            for (int p = 0; p < 8; ++p) {
                int base = p * 32 + pg;      // dword index within a channel row
                unsigned int u0 = sp[d2 * 512 + base];
                unsigned int u1 = sp[d2 * 512 + 256 + base];
                #pragma unroll
                for (int jj = 0; jj < 4; ++jj) {
                    int j = (jj + pg) & 3;   // scramble to spread LDS banks
                    unsigned int b0 = (u0 >> (8 * j)) & 255u;
                    unsigned int b1 = (u1 >> (8 * j)) & 255u;
                    unsigned int val = (b0 ? 0x3F80u : 0u) | ((b1 ? 0x3F80u : 0u) << 16);
                    int pix = p * 128 + pg * 4 + j;
                    dst[pix * 4 + dl] = val;
                }
            }
        }
        __syncthreads();

        int m = lane & 15;
        int g = lane >> 4;
        const int tapA[5] = {0, 2, 4, 6, 8};
        const int tapB[5] = {1, 3, 5, 7, 8};

        short8 afr[5], a1f;
        #pragma unroll
        for (int p = 0; p < 5; ++p) {
            int tap = (g < 2) ? tapA[p] : tapB[p];
            short8 av;
            #pragma unroll
            for (int j = 0; j < 8; ++j) {
                int d = (g & 1) * 8 + j;
                unsigned short w = sm.cv.w2s[m * 144 + d * 9 + tap];
                if (p == 4 && g >= 2) w = 0;
                av[j] = (short)w;
            }
            afr[p] = av;
        }
        #pragma unroll
        for (int j = 0; j < 8; ++j) {
            int d = (g & 1) * 8 + j;
            a1f[j] = (g < 2) ? (short)sm.cv.w1s[m * 16 + d] : (short)0;
        }
        float bias1[4], bias2[4];
        #pragma unroll
        for (int r = 0; r < 4; ++r) {
            bias1[r] = bfu(sm.cv.bs[g * 4 + r]);
            bias2[r] = bfu(sm.cv.bs[16 + g * 4 + r]);
        }

        __hip_bfloat162* occ = cc + (size_t)img * 16384;
        const short* bsrc = (g & 1) ? sm.cv.hi : sm.cv.lo;

        float cs1[4] = {0, 0, 0, 0}, cq1[4] = {0, 0, 0, 0};
        float cs2[4] = {0, 0, 0, 0}, cq2[4] = {0, 0, 0, 0};

        for (int t = wv * 16; t < wv * 16 + 16; ++t) {
            int h = t >> 1;
            int w0 = (t & 1) << 4;
            f32x4 acc2 = {0.f, 0.f, 0.f, 0.f};
            f32x4 acc1 = {0.f, 0.f, 0.f, 0.f};
            #pragma unroll
            for (int p = 0; p < 5; ++p) {
                int tap = (g < 2) ? tapA[p] : tapB[p];
                int row = h + tap / 3 - 1;
                int col = w0 + m + (tap % 3) - 1;
                bool ok = ((unsigned)row < 32u) && ((unsigned)col < 32u);
                int idx = ok ? (row * 32 + col) : 1024;
                short8 bv = *(const short8*)&bsrc[idx * 8];
                acc2 = __builtin_amdgcn_mfma_f32_16x16x32_bf16(afr[p], bv, acc2, 0, 0, 0);
                if (p == 2)
                    acc1 = __builtin_amdgcn_mfma_f32_16x16x32_bf16(a1f, bv, acc1, 0, 0, 0);
            }
            int pix = h * 32 + w0 + m;
            #pragma unroll
            for (int r = 0; r < 4; ++r) {
                int k = g * 4 + r;
                float y1 = acc1[r] + bias1[r];
                float y2 = acc2[r] + bias2[r];
                __hip_bfloat162 pr;
                pr.x = __float2bfloat16(y1);
                pr.y = __float2bfloat16(y2);
                occ[(size_t)k * 1024 + pix] = pr;
                cs1[r] += y1; cq1[r] += y1 * y1;
                cs2[r] += y2; cq2[r] += y2 * y2;
            }
        }
        // reduce across the 16 m-lanes (same g)
        #pragma unroll
        for (int o = 1; o < 16; o <<= 1) {
            #pragma unroll
            for (int r = 0; r < 4; ++r) {
                cs1[r] += __shfl_xor(cs1[r], o, 64);
                cq1[r] += __shfl_xor(cq1[r], o, 64);
                cs2[r] += __shfl_xor(cs2[r], o, 64);
                cq2[r] += __shfl_xor(cq2[r], o, 64);
            }
        }
        if (m == 0) {
            #pragma unroll
            for (int r = 0; r < 4; ++r) {
                sm.cv.parts[wv][g][r * 4 + 0] = cs1[r];
                sm.cv.parts[wv][g][r * 4 + 1] = cq1[r];
                sm.cv.parts[wv][g][r * 4 + 2] = cs2[r];
                sm.cv.parts[wv][g][r * 4 + 3] = cq2[r];
            }
        }
        __syncthreads();
        if (tid < 64) {
            int gg = tid >> 4, r = (tid >> 2) & 3, which = tid & 3;
            float tot = sm.cv.parts[0][gg][r * 4 + which] + sm.cv.parts[1][gg][r * 4 + which]
                      + sm.cv.parts[2][gg][r * 4 + which] + sm.cv.parts[3][gg][r * 4 + which];
            int ch = (img & 15) * 16 + gg * 4 + r;   // global BN channel
            // stats: sums4_sum@3584 sums4_sq@3840 sums5_sum@4096 sums5_sq@4352
            const int base[4] = {3584, 3840, 4096, 4352};
            atomicAdd(&stats[base[which] + ch], tot);
        }
    } else {
        // ------------------------------ stage2 role ------------------------------
        int blk = bid - 256;                  // TB*C = 4096
        int c = blk & 255;
        int tb = blk >> 8;

        // BN1 raw sums: sum the 4 parts1 slots
        const float* p1 = stats + P1OFF;
        float aLs = 0.f, qLs = 0.f, aHs = 0.f, qHs = 0.f;
        #pragma unroll
        for (int slot = 0; slot < 4; ++slot) {
            aLs += p1[(slot * 4 + 0) * 256 + c];
            qLs += p1[(slot * 4 + 1) * 256 + c];
            aHs += p1[(slot * 4 + 2) * 256 + c];
            qHs += p1[(slot * 4 + 3) * 256 + c];
        }

        const float nrm = 1.f / 8192.f;
        float mL = aLs * INVS2 * nrm;
        float vL = fmaxf(qLs * 0.5f * nrm - mL * mL, 0.f);
        float sL = bf2f(wc[OFF_G1 + c]) * rsqrtf(vL + EPSBN);
        float tL = bf2f(wc[OFF_BE1 + c]) - mL * sL;
        float mH = aHs * INVS2 * nrm;
        float vH = fmaxf(qHs * 0.5f * nrm - mH * mH, 0.f);
        float sH = bf2f(wc[OFF_G1 + 256 + c]) * rsqrtf(vH + EPSBN);
        float tH = bf2f(wc[OFF_BE1 + 256 + c]) - mH * sH;

        const signed char* plo = l1 + (((size_t)tb * 512) + c) * (H_ * Wh_);
        const signed char* phi = l1 + (((size_t)tb * 512) + 256 + c) * (H_ * Wh_);
        float slo = sL * INVS2, shi = sH * INVS2;
        // vectorized: tid<128 unpack lo (128 ints = 512 i8), tid>=128 hi
        {
            int t2 = tid & 127;
            bool isLo = tid < 128;
            int v = isLo ? ((const int*)plo)[t2] : ((const int*)phi)[t2];
            float sc = isLo ? slo : shi;
            float tc = isLo ? tL : tH;
            float* dst = isLo ? sm.s2.lo : sm.s2.hi;
            f32x4 fv;
            #pragma unroll
            for (int j = 0; j < 4; ++j)
                fv[j] = (float)(signed char)((v >> (8 * j)) & 0xFF) * sc + tc;
            *(f32x4*)&dst[t2 * 4] = fv;
        }
        __syncthreads();

        int w = tid & 15, v = tid >> 4;
        float a = sm.s2.lo[(2 * v) * Wh_ + w], b = sm.s2.lo[(2 * v + 1) * Wh_ + w];
        float zLL = (a + b) * INVS2;
        float zHL = (a - b) * INVS2;
        a = sm.s2.hi[(2 * v) * Wh_ + w]; b = sm.s2.hi[(2 * v + 1) * Wh_ + w];
        float zLH = (a + b) * INVS2;
        float zHH = (a - b) * INVS2;
        zLL = (fabsf(zLL) - 0.5f >= 0.f) ? zLL : 0.f;
        zHL = (fabsf(zHL) - 0.5f >= 0.f) ? zHL : 0.f;
        zLH = (fabsf(zLH) - 0.5f >= 0.f) ? zLH : 0.f;
        zHH = (fabsf(zHH) - 0.5f >= 0.f) ? zHH : 0.f;

        float r0 = zLL, r1 = zHL, r2 = zLH, r3 = zHH;
        float q0 = zLL * zLL, q1 = zHL * zHL, q2 = zLH * zLH, q3 = zHH * zHH;
        for (int o = 1; o < 64; o <<= 1) {
            r0 += __shfl_xor(r0, o, 64); r1 += __shfl_xor(r1, o, 64);
            r2 += __shfl_xor(r2, o, 64); r3 += __shfl_xor(r3, o, 64);
            q0 += __shfl_xor(q0, o, 64); q1 += __shfl_xor(q1, o, 64);
            q2 += __shfl_xor(q2, o, 64); q3 += __shfl_xor(q3, o, 64);
        }
        if (lane == 0) {
            sm.s2.part[wv][0] = r0; sm.s2.part[wv][1] = r1;
            sm.s2.part[wv][2] = r2; sm.s2.part[wv][3] = r3;
            sm.s2.part[wv][4] = q0; sm.s2.part[wv][5] = q1;
            sm.s2.part[wv][6] = q2; sm.s2.part[wv][7] = q3;
        }
        __syncthreads();
        float S0 = sm.s2.part[0][0] + sm.s2.part[1][0] + sm.s2.part[2][0] + sm.s2.part[3][0];
        float S1 = sm.s2.part[0][1] + sm.s2.part[1][1] + sm.s2.part[2][1] + sm.s2.part[3][1];
        float S2 = sm.s2.part[0][2] + sm.s2.part[1][2] + sm.s2.part[2][2] + sm.s2.part[3][2];
        float S3 = sm.s2.part[0][3] + sm.s2.part[1][3] + sm.s2.part[2][3] + sm.s2.part[3][3];
        float Q0 = sm.s2.part[0][4] + sm.s2.part[1][4] + sm.s2.part[2][4] + sm.s2.part[3][4];
        float Q1 = sm.s2.part[0][5] + sm.s2.part[1][5] + sm.s2.part[2][5] + sm.s2.part[3][5];
        float Q2 = sm.s2.part[0][6] + sm.s2.part[1][6] + sm.s2.part[2][6] + sm.s2.part[3][6];
        float Q3 = sm.s2.part[0][7] + sm.s2.part[1][7] + sm.s2.part[2][7] + sm.s2.part[3][7];
        float fLL = (Q0 * (1.f / 256.f) > 0.01f) ? 1.f : 0.f;
        float fHL = (Q1 * (1.f / 256.f) > 0.02f) ? 1.f : 0.f;
        float fLH = (Q2 * (1.f / 256.f) > 0.02f) ? 1.f : 0.f;
        float fHH = (Q3 * (1.f / 256.f) > 0.05f) ? 1.f : 0.f;

        float* sums2 = stats + 1024;
        if (tid < 8) {
            const int cho[8] = {0, 1024, 256, 1280, 512, 1536, 768, 1792};
            const float vals[8] = {fLL * S0, fLL * Q0, fHL * S1, fHL * Q1,
                                   fLH * S2, fLH * Q2, fHH * S3, fHH * Q3};
            atomicAdd(&sums2[cho[tid] + c], vals[tid]);
        }

        // pixel-major q-interleaved store: one 8B store per thread
        size_t ob = (((size_t)tb * 256) + c) * 256 + tid;
        s16x4 pk;
        pk[0] = (short)f2bfu(zLL * fLL);
        pk[1] = (short)f2bfu(zHL * fHL);
        pk[2] = (short)f2bfu(zLH * fLH);
        pk[3] = (short)f2bfu(zHH * fHH);
        *(s16x4*)(l2 + 4 * ob) = pk;
    }
}

// ---------------------------------------------------------------------------
// K3 k_mixinv: BN2-apply + block channel matmul + inverse Haar -> rec bf16;
// accumulates BN3 raw sums. Grid 1024 = tb(16) x cg(16) x ks(4): each block
// computes 4 of the 16 output channels (4 blocks/CU). l2 is pixel-major
// q-interleaved: one 8B load yields all four q-planes for (d, pixel).
// ---------------------------------------------------------------------------
__global__ __launch_bounds__(256) void k_mixinv(const __hip_bfloat16* __restrict__ l2,
                                                const __hip_bfloat16* __restrict__ wc,
                                                float* __restrict__ stats,
                                                __hip_bfloat16* __restrict__ rec) {
    int bid = blockIdx.x;                 // 1024 = tb(16) * cg(16) * ks(4)
    int ks = bid & 3;
    int cg = (bid >> 2) & 15;
    int tb = bid >> 6;
    int tid = threadIdx.x;
    int lane = tid & 63, wvv = tid >> 6;
    const float* sums2 = stats + 1024;

    __shared__ float wt[4][16][4];        // [q][d][kk] for k = ks*4+kk
    __shared__ float bsc[64], bsh[64];
    __shared__ float parts2[4][8];
    {
        int i = tid;                      // 256 entries = q(4) * d(16) * kk(4)
        int q = i >> 6, rem = i & 63, d = rem >> 2, kk = rem & 3;
        int nb = q * 4 + (cg >> 2);
        int k = ks * 4 + kk;
        wt[q][d][kk] = bf2f(wc[OFF_HW + nb * 256 + d * 16 + k]);
    }
    if (tid < 64) {
        int q = tid >> 4, d = tid & 15;
        int ch = q * 256 + cg * 16 + d;
        float m = sums2[ch] * (1.f / 4096.f);
        float var = fmaxf(sums2[1024 + ch] * (1.f / 4096.f) - m * m, 0.f);
        float sc = bf2f(wc[OFF_G2 + ch]) * rsqrtf(var + EPSBN);
        bsc[tid] = sc;
        bsh[tid] = bf2f(wc[OFF_BE2 + ch]) - m * sc;
    }
    __syncthreads();

    float h[4][4];
    #pragma unroll
    for (int q = 0; q < 4; ++q)
        #pragma unroll
        for (int kk = 0; kk < 4; ++kk) h[q][kk] = 0.f;

    int p = tid;
    #pragma unroll
    for (int d = 0; d < 16; ++d) {
        s16x4 pk = *(const s16x4*)(l2 + 4 * (((size_t)tb * 256 + cg * 16 + d) * 256 + p));
        #pragma unroll
        for (int q = 0; q < 4; ++q) {
            float xv = bfu((unsigned short)pk[q]) * bsc[q * 16 + d] + bsh[q * 16 + d];
            #pragma unroll
            for (int kk = 0; kk < 4; ++kk)
                h[q][kk] = fmaf(xv, wt[q][d][kk], h[q][kk]);
        }
    }

    int uh = tid >> 4, uw = tid & 15;
    __hip_bfloat16* ob = rec + ((size_t)tb * 256 + cg * 16) * 1024;
    float sk[4], qk[4];
    #pragma unroll
    for (int kk = 0; kk < 4; ++kk) {
        int k = ks * 4 + kk;
        float LL = h[0][kk], HL = h[1][kk], LH = h[2][kk], HH = h[3][kk];
        float v00 = 0.5f * (LL + HL + LH + HH);
        float v01 = 0.5f * (LL + HL - LH - HH);
        float v10 = 0.5f * (LL - HL + LH - HH);
        float v11 = 0.5f * (LL - HL - LH + HH);
        __hip_bfloat162 top, bot;
        top.x = __float2bfloat16(v00); top.y = __float2bfloat16(v01);
        bot.x = __float2bfloat16(v10); bot.y = __float2bfloat16(v11);
        *(__hip_bfloat162*)(ob + (size_t)k * 1024 + (2 * uh) * 32 + 2 * uw) = top;
        *(__hip_bfloat162*)(ob + (size_t)k * 1024 + (2 * uh + 1) * 32 + 2 * uw) = bot;
        sk[kk] = v00 + v01 + v10 + v11;
        qk[kk] = v00 * v00 + v01 * v01 + v10 * v10 + v11 * v11;
    }
    for (int o = 1; o < 64; o <<= 1) {
        #pragma unroll
        for (int kk = 0; kk < 4; ++kk) {
            sk[kk] += __shfl_xor(sk[kk], o, 64);
            qk[kk] += __shfl_xor(qk[kk], o, 64);
        }
    }
    if (lane == 0) {
        #pragma unroll
        for (int kk = 0; kk < 4; ++kk) {
            parts2[wvv][kk * 2]     = sk[kk];
            parts2[wvv][kk * 2 + 1] = qk[kk];
        }
    }
    __syncthreads();
    if (tid < 8) {
        int kk = tid >> 1, which = tid & 1;
        float tot = parts2[0][tid] + parts2[1][tid] + parts2[2][tid] + parts2[3][tid];
        atomicAdd(&stats[3072 + which * 256 + cg * 16 + ks * 4 + kk], tot);
    }
}

// ---------------------------------------------------------------------------
// K4 k_final: elementwise combine at 8192 blocks (pure-BW regime); derives
// BN3/4/5 coefficients from raw sums (block-uniform per half-channel).
// Reads rec (bf162) + interleaved cc=(y1,y2) pairs.
// ---------------------------------------------------------------------------
__global__ __launch_bounds__(256) void k_final(const __hip_bfloat16* __restrict__ rec,
                                               const __hip_bfloat162* __restrict__ cc,
                                               const float* __restrict__ stats,
                                               const __hip_bfloat16* __restrict__ wc,
                                               const int* __restrict__ flag,
                                               void* __restrict__ out_) {
    int n2 = blockIdx.x * 256 + threadIdx.x;    // bf162 index (2 output elems)
    int c = ((n2 * 2) >> 10) & 255;
    const float inv = 1.f / 16384.f;
    float m3 = stats[3072 + c] * inv;
    float v3 = fmaxf(stats[3328 + c] * inv - m3 * m3, 0.f);
    float sc3 = bf2f(wc[OFF_G3 + c]) * rsqrtf(v3 + EPSBN);
    float sh3 = bf2f(wc[OFF_BE3 + c]) - m3 * sc3;
    float m4 = stats[3584 + c] * inv;
    float v4 = fmaxf(stats[3840 + c] * inv - m4 * m4, 0.f);
    float sc4 = bf2f(wc[OFF_G4 + c]) * rsqrtf(v4 + EPSBN);
    float sh4 = bf2f(wc[OFF_BE4 + c]) - m4 * sc4;
    float m5 = stats[4096 + c] * inv;
    float v5 = fmaxf(stats[4352 + c] * inv - m5 * m5, 0.f);
    float sc5 = bf2f(wc[OFF_G5 + c]) * rsqrtf(v5 + EPSBN);
    float sh5 = bf2f(wc[OFF_BE5 + c]) - m5 * sc5;

    __hip_bfloat162 r = ((const __hip_bfloat162*)rec)[n2];
    __hip_bfloat162 pa = cc[2 * n2];        // (y1,y2) of elem 2*n2
    __hip_bfloat162 pb = cc[2 * n2 + 1];    // (y1,y2) of elem 2*n2+1
    float v0 = bf2f(r.x) * sc3 + sh3 + bf2f(pa.x) * sc4 + sh4 + bf2f(pa.y) * sc5 + sh5;
    float v1 = bf2f(r.y) * sc3 + sh3 + bf2f(pb.x) * sc4 + sh4 + bf2f(pb.y) * sc5 + sh5;
    if (*flag) {
        ((float2*)out_)[n2] = make_float2(v0, v1);
    } else {
        __hip_bfloat162 o;
        o.x = __float2bfloat16(v0); o.y = __float2bfloat16(v1);
        ((__hip_bfloat162*)out_)[n2] = o;
    }
}

// ---------------------------------------------------------------------------
// Workspace map:
//   [0,4M):   s (planar u8 spikes)      [4,8M):  l1 (i8 codes)
//   [8,16M):  l2 (pixel-major q-interleaved bf16)
//   [16,24M): rec                       [24,40M): cc (y1,y2 bf162 pairs)
//   [40M..):  weight arena, stats(8704 fl incl parts1), flag
// ---------------------------------------------------------------------------
extern "C" void kernel_launch(void* const* d_in, const int* in_sizes, int n_in,
                              void* d_out, int out_size, void* d_ws, size_t ws_size,
                              hipStream_t stream) {
    char* ws = (char*)d_ws;
    unsigned char* s_u8  = (unsigned char*)ws;
    signed char* l1c     = (signed char*)(ws + ((size_t)4 << 20));
    __hip_bfloat16* l2   = (__hip_bfloat16*)(ws + ((size_t)8 << 20));
    __hip_bfloat16* rec  = (__hip_bfloat16*)(ws + ((size_t)16 << 20));
    __hip_bfloat162* cc  = (__hip_bfloat162*)(ws + ((size_t)24 << 20));
    __hip_bfloat16* wc   = (__hip_bfloat16*)(ws + ((size_t)40 << 20));
    float* stats         = (float*)(ws + ((size_t)40 << 20) + (64 << 10));
    int* flag            = (int*)(ws + ((size_t)40 << 20) + (128 << 10));

    WPtrs wp;
    for (int i = 0; i < 15; ++i) wp.p[i] = d_in[i + 1];

    dim3 blk(256);
    k_lifprep<<<dim3(1069), blk, 0, stream>>>(d_in[0], wp, wc, stats, flag, s_u8, l1c);
    k_work<<<dim3(4352), blk, 0, stream>>>(s_u8, l1c, wc, stats, l2, cc);
    k_mixinv<<<dim3(1024), blk, 0, stream>>>(l2, wc, stats, rec);
    k_final<<<dim3(8192), blk, 0, stream>>>(rec, cc, stats, wc, flag, d_out);
}

// Round 8
// 136.044 us; speedup vs baseline: 1.1732x; 1.0227x over previous
//
#include <hip/hip_runtime.h>
#include <hip/hip_bf16.h>

#define T_ 4
#define B_ 4
#define C_ 256
#define H_ 32
#define W_ 32
#define TB_ 16
#define Hh_ 16
#define Wh_ 16
#define INVS2 0.70710678118654752440f
#define EPSBN 1e-5f

// Canonical weight arena offsets (bf16 elements)
#define OFF_HW   0
#define OFF_W1   4096
#define OFF_B1   4352
#define OFF_W2   4368
#define OFF_B2   6672
#define OFF_G1   6688
#define OFF_BE1  7200
#define OFF_G2   7712
#define OFF_BE2  8736
#define OFF_G3   9760
#define OFF_BE3  10016
#define OFF_G4   10272
#define OFF_BE4  10528
#define OFF_G5   10784
#define OFF_BE5  11040
#define W_TOTAL  11296
// stats arena (floats):
//   [0..1024)   unused (legacy sums1 slot, kept for layout stability)
//   [1024..3072) sums2 (BN2)        — zeroed by prep role, atomics in k_work
//   [3072..4608) sums345 (BN3/4/5)  — zeroed by prep role, atomics later
//   [4608..8704) parts1[4][4][256]  — written unconditionally by lif role
#define NSUMS    4608
#define P1OFF    4608

struct WPtrs { const void* p[15]; };

typedef __attribute__((ext_vector_type(8))) short short8;
typedef __attribute__((ext_vector_type(4))) short s16x4;
typedef __attribute__((ext_vector_type(4))) float f32x4;

__device__ inline float bf2f(__hip_bfloat16 v) { return __bfloat162float(v); }
__device__ inline float bfu(unsigned short u) { return __uint_as_float((unsigned)u << 16); }
__device__ inline unsigned short f2bfu(float v) {
    union { __hip_bfloat16 h; unsigned short u; } c;
    c.h = __float2bfloat16(v);
    return c.u;
}

// ---------------------------------------------------------------------------
// K1 k_lifprep: grid 1069.
//   bids [0,1024): LIF + Haar-W role, 4 pixels/thread. l1 codes are packed
//                  lo/hi-interleaved: one uint [cl0|cl1|ch0|ch1] per t
//                  (single 4B store). BN1 partials to private slots.
//   bids [1024,1069): prep role — convert weights to bf16 arena, zero
//                  sums2/sums345, block 1024 publishes flag.
// ---------------------------------------------------------------------------
__global__ __launch_bounds__(256) void k_lifprep(const void* __restrict__ x_,
                                                 WPtrs wp,
                                                 __hip_bfloat16* __restrict__ wc,
                                                 float* __restrict__ stats,
                                                 int* __restrict__ flag,
                                                 unsigned char* __restrict__ s,
                                                 unsigned int* __restrict__ l1u) {
    int bid = blockIdx.x;
    int tid = threadIdx.x;

    // --- self-sniff (all blocks; identical result) ---
    const unsigned short* xr = (const unsigned short*)x_;
    int cnt = 0;
    for (int i = tid; i < 2048; i += 256) {
        int e = (xr[i] >> 7) & 0xFF;
        if (e >= 134) cnt++;
    }
    for (int o = 1; o < 64; o <<= 1) cnt += __shfl_xor(cnt, o, 64);
    __shared__ int sh[4];
    __shared__ float part[4][4];
    if ((tid & 63) == 0) sh[tid >> 6] = cnt;
    __syncthreads();
    int f = (sh[0] + sh[1] + sh[2] + sh[3] >= 32) ? 1 : 0;

    if (bid >= 1024) {
        // ------------------------------ prep role ------------------------------
        int pb = bid - 1024;
        if (pb == 0 && tid == 0) *flag = f;
        const int sizes[15] = {4096, 256, 16, 2304, 16, 512, 512, 1024, 1024,
                               256, 256, 256, 256, 256, 256};
        int i = pb * 256 + tid;
        if (i < W_TOTAL) {
            int seg = 0, off = 0;
            while (i >= off + sizes[seg]) { off += sizes[seg]; seg++; }
            int j = i - off;
            float v = f ? ((const float*)wp.p[seg])[j]
                        : bf2f(((const __hip_bfloat16*)wp.p[seg])[j]);
            wc[i] = __float2bfloat16(v);
        }
        if (i < 3584) stats[1024 + i] = 0.f;   // zero sums2 + sums345
        return;
    }

    // ------------------------------ LIF+Haar role ------------------------------
    int c = bid & 255;
    int b = bid >> 8;
    int wq = tid & 7;                     // 8 quads of 4 pixels per row
    int h = tid >> 3;                     // 32 rows
    const float* xf = (const float*)x_;
    int n = ((b * 256 + c) * 32 + h) * 32 + 4 * wq;

    float v0 = 0.f, v1 = 0.f, v2 = 0.f, v3 = 0.f;
    float aL = 0.f, qL = 0.f, aH = 0.f, qH = 0.f;
    #pragma unroll
    for (int t = 0; t < T_; ++t) {
        size_t idx = (size_t)t * 1048576 + n;
        float x0, x1, x2, x3;
        if (f) {
            float4 xx = *(const float4*)(xf + idx);
            x0 = xx.x; x1 = xx.y; x2 = xx.z; x3 = xx.w;
        } else {
            uint2 u = *(const uint2*)((const char*)x_ + idx * 2);
            x0 = __uint_as_float(u.x << 16);
            x1 = __uint_as_float(u.x & 0xffff0000u);
            x2 = __uint_as_float(u.y << 16);
            x3 = __uint_as_float(u.y & 0xffff0000u);
        }
        v0 += (x0 - v0) * 0.5f;
        v1 += (x1 - v1) * 0.5f;
        v2 += (x2 - v2) * 0.5f;
        v3 += (x3 - v3) * 0.5f;
        float s0 = (v0 >= 1.f) ? 1.f : 0.f;
        float s1 = (v1 >= 1.f) ? 1.f : 0.f;
        float s2 = (v2 >= 1.f) ? 1.f : 0.f;
        float s3 = (v3 >= 1.f) ? 1.f : 0.f;
        v0 *= (1.f - s0);
        v1 *= (1.f - s1);
        v2 *= (1.f - s2);
        v3 *= (1.f - s3);
        int tb = t * 4 + b;
        *(uchar4*)(s + (size_t)(tb * 256 + c) * 1024 + h * 32 + wq * 4) =
            make_uchar4((unsigned char)s0, (unsigned char)s1,
                        (unsigned char)s2, (unsigned char)s3);
        float cl0 = s0 + s1, ch0 = s0 - s1;
        float cl1 = s2 + s3, ch1 = s2 - s3;
        // packed interleaved code: [cl0 | cl1 | ch0 | ch1], one 4B store
        unsigned int pk = (unsigned int)(unsigned char)(signed char)(int)cl0
                        | ((unsigned int)(unsigned char)(signed char)(int)cl1 << 8)
                        | ((unsigned int)(unsigned char)(signed char)(int)ch0 << 16)
                        | ((unsigned int)(unsigned char)(signed char)(int)ch1 << 24);
        l1u[(((size_t)tb * 256 + c) * 32 + h) * 8 + wq] = pk;
        aL += cl0 + cl1; qL += cl0 * cl0 + cl1 * cl1;
        aH += ch0 + ch1; qH += ch0 * ch0 + ch1 * ch1;
    }
    for (int o = 1; o < 64; o <<= 1) {
        aL += __shfl_xor(aL, o, 64); qL += __shfl_xor(qL, o, 64);
        aH += __shfl_xor(aH, o, 64); qH += __shfl_xor(qH, o, 64);
    }
    int lane = tid & 63, wv = tid >> 6;
    if (lane == 0) {
        part[wv][0] = aL; part[wv][1] = qL; part[wv][2] = aH; part[wv][3] = qH;
    }
    __syncthreads();
    if (tid < 4) {
        float tot = part[0][tid] + part[1][tid] + part[2][tid] + part[3][tid];
        // parts1[slot=b][which][c]; which: 0=aL 1=qL 2=aH 3=qH
        stats[P1OFF + (b * 4 + tid) * 256 + c] = tot;
    }
}

// ---------------------------------------------------------------------------
// K2 k_work: bids [0,256) = conv role (MFMA implicit GEMM -> interleaved
// cc=(y1,y2) bf162 stores + BN4/5 sums); bids [256,4352) = stage2 role
// (BN1-apply + Haar-H + gates -> l2 pixel-major q-interleaved, BN2 sums).
// l1 is uint-packed [cl0|cl1|ch0|ch1]: one 4B load/thread, all threads active.
// l2 layout: l2[(((tb*256 + c)*256 + pix)*4 + q] bf16, q = LL/HL/LH/HH.
// ---------------------------------------------------------------------------
struct SharedU {
    union {
        struct {
            short lo[1025 * 8];            // channel-last bf16, d 0..7 (+zero row)
            short hi[1025 * 8];            // d 8..15
            unsigned short w2s[2304];      // [k][d*9+tap]
            unsigned short w1s[256];       // [k][d]
            unsigned short bs[32];         // B1 | B2
            float parts[4][4][16];         // [wv][g][r*4+which]
        } cv;
        struct {
            float lo[512];
            float hi[512];
            float part[4][8];
        } s2;
    };
};

__global__ __launch_bounds__(256) void k_work(const unsigned char* __restrict__ s,
                                              const unsigned int* __restrict__ l1u,
                                              const __hip_bfloat16* __restrict__ wc,
                                              float* __restrict__ stats,
                                              __hip_bfloat16* __restrict__ l2,
                                              __hip_bfloat162* __restrict__ cc) {
    __shared__ SharedU sm;
    int bid = blockIdx.x;
    int tid = threadIdx.x;
    int lane = tid & 63, wv = tid >> 6;

    if (bid < 256) {
        // ------------------------------ conv role ------------------------------
        int img = bid;
        const unsigned short* wr = (const unsigned short*)wc;
        for (int i = tid; i < 2304; i += 256) sm.cv.w2s[i] = wr[OFF_W2 + i];
        sm.cv.w1s[tid] = wr[OFF_W1 + tid];
        if (tid < 16) { sm.cv.bs[tid] = wr[OFF_B1 + tid]; sm.cv.bs[16 + tid] = wr[OFF_B2 + tid]; }
        // zero row (pixel index 1024)
        if (tid < 8) {
            ((unsigned int*)sm.cv.lo)[4096 + (tid & 3)] = 0;
            ((unsigned int*)sm.cv.hi)[4096 + (tid & 3)] = 0;
        }
        // stage planar u8 -> LDS channel-last bf16
        {
            const unsigned int* sp = (const unsigned int*)(s + (size_t)img * 16384);
            int d2 = tid >> 5;               // channel pair 2*d2, 2*d2+1
            int pg = tid & 31;
            unsigned int* dst = (unsigned int*)((d2 < 4) ? sm.cv.lo : sm.cv.hi);
            int dl = d2 & 3;
            #pragma unroll
            for (int p = 0; p < 8; ++p) {
                int base = p * 32 + pg;      // dword index within a channel row
                unsigned int u0 = sp[d2 * 512 + base];
                unsigned int u1 = sp[d2 * 512 + 256 + base];
                #pragma unroll
                for (int jj = 0; jj < 4; ++jj) {
                    int j = (jj + pg) & 3;   // scramble to spread LDS banks
                    unsigned int b0 = (u0 >> (8 * j)) & 255u;
                    unsigned int b1 = (u1 >> (8 * j)) & 255u;
                    unsigned int val = (b0 ? 0x3F80u : 0u) | ((b1 ? 0x3F80u : 0u) << 16);
                    int pix = p * 128 + pg * 4 + j;
                    dst[pix * 4 + dl] = val;
                }
            }
        }
        __syncthreads();

        int m = lane & 15;
        int g = lane >> 4;
        const int tapA[5] = {0, 2, 4, 6, 8};
        const int tapB[5] = {1, 3, 5, 7, 8};

        short8 afr[5], a1f;
        #pragma unroll
        for (int p = 0; p < 5; ++p) {
            int tap = (g < 2) ? tapA[p] : tapB[p];
            short8 av;
            #pragma unroll
            for (int j = 0; j < 8; ++j) {
                int d = (g & 1) * 8 + j;
                unsigned short w = sm.cv.w2s[m * 144 + d * 9 + tap];
                if (p == 4 && g >= 2) w = 0;
                av[j] = (short)w;
            }
            afr[p] = av;
        }
        #pragma unroll
        for (int j = 0; j < 8; ++j) {
            int d = (g & 1) * 8 + j;
            a1f[j] = (g < 2) ? (short)sm.cv.w1s[m * 16 + d] : (short)0;
        }
        float bias1[4], bias2[4];
        #pragma unroll
        for (int r = 0; r < 4; ++r) {
            bias1[r] = bfu(sm.cv.bs[g * 4 + r]);
            bias2[r] = bfu(sm.cv.bs[16 + g * 4 + r]);
        }

        __hip_bfloat162* occ = cc + (size_t)img * 16384;
        const short* bsrc = (g & 1) ? sm.cv.hi : sm.cv.lo;

        float cs1[4] = {0, 0, 0, 0}, cq1[4] = {0, 0, 0, 0};
        float cs2[4] = {0, 0, 0, 0}, cq2[4] = {0, 0, 0, 0};

        for (int t = wv * 16; t < wv * 16 + 16; ++t) {
            int h = t >> 1;
            int w0 = (t & 1) << 4;
            f32x4 acc2 = {0.f, 0.f, 0.f, 0.f};
            f32x4 acc1 = {0.f, 0.f, 0.f, 0.f};
            #pragma unroll
            for (int p = 0; p < 5; ++p) {
                int tap = (g < 2) ? tapA[p] : tapB[p];
                int row = h + tap / 3 - 1;
                int col = w0 + m + (tap % 3) - 1;
                bool ok = ((unsigned)row < 32u) && ((unsigned)col < 32u);
                int idx = ok ? (row * 32 + col) : 1024;
                short8 bv = *(const short8*)&bsrc[idx * 8];
                acc2 = __builtin_amdgcn_mfma_f32_16x16x32_bf16(afr[p], bv, acc2, 0, 0, 0);
                if (p == 2)
                    acc1 = __builtin_amdgcn_mfma_f32_16x16x32_bf16(a1f, bv, acc1, 0, 0, 0);
            }
            int pix = h * 32 + w0 + m;
            #pragma unroll
            for (int r = 0; r < 4; ++r) {
                int k = g * 4 + r;
                float y1 = acc1[r] + bias1[r];
                float y2 = acc2[r] + bias2[r];
                __hip_bfloat162 pr;
                pr.x = __float2bfloat16(y1);
                pr.y = __float2bfloat16(y2);
                occ[(size_t)k * 1024 + pix] = pr;
                cs1[r] += y1; cq1[r] += y1 * y1;
                cs2[r] += y2; cq2[r] += y2 * y2;
            }
        }
        // reduce across the 16 m-lanes (same g)
        #pragma unroll
        for (int o = 1; o < 16; o <<= 1) {
            #pragma unroll
            for (int r = 0; r < 4; ++r) {
                cs1[r] += __shfl_xor(cs1[r], o, 64);
                cq1[r] += __shfl_xor(cq1[r], o, 64);
                cs2[r] += __shfl_xor(cs2[r], o, 64);
                cq2[r] += __shfl_xor(cq2[r], o, 64);
            }
        }
        if (m == 0) {
            #pragma unroll
            for (int r = 0; r < 4; ++r) {
                sm.cv.parts[wv][g][r * 4 + 0] = cs1[r];
                sm.cv.parts[wv][g][r * 4 + 1] = cq1[r];
                sm.cv.parts[wv][g][r * 4 + 2] = cs2[r];
                sm.cv.parts[wv][g][r * 4 + 3] = cq2[r];
            }
        }
        __syncthreads();
        if (tid < 64) {
            int gg = tid >> 4, r = (tid >> 2) & 3, which = tid & 3;
            float tot = sm.cv.parts[0][gg][r * 4 + which] + sm.cv.parts[1][gg][r * 4 + which]
                      + sm.cv.parts[2][gg][r * 4 + which] + sm.cv.parts[3][gg][r * 4 + which];
            int ch = (img & 15) * 16 + gg * 4 + r;   // global BN channel
            // stats: sums4_sum@3584 sums4_sq@3840 sums5_sum@4096 sums5_sq@4352
            const int base[4] = {3584, 3840, 4096, 4352};
            atomicAdd(&stats[base[which] + ch], tot);
        }
    } else {
        // ------------------------------ stage2 role ------------------------------
        int blk = bid - 256;                  // TB*C = 4096
        int c = blk & 255;
        int tb = blk >> 8;

        // BN1 raw sums: sum the 4 parts1 slots
        const float* p1 = stats + P1OFF;
        float aLs = 0.f, qLs = 0.f, aHs = 0.f, qHs = 0.f;
        #pragma unroll
        for (int slot = 0; slot < 4; ++slot) {
            aLs += p1[(slot * 4 + 0) * 256 + c];
            qLs += p1[(slot * 4 + 1) * 256 + c];
            aHs += p1[(slot * 4 + 2) * 256 + c];
            qHs += p1[(slot * 4 + 3) * 256 + c];
        }

        const float nrm = 1.f / 8192.f;
        float mL = aLs * INVS2 * nrm;
        float vL = fmaxf(qLs * 0.5f * nrm - mL * mL, 0.f);
        float sL = bf2f(wc[OFF_G1 + c]) * rsqrtf(vL + EPSBN);
        float tL = bf2f(wc[OFF_BE1 + c]) - mL * sL;
        float mH = aHs * INVS2 * nrm;
        float vH = fmaxf(qHs * 0.5f * nrm - mH * mH, 0.f);
        float sH = bf2f(wc[OFF_G1 + 256 + c]) * rsqrtf(vH + EPSBN);
        float tH = bf2f(wc[OFF_BE1 + 256 + c]) - mH * sH;

        float slo = sL * INVS2, shi = sH * INVS2;
        // one packed 4B load per thread: [cl0|cl1|ch0|ch1]
        {
            unsigned int v = l1u[((size_t)tb * 256 + c) * 256 + tid];
            int h = tid >> 3, wq = tid & 7;
            float lo0 = (float)(signed char)(v & 0xFF) * slo + tL;
            float lo1 = (float)(signed char)((v >> 8) & 0xFF) * slo + tL;
            float hi0 = (float)(signed char)((v >> 16) & 0xFF) * shi + tH;
            float hi1 = (float)(signed char)(v >> 24) * shi + tH;
            *(float2*)&sm.s2.lo[h * 16 + 2 * wq] = make_float2(lo0, lo1);
            *(float2*)&sm.s2.hi[h * 16 + 2 * wq] = make_float2(hi0, hi1);
        }
        __syncthreads();

        int w = tid & 15, v = tid >> 4;
        float a = sm.s2.lo[(2 * v) * Wh_ + w], b = sm.s2.lo[(2 * v + 1) * Wh_ + w];
        float zLL = (a + b) * INVS2;
        float zHL = (a - b) * INVS2;
        a = sm.s2.hi[(2 * v) * Wh_ + w]; b = sm.s2.hi[(2 * v + 1) * Wh_ + w];
        float zLH = (a + b) * INVS2;
        float zHH = (a - b) * INVS2;
        zLL = (fabsf(zLL) - 0.5f >= 0.f) ? zLL : 0.f;
        zHL = (fabsf(zHL) - 0.5f >= 0.f) ? zHL : 0.f;
        zLH = (fabsf(zLH) - 0.5f >= 0.f) ? zLH : 0.f;
        zHH = (fabsf(zHH) - 0.5f >= 0.f) ? zHH : 0.f;

        float r0 = zLL, r1 = zHL, r2 = zLH, r3 = zHH;
        float q0 = zLL * zLL, q1 = zHL * zHL, q2 = zLH * zLH, q3 = zHH * zHH;
        for (int o = 1; o < 64; o <<= 1) {
            r0 += __shfl_xor(r0, o, 64); r1 += __shfl_xor(r1, o, 64);
            r2 += __shfl_xor(r2, o, 64); r3 += __shfl_xor(r3, o, 64);
            q0 += __shfl_xor(q0, o, 64); q1 += __shfl_xor(q1, o, 64);
            q2 += __shfl_xor(q2, o, 64); q3 += __shfl_xor(q3, o, 64);
        }
        if (lane == 0) {
            sm.s2.part[wv][0] = r0; sm.s2.part[wv][1] = r1;
            sm.s2.part[wv][2] = r2; sm.s2.part[wv][3] = r3;
            sm.s2.part[wv][4] = q0; sm.s2.part[wv][5] = q1;
            sm.s2.part[wv][6] = q2; sm.s2.part[wv][7] = q3;
        }
        __syncthreads();
        float S0 = sm.s2.part[0][0] + sm.s2.part[1][0] + sm.s2.part[2][0] + sm.s2.part[3][0];
        float S1 = sm.s2.part[0][1] + sm.s2.part[1][1] + sm.s2.part[2][1] + sm.s2.part[3][1];
        float S2 = sm.s2.part[0][2] + sm.s2.part[1][2] + sm.s2.part[2][2] + sm.s2.part[3][2];
        float S3 = sm.s2.part[0][3] + sm.s2.part[1][3] + sm.s2.part[2][3] + sm.s2.part[3][3];
        float Q0 = sm.s2.part[0][4] + sm.s2.part[1][4] + sm.s2.part[2][4] + sm.s2.part[3][4];
        float Q1 = sm.s2.part[0][5] + sm.s2.part[1][5] + sm.s2.part[2][5] + sm.s2.part[3][5];
        float Q2 = sm.s2.part[0][6] + sm.s2.part[1][6] + sm.s2.part[2][6] + sm.s2.part[3][6];
        float Q3 = sm.s2.part[0][7] + sm.s2.part[1][7] + sm.s2.part[2][7] + sm.s2.part[3][7];
        float fLL = (Q0 * (1.f / 256.f) > 0.01f) ? 1.f : 0.f;
        float fHL = (Q1 * (1.f / 256.f) > 0.02f) ? 1.f : 0.f;
        float fLH = (Q2 * (1.f / 256.f) > 0.02f) ? 1.f : 0.f;
        float fHH = (Q3 * (1.f / 256.f) > 0.05f) ? 1.f : 0.f;

        float* sums2 = stats + 1024;
        if (tid < 8) {
            const int cho[8] = {0, 1024, 256, 1280, 512, 1536, 768, 1792};
            const float vals[8] = {fLL * S0, fLL * Q0, fHL * S1, fHL * Q1,
                                   fLH * S2, fLH * Q2, fHH * S3, fHH * Q3};
            atomicAdd(&sums2[cho[tid] + c], vals[tid]);
        }

        // pixel-major q-interleaved store: one 8B store per thread
        size_t ob = (((size_t)tb * 256) + c) * 256 + tid;
        s16x4 pk;
        pk[0] = (short)f2bfu(zLL * fLL);
        pk[1] = (short)f2bfu(zHL * fHL);
        pk[2] = (short)f2bfu(zLH * fLH);
        pk[3] = (short)f2bfu(zHH * fHH);
        *(s16x4*)(l2 + 4 * ob) = pk;
    }
}

// ---------------------------------------------------------------------------
// K3 k_mixinv: BN2-apply + block channel matmul + inverse Haar -> rec bf16;
// accumulates BN3 raw sums. Grid 1024 = tb(16) x cg(16) x ks(4): each block
// computes 4 of the 16 output channels (4 blocks/CU). l2 is pixel-major
// q-interleaved: one 8B load yields all four q-planes for (d, pixel).
// ---------------------------------------------------------------------------
__global__ __launch_bounds__(256) void k_mixinv(const __hip_bfloat16* __restrict__ l2,
                                                const __hip_bfloat16* __restrict__ wc,
                                                float* __restrict__ stats,
                                                __hip_bfloat16* __restrict__ rec) {
    int bid = blockIdx.x;                 // 1024 = tb(16) * cg(16) * ks(4)
    int ks = bid & 3;
    int cg = (bid >> 2) & 15;
    int tb = bid >> 6;
    int tid = threadIdx.x;
    int lane = tid & 63, wvv = tid >> 6;
    const float* sums2 = stats + 1024;

    __shared__ float wt[4][16][4];        // [q][d][kk] for k = ks*4+kk
    __shared__ float bsc[64], bsh[64];
    __shared__ float parts2[4][8];
    {
        int i = tid;                      // 256 entries = q(4) * d(16) * kk(4)
        int q = i >> 6, rem = i & 63, d = rem >> 2, kk = rem & 3;
        int nb = q * 4 + (cg >> 2);
        int k = ks * 4 + kk;
        wt[q][d][kk] = bf2f(wc[OFF_HW + nb * 256 + d * 16 + k]);
    }
    if (tid < 64) {
        int q = tid >> 4, d = tid & 15;
        int ch = q * 256 + cg * 16 + d;
        float m = sums2[ch] * (1.f / 4096.f);
        float var = fmaxf(sums2[1024 + ch] * (1.f / 4096.f) - m * m, 0.f);
        float sc = bf2f(wc[OFF_G2 + ch]) * rsqrtf(var + EPSBN);
        bsc[tid] = sc;
        bsh[tid] = bf2f(wc[OFF_BE2 + ch]) - m * sc;
    }
    __syncthreads();

    float h[4][4];
    #pragma unroll
    for (int q = 0; q < 4; ++q)
        #pragma unroll
        for (int kk = 0; kk < 4; ++kk) h[q][kk] = 0.f;

    int p = tid;
    #pragma unroll
    for (int d = 0; d < 16; ++d) {
        s16x4 pk = *(const s16x4*)(l2 + 4 * (((size_t)tb * 256 + cg * 16 + d) * 256 + p));
        #pragma unroll
        for (int q = 0; q < 4; ++q) {
            float xv = bfu((unsigned short)pk[q]) * bsc[q * 16 + d] + bsh[q * 16 + d];
            #pragma unroll
            for (int kk = 0; kk < 4; ++kk)
                h[q][kk] = fmaf(xv, wt[q][d][kk], h[q][kk]);
        }
    }

    int uh = tid >> 4, uw = tid & 15;
    __hip_bfloat16* ob = rec + ((size_t)tb * 256 + cg * 16) * 1024;
    float sk[4], qk[4];
    #pragma unroll
    for (int kk = 0; kk < 4; ++kk) {
        int k = ks * 4 + kk;
        float LL = h[0][kk], HL = h[1][kk], LH = h[2][kk], HH = h[3][kk];
        float v00 = 0.5f * (LL + HL + LH + HH);
        float v01 = 0.5f * (LL + HL - LH - HH);
        float v10 = 0.5f * (LL - HL + LH - HH);
        float v11 = 0.5f * (LL - HL - LH + HH);
        __hip_bfloat162 top, bot;
        top.x = __float2bfloat16(v00); top.y = __float2bfloat16(v01);
        bot.x = __float2bfloat16(v10); bot.y = __float2bfloat16(v11);
        *(__hip_bfloat162*)(ob + (size_t)k * 1024 + (2 * uh) * 32 + 2 * uw) = top;
        *(__hip_bfloat162*)(ob + (size_t)k * 1024 + (2 * uh + 1) * 32 + 2 * uw) = bot;
        sk[kk] = v00 + v01 + v10 + v11;
        qk[kk] = v00 * v00 + v01 * v01 + v10 * v10 + v11 * v11;
    }
    for (int o = 1; o < 64; o <<= 1) {
        #pragma unroll
        for (int kk = 0; kk < 4; ++kk) {
            sk[kk] += __shfl_xor(sk[kk], o, 64);
            qk[kk] += __shfl_xor(qk[kk], o, 64);
        }
    }
    if (lane == 0) {
        #pragma unroll
        for (int kk = 0; kk < 4; ++kk) {
            parts2[wvv][kk * 2]     = sk[kk];
            parts2[wvv][kk * 2 + 1] = qk[kk];
        }
    }
    __syncthreads();
    if (tid < 8) {
        int kk = tid >> 1, which = tid & 1;
        float tot = parts2[0][tid] + parts2[1][tid] + parts2[2][tid] + parts2[3][tid];
        atomicAdd(&stats[3072 + which * 256 + cg * 16 + ks * 4 + kk], tot);
    }
}

// ---------------------------------------------------------------------------
// K4 k_final: elementwise combine, 4 elems/thread (grid 4096); derives
// BN3/4/5 coefficients from raw sums (block covers exactly one BN channel,
// so coefficient math is wave-uniform). 16B vectorized loads/stores.
// ---------------------------------------------------------------------------
__global__ __launch_bounds__(256) void k_final(const __hip_bfloat16* __restrict__ rec,
                                               const __hip_bfloat162* __restrict__ cc,
                                               const float* __restrict__ stats,
                                               const __hip_bfloat16* __restrict__ wc,
                                               const int* __restrict__ flag,
                                               void* __restrict__ out_) {
    int n4 = blockIdx.x * 256 + threadIdx.x;    // 4-elem group index
    int c = ((n4 * 4) >> 10) & 255;             // uniform per block
    const float inv = 1.f / 16384.f;
    float m3 = stats[3072 + c] * inv;
    float v3 = fmaxf(stats[3328 + c] * inv - m3 * m3, 0.f);
    float sc3 = bf2f(wc[OFF_G3 + c]) * rsqrtf(v3 + EPSBN);
    float sh3 = bf2f(wc[OFF_BE3 + c]) - m3 * sc3;
    float m4 = stats[3584 + c] * inv;
    float v4 = fmaxf(stats[3840 + c] * inv - m4 * m4, 0.f);
    float sc4 = bf2f(wc[OFF_G4 + c]) * rsqrtf(v4 + EPSBN);
    float sh4 = bf2f(wc[OFF_BE4 + c]) - m4 * sc4;
    float m5 = stats[4096 + c] * inv;
    float v5 = fmaxf(stats[4352 + c] * inv - m5 * m5, 0.f);
    float sc5 = bf2f(wc[OFF_G5 + c]) * rsqrtf(v5 + EPSBN);
    float sh5 = bf2f(wc[OFF_BE5 + c]) - m5 * sc5;
    float shS = sh3 + sh4 + sh5;

    ushort4 r = ((const ushort4*)rec)[n4];         // 4 bf16 rec values
    short8 pc = ((const short8*)cc)[n4];           // 4 (y1,y2) bf162 pairs

    float o0 = bfu(r.x) * sc3 + bfu((unsigned short)pc[0]) * sc4 + bfu((unsigned short)pc[1]) * sc5 + shS;
    float o1 = bfu(r.y) * sc3 + bfu((unsigned short)pc[2]) * sc4 + bfu((unsigned short)pc[3]) * sc5 + shS;
    float o2 = bfu(r.z) * sc3 + bfu((unsigned short)pc[4]) * sc4 + bfu((unsigned short)pc[5]) * sc5 + shS;
    float o3 = bfu(r.w) * sc3 + bfu((unsigned short)pc[6]) * sc4 + bfu((unsigned short)pc[7]) * sc5 + shS;

    if (*flag) {
        ((float4*)out_)[n4] = make_float4(o0, o1, o2, o3);
    } else {
        ushort4 ov;
        ov.x = f2bfu(o0); ov.y = f2bfu(o1); ov.z = f2bfu(o2); ov.w = f2bfu(o3);
        ((ushort4*)out_)[n4] = ov;
    }
}

// ---------------------------------------------------------------------------
// Workspace map:
//   [0,4M):   s (planar u8 spikes)      [4,8M):  l1u (packed uint codes)
//   [8,16M):  l2 (pixel-major q-interleaved bf16)
//   [16,24M): rec                       [24,40M): cc (y1,y2 bf162 pairs)
//   [40M..):  weight arena, stats(8704 fl incl parts1), flag
// ---------------------------------------------------------------------------
extern "C" void kernel_launch(void* const* d_in, const int* in_sizes, int n_in,
                              void* d_out, int out_size, void* d_ws, size_t ws_size,
                              hipStream_t stream) {
    char* ws = (char*)d_ws;
    unsigned char* s_u8  = (unsigned char*)ws;
    unsigned int* l1u    = (unsigned int*)(ws + ((size_t)4 << 20));
    __hip_bfloat16* l2   = (__hip_bfloat16*)(ws + ((size_t)8 << 20));
    __hip_bfloat16* rec  = (__hip_bfloat16*)(ws + ((size_t)16 << 20));
    __hip_bfloat162* cc  = (__hip_bfloat162*)(ws + ((size_t)24 << 20));
    __hip_bfloat16* wc   = (__hip_bfloat16*)(ws + ((size_t)40 << 20));
    float* stats         = (float*)(ws + ((size_t)40 << 20) + (64 << 10));
    int* flag            = (int*)(ws + ((size_t)40 << 20) + (128 << 10));

    WPtrs wp;
    for (int i = 0; i < 15; ++i) wp.p[i] = d_in[i + 1];

    dim3 blk(256);
    k_lifprep<<<dim3(1069), blk, 0, stream>>>(d_in[0], wp, wc, stats, flag, s_u8, l1u);
    k_work<<<dim3(4352), blk, 0, stream>>>(s_u8, l1u, wc, stats, l2, cc);
    k_mixinv<<<dim3(1024), blk, 0, stream>>>(l2, wc, stats, rec);
    k_final<<<dim3(4096), blk, 0, stream>>>(rec, cc, stats, wc, flag, d_out);
}